// Round 1
// baseline (5535.314 us; speedup 1.0000x reference)
//
#include <hip/hip_runtime.h>
#include <hip/hip_bf16.h>
#include <math.h>

#define DIMC 512
#define HEADS 8
#define HD 64
#define BB 4
#define HH 32
#define WW 32
#define HWX 1024          // H*W
#define TXT 77
#define LATC 512
#define NE 8
#define HIDC 2048
#define NTOK 4096         // B*H*W

// ---------------- style = w @ mod_w.T + mod_b  ([B,DIM]) ----------------
__global__ void style_kernel(const float* __restrict__ w, const float* __restrict__ mod_w,
                             const float* __restrict__ mod_b, float* __restrict__ style) {
    int t = blockIdx.x * blockDim.x + threadIdx.x;
    if (t >= BB * DIMC) return;
    int b = t / DIMC, i = t % DIMC;
    const float* wr = w + (long)b * LATC;
    const float* mr = mod_w + (long)i * LATC;
    float s = 0.f;
    #pragma unroll 8
    for (int l = 0; l < LATC; l++) s += wr[l] * mr[l];
    style[t] = s + mod_b[i];
}

// ------- wtmod[b,o,i] = weight[o,i]*style[b,i]*rsqrt(sum_i(.)^2+1e-8) -------
__global__ void wtmod_kernel(const float* __restrict__ weight, const float* __restrict__ style,
                             float* __restrict__ wtmod) {
    int bo = blockIdx.x;            // b*DIM + o
    int b = bo / DIMC, o = bo % DIMC;
    const float* wr = weight + (long)o * DIMC;
    const float* sr = style + (long)b * DIMC;
    int t = threadIdx.x;            // 256
    float vals[2]; float part = 0.f;
    for (int j = 0; j < 2; j++) {
        int i = t + j * 256;
        float v = wr[i] * sr[i];
        vals[j] = v; part += v * v;
    }
    __shared__ float red[256];
    red[t] = part; __syncthreads();
    for (int s = 128; s > 0; s >>= 1) { if (t < s) red[t] += red[t + s]; __syncthreads(); }
    float d = rsqrtf(red[0] + 1e-8f);
    float* outp = wtmod + (long)bo * DIMC;
    for (int j = 0; j < 2; j++) { int i = t + j * 256; outp[i] = vals[j] * d; }
}

// ---------------- generic strided fp32 GEMM: C[m,n] = sum_k A(m,k)*B(n,k) (+bias)(+resid) ----------------
__global__ void gemm_kernel(const float* __restrict__ A, const float* __restrict__ Bm,
                            const float* __restrict__ bias, const float* __restrict__ resid,
                            float* __restrict__ C,
                            int M, int N, int K,
                            long as_m, long as_k, long a_bat,
                            long bs_n, long bs_k, long b_bat,
                            long cs_m, long cs_n, long c_bat) {
    __shared__ float As[32][33];
    __shared__ float Bs[32][33];
    int bm = blockIdx.y * 32, bn = blockIdx.x * 32, bat = blockIdx.z;
    A += (long)bat * a_bat; Bm += (long)bat * b_bat; C += (long)bat * c_bat;
    const float* R = resid ? resid + (long)bat * c_bat : nullptr;
    int tx = threadIdx.x & 15, ty = threadIdx.x >> 4;   // 256 threads
    float acc[2][2] = {{0.f,0.f},{0.f,0.f}};
    for (int k0 = 0; k0 < K; k0 += 32) {
        #pragma unroll
        for (int j = 0; j < 4; j++) {
            int e = threadIdx.x + j * 256;
            int mi = e >> 5, ki = e & 31;
            int m = bm + mi, k = k0 + ki;
            As[mi][ki] = (m < M && k < K) ? A[(long)m * as_m + (long)k * as_k] : 0.f;
            int n = bn + mi;
            Bs[mi][ki] = (n < N && k < K) ? Bm[(long)n * bs_n + (long)k * bs_k] : 0.f;
        }
        __syncthreads();
        #pragma unroll
        for (int kk = 0; kk < 32; kk++) {
            float a0 = As[ty][kk], a1 = As[ty + 16][kk];
            float b0 = Bs[tx][kk], b1 = Bs[tx + 16][kk];
            acc[0][0] += a0 * b0; acc[0][1] += a0 * b1;
            acc[1][0] += a1 * b0; acc[1][1] += a1 * b1;
        }
        __syncthreads();
    }
    #pragma unroll
    for (int im = 0; im < 2; im++)
    #pragma unroll
    for (int in_ = 0; in_ < 2; in_++) {
        int m = bm + ty + im * 16, n = bn + tx + in_ * 16;
        if (m < M && n < N) {
            float v = acc[im][in_];
            if (bias) v += bias[n];
            long coff = (long)m * cs_m + (long)n * cs_n;
            if (R) v += R[coff];
            C[coff] = v;
        }
    }
}

// ---------------- LayerNorm over DIM=512, block=256, one block per token ----------------
__global__ void ln_kernel(const float* __restrict__ x, const float* __restrict__ g,
                          const float* __restrict__ b, float* __restrict__ y) {
    int tok = blockIdx.x;
    int t = threadIdx.x;
    const float* xr = x + (long)tok * DIMC;
    float v0 = xr[t], v1 = xr[t + 256];
    __shared__ float red[256];
    red[t] = v0 + v1; __syncthreads();
    for (int s = 128; s > 0; s >>= 1) { if (t < s) red[t] += red[t + s]; __syncthreads(); }
    float mu = red[0] * (1.f / DIMC);
    __syncthreads();
    float d0 = v0 - mu, d1 = v1 - mu;
    red[t] = d0 * d0 + d1 * d1; __syncthreads();
    for (int s = 128; s > 0; s >>= 1) { if (t < s) red[t] += red[t + s]; __syncthreads(); }
    float rs = rsqrtf(red[0] * (1.f / DIMC) + 1e-5f);
    float* yr = y + (long)tok * DIMC;
    yr[t]       = d0 * rs * g[t]       + b[t];
    yr[t + 256] = d1 * rs * g[t + 256] + b[t + 256];
}

// ---------------- self-attention: one block per (q-row, head) ----------------
__global__ void sa_attn_kernel(const float* __restrict__ qkv, float* __restrict__ o) {
    int m = blockIdx.x;          // b*1024 + q
    int h = blockIdx.y;
    int b = m >> 10;
    int t = threadIdx.x;         // 256
    __shared__ float qs[64];
    __shared__ float sc[1024];
    __shared__ float red[256];
    __shared__ float ored[4][64];
    if (t < 64) qs[t] = qkv[(long)m * 1536 + h * 64 + t];
    __syncthreads();
    float lm = -1e30f;
    #pragma unroll
    for (int j = 0; j < 4; j++) {
        int kidx = t + j * 256;
        const float* kr = qkv + ((long)(b * 1024 + kidx)) * 1536 + 512 + h * 64;
        float s = 0.f;
        #pragma unroll 8
        for (int d = 0; d < 64; d++) s += qs[d] * kr[d];
        s *= 0.125f;             // HD^-0.5
        sc[kidx] = s;
        lm = fmaxf(lm, s);
    }
    red[t] = lm; __syncthreads();
    for (int s = 128; s > 0; s >>= 1) { if (t < s) red[t] = fmaxf(red[t], red[t + s]); __syncthreads(); }
    float mx = red[0]; __syncthreads();
    float ls = 0.f;
    #pragma unroll
    for (int j = 0; j < 4; j++) {
        int kidx = t + j * 256;
        float e = __expf(sc[kidx] - mx);
        sc[kidx] = e; ls += e;
    }
    red[t] = ls; __syncthreads();
    for (int s = 128; s > 0; s >>= 1) { if (t < s) red[t] += red[t + s]; __syncthreads(); }
    float inv = 1.f / red[0];
    __syncthreads();
    int d = t & 63, ch = t >> 6;
    float acc = 0.f;
    for (int kidx = ch * 256; kidx < (ch + 1) * 256; kidx++)
        acc += sc[kidx] * qkv[((long)(b * 1024 + kidx)) * 1536 + 1024 + h * 64 + d];
    ored[ch][d] = acc; __syncthreads();
    if (t < 64) {
        float v = (ored[0][t] + ored[1][t] + ored[2][t] + ored[3][t]) * inv;
        o[(long)m * DIMC + h * 64 + t] = v;
    }
}

// ---------------- cross-attention (77 keys): block=128 per (q-row, head) ----------------
__global__ void ca_attn_kernel(const float* __restrict__ q, const float* __restrict__ kv,
                               float* __restrict__ o) {
    int m = blockIdx.x; int h = blockIdx.y; int b = m >> 10;
    int t = threadIdx.x;    // 128
    __shared__ float qs[64];
    __shared__ float sc[77];
    __shared__ float red[128];
    if (t < 64) qs[t] = q[(long)m * DIMC + h * 64 + t];
    __syncthreads();
    float lm = -1e30f;
    if (t < 77) {
        const float* kr = kv + ((long)(b * 77 + t)) * 1024 + h * 64;
        float s = 0.f;
        #pragma unroll 8
        for (int d = 0; d < 64; d++) s += qs[d] * kr[d];
        s *= 0.125f;
        sc[t] = s; lm = s;
    }
    red[t] = lm; __syncthreads();
    for (int s = 64; s > 0; s >>= 1) { if (t < s) red[t] = fmaxf(red[t], red[t + s]); __syncthreads(); }
    float mx = red[0]; __syncthreads();
    float ls = 0.f;
    if (t < 77) { float e = __expf(sc[t] - mx); sc[t] = e; ls = e; }
    red[t] = ls; __syncthreads();
    for (int s = 64; s > 0; s >>= 1) { if (t < s) red[t] += red[t + s]; __syncthreads(); }
    float inv = 1.f / red[0];
    __syncthreads();
    if (t < 64) {
        float acc = 0.f;
        for (int kk = 0; kk < 77; kk++)
            acc += sc[kk] * kv[((long)(b * 77 + kk)) * 1024 + 512 + h * 64 + t];
        o[(long)m * DIMC + h * 64 + t] = acc * inv;
    }
}

// ---------------- router text part: tp[b,e] = sum_c (w[b]·r_text_mu[:,c]) * r_comb[128+c,e] ----------------
__global__ void textpart_kernel(const float* __restrict__ w, const float* __restrict__ r_text_mu,
                                const float* __restrict__ r_comb_mu, float* __restrict__ tp) {
    __shared__ float tw[4][128];
    int t = threadIdx.x;   // 256
    for (int j = 0; j < 2; j++) {
        int idx = t + j * 256; int b = idx >> 7, c = idx & 127;
        const float* wr = w + (long)b * LATC;
        float s = 0.f;
        for (int k = 0; k < LATC; k++) s += wr[k] * r_text_mu[(long)k * 128 + c];
        tw[b][c] = s;
    }
    __syncthreads();
    if (t < 32) {
        int b = t >> 3, e = t & 7;
        float s = 0.f;
        for (int c = 0; c < 128; c++) s += tw[b][c] * r_comb_mu[(long)(128 + c) * 8 + e];
        tp[t] = s;
    }
}

// ---------------- router final: logits -> argmax -> one_hot + idx ----------------
__global__ void route_kernel(const float* __restrict__ feat, const float* __restrict__ tp,
                             const float* __restrict__ r_comb_mu, const float* __restrict__ r_temp,
                             float* __restrict__ onehot, int* __restrict__ idx) {
    int n = blockIdx.x * blockDim.x + threadIdx.x;
    if (n >= NTOK) return;
    int b = n >> 10;
    float tmp = fmaxf(r_temp[0], 0.1f);
    float invt = 1.f / tmp;
    const float* fr = feat + (long)n * 128;
    float lg[8];
    for (int e = 0; e < 8; e++) {
        float s = 0.f;
        for (int c = 0; c < 128; c++) s += fr[c] * r_comb_mu[(long)c * 8 + e];
        lg[e] = (s + tp[b * 8 + e]) * invt;
    }
    float best = lg[0]; int bi = 0;
    for (int e = 1; e < 8; e++) { if (lg[e] > best) { best = lg[e]; bi = e; } }
    for (int e = 0; e < 8; e++) onehot[(long)n * 8 + e] = (e == bi) ? 1.f : 0.f;
    idx[n] = bi;
}

// ---------------- MoE: one block per token, only the selected expert ----------------
__global__ void moe_kernel(const float* __restrict__ tok, const int* __restrict__ idx,
                           const float* __restrict__ e_w1, const float* __restrict__ e_b1,
                           const float* __restrict__ e_w2, const float* __restrict__ e_b2,
                           float* __restrict__ x_flat) {
    int n = blockIdx.x;
    int t = threadIdx.x;   // 256
    int e = idx[n];
    __shared__ float ts[DIMC];
    __shared__ float hid[HIDC];
    ts[t] = tok[(long)n * DIMC + t];
    ts[t + 256] = tok[(long)n * DIMC + t + 256];
    __syncthreads();
    const float* w1 = e_w1 + (long)e * DIMC * HIDC;
    float acc[8];
    #pragma unroll
    for (int j = 0; j < 8; j++) acc[j] = e_b1[(long)e * HIDC + t + j * 256];
    for (int k = 0; k < DIMC; k++) {
        float tv = ts[k];
        const float* row = w1 + (long)k * HIDC + t;
        #pragma unroll
        for (int j = 0; j < 8; j++) acc[j] += tv * row[j * 256];
    }
    #pragma unroll
    for (int j = 0; j < 8; j++) {
        float v = acc[j];
        hid[t + j * 256] = 0.5f * v * (1.f + erff(v * 0.70710678f));   // exact GELU
    }
    __syncthreads();
    const float* w2 = e_w2 + (long)e * HIDC * DIMC;
    float o0 = e_b2[(long)e * DIMC + t], o1 = e_b2[(long)e * DIMC + t + 256];
    for (int hh = 0; hh < HIDC; hh++) {
        float hv = hid[hh];
        const float* row = w2 + (long)hh * DIMC;
        o0 += hv * row[t];
        o1 += hv * row[t + 256];
    }
    x_flat[(long)n * DIMC + t]       += o0;
    x_flat[(long)n * DIMC + t + 256] += o1;
}

extern "C" void kernel_launch(void* const* d_in, const int* in_sizes, int n_in,
                              void* d_out, int out_size, void* d_ws, size_t ws_size,
                              hipStream_t stream) {
    const float* x        = (const float*)d_in[0];
    const float* w        = (const float*)d_in[1];
    const float* text     = (const float*)d_in[2];
    const float* pin_w    = (const float*)d_in[3];
    const float* pin_mw   = (const float*)d_in[4];
    const float* pin_mb   = (const float*)d_in[5];
    const float* pout_w   = (const float*)d_in[6];
    const float* pout_mw  = (const float*)d_in[7];
    const float* pout_mb  = (const float*)d_in[8];
    const float* ln1g     = (const float*)d_in[9];
    const float* ln1b     = (const float*)d_in[10];
    const float* ln2g     = (const float*)d_in[11];
    const float* ln2b     = (const float*)d_in[12];
    const float* ln3g     = (const float*)d_in[13];
    const float* ln3b     = (const float*)d_in[14];
    const float* sa_in_w  = (const float*)d_in[15];
    const float* sa_in_b  = (const float*)d_in[16];
    const float* sa_out_w = (const float*)d_in[17];
    const float* sa_out_b = (const float*)d_in[18];
    const float* ca_in_w  = (const float*)d_in[19];
    const float* ca_in_b  = (const float*)d_in[20];
    const float* ca_out_w = (const float*)d_in[21];
    const float* ca_out_b = (const float*)d_in[22];
    const float* r_feat   = (const float*)d_in[23];
    const float* r_text   = (const float*)d_in[24];
    const float* r_comb   = (const float*)d_in[25];
    const float* r_temp   = (const float*)d_in[26];
    const float* e_w1     = (const float*)d_in[27];
    const float* e_b1     = (const float*)d_in[28];
    const float* e_w2     = (const float*)d_in[29];
    const float* e_b2     = (const float*)d_in[30];

    float* out    = (float*)d_out;               // [B, DIM, H, W] = 2097152
    float* onehot = out + (long)BB * DIMC * HWX; // [4096, 8]

    float* ws = (float*)d_ws;
    float* style_in  = ws;                         // 2048
    float* style_out = style_in + 2048;            // 2048
    float* wtmod     = style_out + 2048;           // 1048576 (reused in/out)
    float* x_flat    = wtmod + 1048576;            // 2097152  [B, HW, DIM]
    float* xn        = x_flat + 2097152;           // 2097152
    float* qkv       = xn + 2097152;               // 6291456  (also CA q re-use)
    float* obuf      = qkv + 6291456;              // 2097152
    float* kvtext    = obuf + 2097152;             // 315392   [B*77, 1024]
    float* feat      = kvtext + 315392;            // 524288   [4096, 128]
    float* tp        = feat + 524288;              // 32
    int*   idx       = (int*)(tp + 32);            // 4096 ints

    auto gemm = [&](const float* A, const float* Bm, const float* bias, const float* resid, float* C,
                    int M, int N, int K,
                    long as_m, long as_k, long a_bat,
                    long bs_n, long bs_k, long b_bat,
                    long cs_m, long cs_n, long c_bat, int nbat) {
        dim3 g((N + 31) / 32, (M + 31) / 32, nbat);
        hipLaunchKernelGGL(gemm_kernel, g, dim3(256), 0, stream,
                           A, Bm, bias, resid, C, M, N, K,
                           as_m, as_k, a_bat, bs_n, bs_k, b_bat, cs_m, cs_n, c_bat);
    };

    // ---- modconv in ----
    hipLaunchKernelGGL(style_kernel, dim3(8), dim3(256), 0, stream, w, pin_mw, pin_mb, style_in);
    hipLaunchKernelGGL(wtmod_kernel, dim3(BB * DIMC), dim3(256), 0, stream, pin_w, style_in, wtmod);
    // x_flat[b,hw,o] = sum_i wtmod[b,o,i] * x[b,i,hw]
    gemm(x, wtmod, nullptr, nullptr, x_flat,
         HWX, DIMC, DIMC,
         1, HWX, (long)DIMC * HWX,
         DIMC, 1, (long)DIMC * DIMC,
         DIMC, 1, (long)HWX * DIMC, BB);

    // ---- LN1 + self-attention ----
    hipLaunchKernelGGL(ln_kernel, dim3(NTOK), dim3(256), 0, stream, x_flat, ln1g, ln1b, xn);
    gemm(xn, sa_in_w, sa_in_b, nullptr, qkv,
         NTOK, 1536, DIMC,
         DIMC, 1, 0, DIMC, 1, 0, 1536, 1, 0, 1);
    hipLaunchKernelGGL(sa_attn_kernel, dim3(NTOK, HEADS), dim3(256), 0, stream, qkv, obuf);
    gemm(obuf, sa_out_w, sa_out_b, x_flat, x_flat,
         NTOK, DIMC, DIMC,
         DIMC, 1, 0, DIMC, 1, 0, DIMC, 1, 0, 1);

    // ---- LN2 + cross-attention ----
    hipLaunchKernelGGL(ln_kernel, dim3(NTOK), dim3(256), 0, stream, x_flat, ln2g, ln2b, xn);
    gemm(xn, ca_in_w, ca_in_b, nullptr, qkv,        // q_ca = [4096,512] (reuse qkv buf)
         NTOK, DIMC, DIMC,
         DIMC, 1, 0, DIMC, 1, 0, DIMC, 1, 0, 1);
    gemm(text, ca_in_w + (long)DIMC * DIMC, ca_in_b + DIMC, nullptr, kvtext,
         BB * TXT, 1024, DIMC,
         DIMC, 1, 0, DIMC, 1, 0, 1024, 1, 0, 1);
    hipLaunchKernelGGL(ca_attn_kernel, dim3(NTOK, HEADS), dim3(128), 0, stream, qkv, kvtext, obuf);
    gemm(obuf, ca_out_w, ca_out_b, x_flat, x_flat,
         NTOK, DIMC, DIMC,
         DIMC, 1, 0, DIMC, 1, 0, DIMC, 1, 0, 1);

    // ---- LN3 + router + MoE ----
    hipLaunchKernelGGL(ln_kernel, dim3(NTOK), dim3(256), 0, stream, x_flat, ln3g, ln3b, xn);
    // feat[n,c] = tok[n,:] @ r_feat_mu[:,c]
    gemm(xn, r_feat, nullptr, nullptr, feat,
         NTOK, 128, DIMC,
         DIMC, 1, 0, 1, 128, 0, 128, 1, 0, 1);
    hipLaunchKernelGGL(textpart_kernel, dim3(1), dim3(256), 0, stream, w, r_text, r_comb, tp);
    hipLaunchKernelGGL(route_kernel, dim3(16), dim3(256), 0, stream, feat, tp, r_comb, r_temp, onehot, idx);
    hipLaunchKernelGGL(moe_kernel, dim3(NTOK), dim3(256), 0, stream, xn, idx, e_w1, e_b1, e_w2, e_b2, x_flat);

    // ---- modconv out -> d_out ----
    hipLaunchKernelGGL(style_kernel, dim3(8), dim3(256), 0, stream, w, pout_mw, pout_mb, style_out);
    hipLaunchKernelGGL(wtmod_kernel, dim3(BB * DIMC), dim3(256), 0, stream, pout_w, style_out, wtmod);
    // out[b,o,hw] = sum_i x_flat[b,hw,i] * wtmod[b,o,i]
    gemm(x_flat, wtmod, nullptr, nullptr, out,
         HWX, DIMC, DIMC,
         DIMC, 1, (long)HWX * DIMC,
         DIMC, 1, (long)DIMC * DIMC,
         1, HWX, (long)DIMC * HWX, BB);
}

// Round 2
// 2829.901 us; speedup vs baseline: 1.9560x; 1.9560x over previous
//
#include <hip/hip_runtime.h>
#include <hip/hip_bf16.h>
#include <math.h>

#define DIMC 512
#define HEADS 8
#define HD 64
#define BB 4
#define HWX 1024          // H*W
#define TXT 77
#define LATC 512
#define NE 8
#define HIDC 2048
#define NTOK 4096         // B*H*W
#define MAXTILES 72       // sum(ceil(cnt_e/64)) <= 4096/64 + 8 = 72

// ---------------- style = w @ mod_w.T + mod_b  ([B,DIM]) ----------------
__global__ void style_kernel(const float* __restrict__ w, const float* __restrict__ mod_w,
                             const float* __restrict__ mod_b, float* __restrict__ style) {
    int t = blockIdx.x * blockDim.x + threadIdx.x;
    if (t >= BB * DIMC) return;
    int b = t / DIMC, i = t % DIMC;
    const float* wr = w + (long)b * LATC;
    const float* mr = mod_w + (long)i * LATC;
    float s = 0.f;
    #pragma unroll 8
    for (int l = 0; l < LATC; l++) s += wr[l] * mr[l];
    style[t] = s + mod_b[i];
}

// ------- wtmod[b,o,i] = weight[o,i]*style[b,i]*rsqrt(sum_i(.)^2+1e-8) -------
__global__ void wtmod_kernel(const float* __restrict__ weight, const float* __restrict__ style,
                             float* __restrict__ wtmod) {
    int bo = blockIdx.x;            // b*DIM + o
    int b = bo / DIMC, o = bo % DIMC;
    const float* wr = weight + (long)o * DIMC;
    const float* sr = style + (long)b * DIMC;
    int t = threadIdx.x;            // 256
    float vals[2]; float part = 0.f;
    for (int j = 0; j < 2; j++) {
        int i = t + j * 256;
        float v = wr[i] * sr[i];
        vals[j] = v; part += v * v;
    }
    __shared__ float red[256];
    red[t] = part; __syncthreads();
    for (int s = 128; s > 0; s >>= 1) { if (t < s) red[t] += red[t + s]; __syncthreads(); }
    float d = rsqrtf(red[0] + 1e-8f);
    float* outp = wtmod + (long)bo * DIMC;
    for (int j = 0; j < 2; j++) { int i = t + j * 256; outp[i] = vals[j] * d; }
}

// ---- generic strided fp32 GEMM: C[m,n] = sum_k A(m,k)*B(n,k) (+bias)(+resid) ----
// 64x64 tile, BK=16, 256 threads, 4x4 per thread. K must be a multiple of 16.
__global__ void gemm_kernel(const float* __restrict__ A, const float* __restrict__ Bm,
                            const float* __restrict__ bias, const float* __restrict__ resid,
                            float* __restrict__ C,
                            int M, int N, int K,
                            long as_m, long as_k, long a_bat,
                            long bs_n, long bs_k, long b_bat,
                            long cs_m, long cs_n, long c_bat) {
    __shared__ float As[16][68];
    __shared__ float Bs[16][68];
    int bm = blockIdx.y * 64, bn = blockIdx.x * 64, bat = blockIdx.z;
    A += (long)bat * a_bat; Bm += (long)bat * b_bat; C += (long)bat * c_bat;
    const float* R = resid ? resid + (long)bat * c_bat : nullptr;
    int t = threadIdx.x;
    int tx = t & 15, ty = t >> 4;
    float acc[4][4] = {};
    for (int k0 = 0; k0 < K; k0 += 16) {
        #pragma unroll
        for (int j = 0; j < 4; j++) {
            int e = t + j * 256;               // 1024 elems: 64 rows x 16 k
            int mi = e >> 4, ki = e & 15;
            int m = bm + mi, k = k0 + ki;
            As[ki][mi] = (m < M) ? A[(long)m * as_m + (long)k * as_k] : 0.f;
            int n = bn + mi;
            Bs[ki][mi] = (n < N) ? Bm[(long)n * bs_n + (long)k * bs_k] : 0.f;
        }
        __syncthreads();
        #pragma unroll
        for (int kk = 0; kk < 16; kk++) {
            float a[4], b[4];
            #pragma unroll
            for (int i = 0; i < 4; i++) { a[i] = As[kk][ty * 4 + i]; b[i] = Bs[kk][tx * 4 + i]; }
            #pragma unroll
            for (int i = 0; i < 4; i++)
            #pragma unroll
            for (int j2 = 0; j2 < 4; j2++) acc[i][j2] += a[i] * b[j2];
        }
        __syncthreads();
    }
    #pragma unroll
    for (int i = 0; i < 4; i++) {
        int m = bm + ty * 4 + i;
        if (m >= M) continue;
        #pragma unroll
        for (int j2 = 0; j2 < 4; j2++) {
            int n = bn + tx * 4 + j2;
            if (n >= N) continue;
            float v = acc[i][j2];
            if (bias) v += bias[n];
            long coff = (long)m * cs_m + (long)n * cs_n;
            if (R) v += R[coff];
            C[coff] = v;
        }
    }
}

// ---------------- LayerNorm over DIM=512, block=256, one block per token ----------------
__global__ void ln_kernel(const float* __restrict__ x, const float* __restrict__ g,
                          const float* __restrict__ b, float* __restrict__ y) {
    int tok = blockIdx.x;
    int t = threadIdx.x;
    const float* xr = x + (long)tok * DIMC;
    float v0 = xr[t], v1 = xr[t + 256];
    __shared__ float red[256];
    red[t] = v0 + v1; __syncthreads();
    for (int s = 128; s > 0; s >>= 1) { if (t < s) red[t] += red[t + s]; __syncthreads(); }
    float mu = red[0] * (1.f / DIMC);
    __syncthreads();
    float d0 = v0 - mu, d1 = v1 - mu;
    red[t] = d0 * d0 + d1 * d1; __syncthreads();
    for (int s = 128; s > 0; s >>= 1) { if (t < s) red[t] += red[t + s]; __syncthreads(); }
    float rs = rsqrtf(red[0] * (1.f / DIMC) + 1e-5f);
    float* yr = y + (long)tok * DIMC;
    yr[t]       = d0 * rs * g[t]       + b[t];
    yr[t + 256] = d1 * rs * g[t + 256] + b[t + 256];
}

// ---------------- self-attention: one block per (q-row, head) ----------------
__global__ void sa_attn_kernel(const float* __restrict__ qkv, float* __restrict__ o) {
    int m = blockIdx.x;          // b*1024 + q
    int h = blockIdx.y;
    int b = m >> 10;
    int t = threadIdx.x;         // 256
    __shared__ float qs[64];
    __shared__ float sc[1024];
    __shared__ float red[256];
    __shared__ float ored[4][64];
    if (t < 64) qs[t] = qkv[(long)m * 1536 + h * 64 + t];
    __syncthreads();
    float lm = -1e30f;
    #pragma unroll
    for (int j = 0; j < 4; j++) {
        int kidx = t + j * 256;
        const float* kr = qkv + ((long)(b * 1024 + kidx)) * 1536 + 512 + h * 64;
        float s = 0.f;
        #pragma unroll 8
        for (int d = 0; d < 64; d++) s += qs[d] * kr[d];
        s *= 0.125f;             // HD^-0.5
        sc[kidx] = s;
        lm = fmaxf(lm, s);
    }
    red[t] = lm; __syncthreads();
    for (int s = 128; s > 0; s >>= 1) { if (t < s) red[t] = fmaxf(red[t], red[t + s]); __syncthreads(); }
    float mx = red[0]; __syncthreads();
    float ls = 0.f;
    #pragma unroll
    for (int j = 0; j < 4; j++) {
        int kidx = t + j * 256;
        float e = __expf(sc[kidx] - mx);
        sc[kidx] = e; ls += e;
    }
    red[t] = ls; __syncthreads();
    for (int s = 128; s > 0; s >>= 1) { if (t < s) red[t] += red[t + s]; __syncthreads(); }
    float inv = 1.f / red[0];
    __syncthreads();
    int d = t & 63, ch = t >> 6;
    float acc = 0.f;
    for (int kidx = ch * 256; kidx < (ch + 1) * 256; kidx++)
        acc += sc[kidx] * qkv[((long)(b * 1024 + kidx)) * 1536 + 1024 + h * 64 + d];
    ored[ch][d] = acc; __syncthreads();
    if (t < 64) {
        float v = (ored[0][t] + ored[1][t] + ored[2][t] + ored[3][t]) * inv;
        o[(long)m * DIMC + h * 64 + t] = v;
    }
}

// ---------------- cross-attention (77 keys): block=128 per (q-row, head) ----------------
__global__ void ca_attn_kernel(const float* __restrict__ q, const float* __restrict__ kv,
                               float* __restrict__ o) {
    int m = blockIdx.x; int h = blockIdx.y; int b = m >> 10;
    int t = threadIdx.x;    // 128
    __shared__ float qs[64];
    __shared__ float sc[77];
    __shared__ float red[128];
    if (t < 64) qs[t] = q[(long)m * DIMC + h * 64 + t];
    __syncthreads();
    float lm = -1e30f;
    if (t < 77) {
        const float* kr = kv + ((long)(b * 77 + t)) * 1024 + h * 64;
        float s = 0.f;
        #pragma unroll 8
        for (int d = 0; d < 64; d++) s += qs[d] * kr[d];
        s *= 0.125f;
        sc[t] = s; lm = s;
    }
    red[t] = lm; __syncthreads();
    for (int s = 64; s > 0; s >>= 1) { if (t < s) red[t] = fmaxf(red[t], red[t + s]); __syncthreads(); }
    float mx = red[0]; __syncthreads();
    float ls = 0.f;
    if (t < 77) { float e = __expf(sc[t] - mx); sc[t] = e; ls = e; }
    red[t] = ls; __syncthreads();
    for (int s = 64; s > 0; s >>= 1) { if (t < s) red[t] += red[t + s]; __syncthreads(); }
    float inv = 1.f / red[0];
    __syncthreads();
    if (t < 64) {
        float acc = 0.f;
        for (int kk = 0; kk < 77; kk++)
            acc += sc[kk] * kv[((long)(b * 77 + kk)) * 1024 + 512 + h * 64 + t];
        o[(long)m * DIMC + h * 64 + t] = acc * inv;
    }
}

// ---------------- router text part ----------------
__global__ void textpart_kernel(const float* __restrict__ w, const float* __restrict__ r_text_mu,
                                const float* __restrict__ r_comb_mu, float* __restrict__ tp) {
    __shared__ float tw[4][128];
    int t = threadIdx.x;   // 256
    for (int j = 0; j < 2; j++) {
        int idx = t + j * 256; int b = idx >> 7, c = idx & 127;
        const float* wr = w + (long)b * LATC;
        float s = 0.f;
        for (int k = 0; k < LATC; k++) s += wr[k] * r_text_mu[(long)k * 128 + c];
        tw[b][c] = s;
    }
    __syncthreads();
    if (t < 32) {
        int b = t >> 3, e = t & 7;
        float s = 0.f;
        for (int c = 0; c < 128; c++) s += tw[b][c] * r_comb_mu[(long)(128 + c) * 8 + e];
        tp[t] = s;
    }
}

// ---------------- MoE meta: init, route(+count), offsets, scatter ----------------
__global__ void moe_init_kernel(int* __restrict__ cnt, int* __restrict__ perm) {
    int g = blockIdx.x * blockDim.x + threadIdx.x;
    if (g < MAXTILES * 64) perm[g] = -1;
    if (g < NE) cnt[g] = 0;
}

__global__ void route_kernel(const float* __restrict__ feat, const float* __restrict__ tp,
                             const float* __restrict__ r_comb_mu, const float* __restrict__ r_temp,
                             float* __restrict__ onehot, int* __restrict__ idx, int* __restrict__ cnt) {
    int n = blockIdx.x * blockDim.x + threadIdx.x;
    if (n >= NTOK) return;
    int b = n >> 10;
    float tmp = fmaxf(r_temp[0], 0.1f);
    float invt = 1.f / tmp;
    const float* fr = feat + (long)n * 128;
    float lg[8];
    for (int e = 0; e < 8; e++) {
        float s = 0.f;
        for (int c = 0; c < 128; c++) s += fr[c] * r_comb_mu[(long)c * 8 + e];
        lg[e] = (s + tp[b * 8 + e]) * invt;
    }
    float best = lg[0]; int bi = 0;
    for (int e = 1; e < 8; e++) { if (lg[e] > best) { best = lg[e]; bi = e; } }
    for (int e = 0; e < 8; e++) onehot[(long)n * 8 + e] = (e == bi) ? 1.f : 0.f;
    idx[n] = bi;
    atomicAdd(&cnt[bi], 1);
}

__global__ void offsets_kernel(const int* __restrict__ cnt, int* __restrict__ cursor,
                               int* __restrict__ ntiles, int* __restrict__ table) {
    if (threadIdx.x != 0) return;
    int po = 0, nt = 0;
    for (int e = 0; e < NE; e++) {
        cursor[e] = po;
        int tiles = (cnt[e] + 63) >> 6;
        for (int j = 0; j < tiles; j++) { table[2 * nt] = e; table[2 * nt + 1] = po + j * 64; nt++; }
        po += tiles * 64;
    }
    ntiles[0] = nt;
}

__global__ void scatter_kernel(const int* __restrict__ idx, int* __restrict__ cursor,
                               int* __restrict__ perm) {
    int n = blockIdx.x * blockDim.x + threadIdx.x;
    if (n >= NTOK) return;
    int e = idx[n];
    int pos = atomicAdd(&cursor[e], 1);
    perm[pos] = n;
}

// -------- MoE GEMM1: hid[tok, :] = gelu(xn[tok, :] @ w1[e] + b1[e]) --------
__global__ void moe_gemm1_kernel(const float* __restrict__ xn, const float* __restrict__ e_w1,
                                 const float* __restrict__ e_b1,
                                 const int* __restrict__ table, const int* __restrict__ ntiles,
                                 const int* __restrict__ perm, float* __restrict__ hid) {
    int by = blockIdx.y;
    if (by >= ntiles[0]) return;
    int e = table[2 * by], row0 = table[2 * by + 1];
    int bn = blockIdx.x * 64;
    __shared__ float As[16][68];
    __shared__ float Bs[16][68];
    __shared__ int rows[64];
    int t = threadIdx.x;
    if (t < 64) rows[t] = perm[row0 + t];
    __syncthreads();
    const float* W = e_w1 + (long)e * DIMC * HIDC;   // [DIMC, HIDC] k-major
    int tx = t & 15, ty = t >> 4;
    float acc[4][4] = {};
    for (int k0 = 0; k0 < DIMC; k0 += 16) {
        #pragma unroll
        for (int j = 0; j < 4; j++) {
            int ea = t + j * 256;
            int mi = ea >> 4, ki = ea & 15;              // A: 64 rows x 16 k, k fastest
            int r = rows[mi];
            As[ki][mi] = (r >= 0) ? xn[(long)r * DIMC + k0 + ki] : 0.f;
            int kb = ea >> 6, nb = ea & 63;              // B: 16 k x 64 n, n fastest (coalesced)
            Bs[kb][nb] = W[(long)(k0 + kb) * HIDC + bn + nb];
        }
        __syncthreads();
        #pragma unroll
        for (int kk = 0; kk < 16; kk++) {
            float a[4], b[4];
            #pragma unroll
            for (int i = 0; i < 4; i++) { a[i] = As[kk][ty * 4 + i]; b[i] = Bs[kk][tx * 4 + i]; }
            #pragma unroll
            for (int i = 0; i < 4; i++)
            #pragma unroll
            for (int j2 = 0; j2 < 4; j2++) acc[i][j2] += a[i] * b[j2];
        }
        __syncthreads();
    }
    #pragma unroll
    for (int i = 0; i < 4; i++) {
        int r = rows[ty * 4 + i];
        if (r < 0) continue;
        #pragma unroll
        for (int j2 = 0; j2 < 4; j2++) {
            int n = bn + tx * 4 + j2;
            float v = acc[i][j2] + e_b1[(long)e * HIDC + n];
            hid[(long)r * HIDC + n] = 0.5f * v * (1.f + erff(v * 0.70710678f));
        }
    }
}

// -------- MoE GEMM2: x_flat[tok, :] += hid[tok, :] @ w2[e] + b2[e] --------
__global__ void moe_gemm2_kernel(const float* __restrict__ hid, const float* __restrict__ e_w2,
                                 const float* __restrict__ e_b2,
                                 const int* __restrict__ table, const int* __restrict__ ntiles,
                                 const int* __restrict__ perm, float* __restrict__ x_flat) {
    int by = blockIdx.y;
    if (by >= ntiles[0]) return;
    int e = table[2 * by], row0 = table[2 * by + 1];
    int bn = blockIdx.x * 64;
    __shared__ float As[16][68];
    __shared__ float Bs[16][68];
    __shared__ int rows[64];
    int t = threadIdx.x;
    if (t < 64) rows[t] = perm[row0 + t];
    __syncthreads();
    const float* W = e_w2 + (long)e * HIDC * DIMC;   // [HIDC, DIMC] k-major
    int tx = t & 15, ty = t >> 4;
    float acc[4][4] = {};
    for (int k0 = 0; k0 < HIDC; k0 += 16) {
        #pragma unroll
        for (int j = 0; j < 4; j++) {
            int ea = t + j * 256;
            int mi = ea >> 4, ki = ea & 15;
            int r = rows[mi];
            As[ki][mi] = (r >= 0) ? hid[(long)r * HIDC + k0 + ki] : 0.f;
            int kb = ea >> 6, nb = ea & 63;
            Bs[kb][nb] = W[(long)(k0 + kb) * DIMC + bn + nb];
        }
        __syncthreads();
        #pragma unroll
        for (int kk = 0; kk < 16; kk++) {
            float a[4], b[4];
            #pragma unroll
            for (int i = 0; i < 4; i++) { a[i] = As[kk][ty * 4 + i]; b[i] = Bs[kk][tx * 4 + i]; }
            #pragma unroll
            for (int i = 0; i < 4; i++)
            #pragma unroll
            for (int j2 = 0; j2 < 4; j2++) acc[i][j2] += a[i] * b[j2];
        }
        __syncthreads();
    }
    #pragma unroll
    for (int i = 0; i < 4; i++) {
        int r = rows[ty * 4 + i];
        if (r < 0) continue;
        #pragma unroll
        for (int j2 = 0; j2 < 4; j2++) {
            int n = bn + tx * 4 + j2;
            float v = acc[i][j2] + e_b2[(long)e * DIMC + n];
            x_flat[(long)r * DIMC + n] += v;
        }
    }
}

extern "C" void kernel_launch(void* const* d_in, const int* in_sizes, int n_in,
                              void* d_out, int out_size, void* d_ws, size_t ws_size,
                              hipStream_t stream) {
    const float* x        = (const float*)d_in[0];
    const float* w        = (const float*)d_in[1];
    const float* text     = (const float*)d_in[2];
    const float* pin_w    = (const float*)d_in[3];
    const float* pin_mw   = (const float*)d_in[4];
    const float* pin_mb   = (const float*)d_in[5];
    const float* pout_w   = (const float*)d_in[6];
    const float* pout_mw  = (const float*)d_in[7];
    const float* pout_mb  = (const float*)d_in[8];
    const float* ln1g     = (const float*)d_in[9];
    const float* ln1b     = (const float*)d_in[10];
    const float* ln2g     = (const float*)d_in[11];
    const float* ln2b     = (const float*)d_in[12];
    const float* ln3g     = (const float*)d_in[13];
    const float* ln3b     = (const float*)d_in[14];
    const float* sa_in_w  = (const float*)d_in[15];
    const float* sa_in_b  = (const float*)d_in[16];
    const float* sa_out_w = (const float*)d_in[17];
    const float* sa_out_b = (const float*)d_in[18];
    const float* ca_in_w  = (const float*)d_in[19];
    const float* ca_in_b  = (const float*)d_in[20];
    const float* ca_out_w = (const float*)d_in[21];
    const float* ca_out_b = (const float*)d_in[22];
    const float* r_feat   = (const float*)d_in[23];
    const float* r_text   = (const float*)d_in[24];
    const float* r_comb   = (const float*)d_in[25];
    const float* r_temp   = (const float*)d_in[26];
    const float* e_w1     = (const float*)d_in[27];
    const float* e_b1     = (const float*)d_in[28];
    const float* e_w2     = (const float*)d_in[29];
    const float* e_b2     = (const float*)d_in[30];

    float* out    = (float*)d_out;               // [B, DIM, H, W] = 2097152
    float* onehot = out + (long)BB * DIMC * HWX; // [4096, 8]

    float* ws = (float*)d_ws;
    float* style_in  = ws;                         // 2048
    float* style_out = style_in + 2048;            // 2048
    float* wtmod     = style_out + 2048;           // 1048576 (reused in/out)
    float* x_flat    = wtmod + 1048576;            // 2097152  [B, HW, DIM]
    float* xn        = x_flat + 2097152;           // 2097152
    float* qkv       = xn + 2097152;               // 6291456  (SA qkv; CA q; later reused as hid)
    float* obuf      = qkv + 6291456;              // 2097152  (contiguous with qkv)
    float* kvtext    = obuf + 2097152;             // 315392   [B*77, 1024]
    float* feat      = kvtext + 315392;            // 524288   [4096, 128]
    float* tp        = feat + 524288;              // 32
    int*   idx       = (int*)(tp + 32);            // 4096
    int*   cnt       = idx + 4096;                 // 8
    int*   cursor    = cnt + 8;                    // 8
    int*   ntiles    = cursor + 8;                 // 4
    int*   table     = ntiles + 4;                 // 144
    int*   perm      = table + 144;                // 4608
    float* hid       = qkv;                        // reuse qkv+obuf: 8388608 = 4096*2048

    auto gemm = [&](const float* A, const float* Bm, const float* bias, const float* resid, float* C,
                    int M, int N, int K,
                    long as_m, long as_k, long a_bat,
                    long bs_n, long bs_k, long b_bat,
                    long cs_m, long cs_n, long c_bat, int nbat) {
        dim3 g((N + 63) / 64, (M + 63) / 64, nbat);
        hipLaunchKernelGGL(gemm_kernel, g, dim3(256), 0, stream,
                           A, Bm, bias, resid, C, M, N, K,
                           as_m, as_k, a_bat, bs_n, bs_k, b_bat, cs_m, cs_n, c_bat);
    };

    // ---- modconv in ----
    hipLaunchKernelGGL(style_kernel, dim3(8), dim3(256), 0, stream, w, pin_mw, pin_mb, style_in);
    hipLaunchKernelGGL(wtmod_kernel, dim3(BB * DIMC), dim3(256), 0, stream, pin_w, style_in, wtmod);
    gemm(x, wtmod, nullptr, nullptr, x_flat,
         HWX, DIMC, DIMC,
         1, HWX, (long)DIMC * HWX,
         DIMC, 1, (long)DIMC * DIMC,
         DIMC, 1, (long)HWX * DIMC, BB);

    // ---- LN1 + self-attention ----
    hipLaunchKernelGGL(ln_kernel, dim3(NTOK), dim3(256), 0, stream, x_flat, ln1g, ln1b, xn);
    gemm(xn, sa_in_w, sa_in_b, nullptr, qkv,
         NTOK, 1536, DIMC,
         DIMC, 1, 0, DIMC, 1, 0, 1536, 1, 0, 1);
    hipLaunchKernelGGL(sa_attn_kernel, dim3(NTOK, HEADS), dim3(256), 0, stream, qkv, obuf);
    gemm(obuf, sa_out_w, sa_out_b, x_flat, x_flat,
         NTOK, DIMC, DIMC,
         DIMC, 1, 0, DIMC, 1, 0, DIMC, 1, 0, 1);

    // ---- LN2 + cross-attention ----
    hipLaunchKernelGGL(ln_kernel, dim3(NTOK), dim3(256), 0, stream, x_flat, ln2g, ln2b, xn);
    gemm(xn, ca_in_w, ca_in_b, nullptr, qkv,
         NTOK, DIMC, DIMC,
         DIMC, 1, 0, DIMC, 1, 0, DIMC, 1, 0, 1);
    gemm(text, ca_in_w + (long)DIMC * DIMC, ca_in_b + DIMC, nullptr, kvtext,
         BB * TXT, 1024, DIMC,
         DIMC, 1, 0, DIMC, 1, 0, 1024, 1, 0, 1);
    hipLaunchKernelGGL(ca_attn_kernel, dim3(NTOK, HEADS), dim3(128), 0, stream, qkv, kvtext, obuf);
    gemm(obuf, ca_out_w, ca_out_b, x_flat, x_flat,
         NTOK, DIMC, DIMC,
         DIMC, 1, 0, DIMC, 1, 0, DIMC, 1, 0, 1);

    // ---- LN3 + router ----
    hipLaunchKernelGGL(ln_kernel, dim3(NTOK), dim3(256), 0, stream, x_flat, ln3g, ln3b, xn);
    gemm(xn, r_feat, nullptr, nullptr, feat,
         NTOK, 128, DIMC,
         DIMC, 1, 0, 1, 128, 0, 128, 1, 0, 1);
    hipLaunchKernelGGL(textpart_kernel, dim3(1), dim3(256), 0, stream, w, r_text, r_comb, tp);
    hipLaunchKernelGGL(moe_init_kernel, dim3(18), dim3(256), 0, stream, cnt, perm);
    hipLaunchKernelGGL(route_kernel, dim3(16), dim3(256), 0, stream, feat, tp, r_comb, r_temp, onehot, idx, cnt);
    hipLaunchKernelGGL(offsets_kernel, dim3(1), dim3(64), 0, stream, cnt, cursor, ntiles, table);
    hipLaunchKernelGGL(scatter_kernel, dim3(16), dim3(256), 0, stream, idx, cursor, perm);

    // ---- MoE grouped GEMMs (only the selected expert per token) ----
    hipLaunchKernelGGL(moe_gemm1_kernel, dim3(HIDC / 64, MAXTILES), dim3(256), 0, stream,
                       xn, e_w1, e_b1, table, ntiles, perm, hid);
    hipLaunchKernelGGL(moe_gemm2_kernel, dim3(DIMC / 64, MAXTILES), dim3(256), 0, stream,
                       hid, e_w2, e_b2, table, ntiles, perm, x_flat);

    // ---- modconv out -> d_out ----
    hipLaunchKernelGGL(style_kernel, dim3(8), dim3(256), 0, stream, w, pout_mw, pout_mb, style_out);
    hipLaunchKernelGGL(wtmod_kernel, dim3(BB * DIMC), dim3(256), 0, stream, pout_w, style_out, wtmod);
    gemm(x_flat, wtmod, nullptr, nullptr, out,
         HWX, DIMC, DIMC,
         DIMC, 1, (long)HWX * DIMC,
         DIMC, 1, (long)DIMC * DIMC,
         1, HWX, (long)DIMC * HWX, BB);
}

// Round 3
// 1650.159 us; speedup vs baseline: 3.3544x; 1.7149x over previous
//
#include <hip/hip_runtime.h>
#include <hip/hip_bf16.h>
#include <math.h>

#define DIMC 512
#define HEADS 8
#define HD 64
#define BB 4
#define HWX 1024          // H*W
#define TXT 77
#define LATC 512
#define NE 8
#define HIDC 2048
#define NTOK 4096         // B*H*W
#define MAXTILES 72       // sum(ceil(cnt_e/64)) <= 4096/64 + 8 = 72

// ---------------- style = w @ mod_w.T + mod_b  ([B,DIM]) ----------------
__global__ void style_kernel(const float* __restrict__ w, const float* __restrict__ mod_w,
                             const float* __restrict__ mod_b, float* __restrict__ style) {
    int t = blockIdx.x * blockDim.x + threadIdx.x;
    if (t >= BB * DIMC) return;
    int b = t / DIMC, i = t % DIMC;
    const float* wr = w + (long)b * LATC;
    const float* mr = mod_w + (long)i * LATC;
    float s = 0.f;
    #pragma unroll 8
    for (int l = 0; l < LATC; l++) s += wr[l] * mr[l];
    style[t] = s + mod_b[i];
}

// ------- wtmod[b,o,i] = weight[o,i]*style[b,i]*rsqrt(sum_i(.)^2+1e-8) -------
__global__ void wtmod_kernel(const float* __restrict__ weight, const float* __restrict__ style,
                             float* __restrict__ wtmod) {
    int bo = blockIdx.x;            // b*DIM + o
    int b = bo / DIMC, o = bo % DIMC;
    const float* wr = weight + (long)o * DIMC;
    const float* sr = style + (long)b * DIMC;
    int t = threadIdx.x;            // 256
    float vals[2]; float part = 0.f;
    for (int j = 0; j < 2; j++) {
        int i = t + j * 256;
        float v = wr[i] * sr[i];
        vals[j] = v; part += v * v;
    }
    __shared__ float red[256];
    red[t] = part; __syncthreads();
    for (int s = 128; s > 0; s >>= 1) { if (t < s) red[t] += red[t + s]; __syncthreads(); }
    float d = rsqrtf(red[0] + 1e-8f);
    float* outp = wtmod + (long)bo * DIMC;
    for (int j = 0; j < 2; j++) { int i = t + j * 256; outp[i] = vals[j] * d; }
}

// ---- generic strided fp32 GEMM: C[m,n] = sum_k A(m,k)*B(n,k) (+bias)(+resid) ----
// 64x64 tile, BK=16, 256 threads, 4x4 per thread. K must be a multiple of 16.
__global__ void gemm_kernel(const float* __restrict__ A, const float* __restrict__ Bm,
                            const float* __restrict__ bias, const float* __restrict__ resid,
                            float* __restrict__ C,
                            int M, int N, int K,
                            long as_m, long as_k, long a_bat,
                            long bs_n, long bs_k, long b_bat,
                            long cs_m, long cs_n, long c_bat) {
    __shared__ float As[16][68];
    __shared__ float Bs[16][68];
    int bm = blockIdx.y * 64, bn = blockIdx.x * 64, bat = blockIdx.z;
    A += (long)bat * a_bat; Bm += (long)bat * b_bat; C += (long)bat * c_bat;
    const float* R = resid ? resid + (long)bat * c_bat : nullptr;
    int t = threadIdx.x;
    int tx = t & 15, ty = t >> 4;
    float acc[4][4] = {};
    for (int k0 = 0; k0 < K; k0 += 16) {
        #pragma unroll
        for (int j = 0; j < 4; j++) {
            int e = t + j * 256;               // 1024 elems: 64 rows x 16 k
            int mi = e >> 4, ki = e & 15;
            int m = bm + mi, k = k0 + ki;
            As[ki][mi] = (m < M) ? A[(long)m * as_m + (long)k * as_k] : 0.f;
            int n = bn + mi;
            Bs[ki][mi] = (n < N) ? Bm[(long)n * bs_n + (long)k * bs_k] : 0.f;
        }
        __syncthreads();
        #pragma unroll
        for (int kk = 0; kk < 16; kk++) {
            float a[4], b[4];
            #pragma unroll
            for (int i = 0; i < 4; i++) { a[i] = As[kk][ty * 4 + i]; b[i] = Bs[kk][tx * 4 + i]; }
            #pragma unroll
            for (int i = 0; i < 4; i++)
            #pragma unroll
            for (int j2 = 0; j2 < 4; j2++) acc[i][j2] += a[i] * b[j2];
        }
        __syncthreads();
    }
    #pragma unroll
    for (int i = 0; i < 4; i++) {
        int m = bm + ty * 4 + i;
        if (m >= M) continue;
        #pragma unroll
        for (int j2 = 0; j2 < 4; j2++) {
            int n = bn + tx * 4 + j2;
            if (n >= N) continue;
            float v = acc[i][j2];
            if (bias) v += bias[n];
            long coff = (long)m * cs_m + (long)n * cs_n;
            if (R) v += R[coff];
            C[coff] = v;
        }
    }
}

// ---------------- LayerNorm over DIM=512, block=256, one block per token ----------------
__global__ void ln_kernel(const float* __restrict__ x, const float* __restrict__ g,
                          const float* __restrict__ b, float* __restrict__ y) {
    int tok = blockIdx.x;
    int t = threadIdx.x;
    const float* xr = x + (long)tok * DIMC;
    float v0 = xr[t], v1 = xr[t + 256];
    __shared__ float red[256];
    red[t] = v0 + v1; __syncthreads();
    for (int s = 128; s > 0; s >>= 1) { if (t < s) red[t] += red[t + s]; __syncthreads(); }
    float mu = red[0] * (1.f / DIMC);
    __syncthreads();
    float d0 = v0 - mu, d1 = v1 - mu;
    red[t] = d0 * d0 + d1 * d1; __syncthreads();
    for (int s = 128; s > 0; s >>= 1) { if (t < s) red[t] += red[t + s]; __syncthreads(); }
    float rs = rsqrtf(red[0] * (1.f / DIMC) + 1e-5f);
    float* yr = y + (long)tok * DIMC;
    yr[t]       = d0 * rs * g[t]       + b[t];
    yr[t + 256] = d1 * rs * g[t + 256] + b[t + 256];
}

// ---- flash self-attention: block per (q-tile 64, head, batch), 256 threads ----
// S=1024, HD=64. Q pre-scaled by 0.125. Online softmax. fp32 throughout.
__global__ __launch_bounds__(256) void sa_flash_kernel(const float* __restrict__ qkv,
                                                       float* __restrict__ o) {
    int qt = blockIdx.x, h = blockIdx.y, b = blockIdx.z;
    __shared__ float Qs[64][68];   // [d][q]  (transposed)
    __shared__ float KVs[64][68];  // K: [d][n] ; V: [n][d]
    __shared__ float Pt[64][68];   // [n][m]  (P transposed)
    int t = threadIdx.x;
    int tx = t & 15, ty = t >> 4;
    long qbase = ((long)(b * 1024 + qt * 64)) * 1536 + h * 64;
    #pragma unroll
    for (int j = 0; j < 16; j++) {
        int e = t + j * 256;
        int r = e >> 6, d = e & 63;
        Qs[d][r] = qkv[qbase + (long)r * 1536 + d] * 0.125f;
    }
    float m_i[4], l_i[4], o_acc[4][4] = {};
    #pragma unroll
    for (int i = 0; i < 4; i++) { m_i[i] = -1e30f; l_i[i] = 0.f; }
    long kbase = ((long)b * 1024) * 1536 + 512 + h * 64;
    long vbase = kbase + 512;
    for (int kt = 0; kt < 16; kt++) {
        __syncthreads();                       // prev PV done reading KVs (and Qs ready)
        #pragma unroll
        for (int j = 0; j < 16; j++) {
            int e = t + j * 256;
            int r = e >> 6, d = e & 63;
            KVs[d][r] = qkv[kbase + (long)(kt * 64 + r) * 1536 + d];   // K transposed
        }
        __syncthreads();
        // ---- S = Q @ K^T (64x64x64) ----
        float s[4][4] = {};
        #pragma unroll
        for (int kk = 0; kk < 64; kk++) {
            float a[4], bv[4];
            #pragma unroll
            for (int i = 0; i < 4; i++) { a[i] = Qs[kk][ty * 4 + i]; bv[i] = KVs[kk][tx * 4 + i]; }
            #pragma unroll
            for (int i = 0; i < 4; i++)
            #pragma unroll
            for (int j2 = 0; j2 < 4; j2++) s[i][j2] += a[i] * bv[j2];
        }
        // ---- online softmax (rows distributed: row = ty*4+i, 16 lanes share a row) ----
        float sc_i[4];
        #pragma unroll
        for (int i = 0; i < 4; i++) {
            float mx = fmaxf(fmaxf(s[i][0], s[i][1]), fmaxf(s[i][2], s[i][3]));
            mx = fmaxf(mx, __shfl_xor(mx, 1));
            mx = fmaxf(mx, __shfl_xor(mx, 2));
            mx = fmaxf(mx, __shfl_xor(mx, 4));
            mx = fmaxf(mx, __shfl_xor(mx, 8));
            float mn = fmaxf(m_i[i], mx);
            sc_i[i] = __expf(m_i[i] - mn);
            m_i[i] = mn;
            float rs = 0.f;
            #pragma unroll
            for (int j2 = 0; j2 < 4; j2++) { s[i][j2] = __expf(s[i][j2] - mn); rs += s[i][j2]; }
            rs += __shfl_xor(rs, 1);
            rs += __shfl_xor(rs, 2);
            rs += __shfl_xor(rs, 4);
            rs += __shfl_xor(rs, 8);
            l_i[i] = l_i[i] * sc_i[i] + rs;
        }
        __syncthreads();                       // all lanes done reading K from KVs
        // ---- stage P^T, load V ----
        #pragma unroll
        for (int i = 0; i < 4; i++)
        #pragma unroll
        for (int j2 = 0; j2 < 4; j2++) Pt[tx * 4 + j2][ty * 4 + i] = s[i][j2];
        #pragma unroll
        for (int j = 0; j < 16; j++) {
            int e = t + j * 256;
            int r = e >> 6, d = e & 63;
            KVs[r][d] = qkv[vbase + (long)(kt * 64 + r) * 1536 + d];   // V natural [n][d]
        }
        __syncthreads();
        // ---- O = O*scale + P @ V ----
        #pragma unroll
        for (int i = 0; i < 4; i++)
        #pragma unroll
        for (int j2 = 0; j2 < 4; j2++) o_acc[i][j2] *= sc_i[i];
        #pragma unroll
        for (int kk = 0; kk < 64; kk++) {
            float a[4], bv[4];
            #pragma unroll
            for (int i = 0; i < 4; i++) { a[i] = Pt[kk][ty * 4 + i]; bv[i] = KVs[kk][tx * 4 + i]; }
            #pragma unroll
            for (int i = 0; i < 4; i++)
            #pragma unroll
            for (int j2 = 0; j2 < 4; j2++) o_acc[i][j2] += a[i] * bv[j2];
        }
    }
    #pragma unroll
    for (int i = 0; i < 4; i++) {
        float inv = 1.f / l_i[i];
        long m = b * 1024 + qt * 64 + ty * 4 + i;
        #pragma unroll
        for (int j2 = 0; j2 < 4; j2++)
            o[m * DIMC + h * 64 + tx * 4 + j2] = o_acc[i][j2] * inv;
    }
}

// ---------------- cross-attention (77 keys): block=128 per (q-row, head) ----------------
__global__ void ca_attn_kernel(const float* __restrict__ q, const float* __restrict__ kv,
                               float* __restrict__ o) {
    int m = blockIdx.x; int h = blockIdx.y; int b = m >> 10;
    int t = threadIdx.x;    // 128
    __shared__ float qs[64];
    __shared__ float sc[77];
    __shared__ float red[128];
    if (t < 64) qs[t] = q[(long)m * DIMC + h * 64 + t];
    __syncthreads();
    float lm = -1e30f;
    if (t < 77) {
        const float* kr = kv + ((long)(b * 77 + t)) * 1024 + h * 64;
        float s = 0.f;
        #pragma unroll 8
        for (int d = 0; d < 64; d++) s += qs[d] * kr[d];
        s *= 0.125f;
        sc[t] = s; lm = s;
    }
    red[t] = lm; __syncthreads();
    for (int s = 64; s > 0; s >>= 1) { if (t < s) red[t] = fmaxf(red[t], red[t + s]); __syncthreads(); }
    float mx = red[0]; __syncthreads();
    float ls = 0.f;
    if (t < 77) { float e = __expf(sc[t] - mx); sc[t] = e; ls = e; }
    red[t] = ls; __syncthreads();
    for (int s = 64; s > 0; s >>= 1) { if (t < s) red[t] += red[t + s]; __syncthreads(); }
    float inv = 1.f / red[0];
    __syncthreads();
    if (t < 64) {
        float acc = 0.f;
        for (int kk = 0; kk < 77; kk++)
            acc += sc[kk] * kv[((long)(b * 77 + kk)) * 1024 + 512 + h * 64 + t];
        o[(long)m * DIMC + h * 64 + t] = acc * inv;
    }
}

// ---------------- router text part ----------------
__global__ void textpart_kernel(const float* __restrict__ w, const float* __restrict__ r_text_mu,
                                const float* __restrict__ r_comb_mu, float* __restrict__ tp) {
    __shared__ float tw[4][128];
    int t = threadIdx.x;   // 256
    for (int j = 0; j < 2; j++) {
        int idx = t + j * 256; int b = idx >> 7, c = idx & 127;
        const float* wr = w + (long)b * LATC;
        float s = 0.f;
        for (int k = 0; k < LATC; k++) s += wr[k] * r_text_mu[(long)k * 128 + c];
        tw[b][c] = s;
    }
    __syncthreads();
    if (t < 32) {
        int b = t >> 3, e = t & 7;
        float s = 0.f;
        for (int c = 0; c < 128; c++) s += tw[b][c] * r_comb_mu[(long)(128 + c) * 8 + e];
        tp[t] = s;
    }
}

// ---------------- MoE meta: init, route(+count), offsets, scatter ----------------
__global__ void moe_init_kernel(int* __restrict__ cnt, int* __restrict__ perm) {
    int g = blockIdx.x * blockDim.x + threadIdx.x;
    if (g < MAXTILES * 64) perm[g] = -1;
    if (g < NE) cnt[g] = 0;
}

__global__ void route_kernel(const float* __restrict__ feat, const float* __restrict__ tp,
                             const float* __restrict__ r_comb_mu, const float* __restrict__ r_temp,
                             float* __restrict__ onehot, int* __restrict__ idx, int* __restrict__ cnt) {
    int n = blockIdx.x * blockDim.x + threadIdx.x;
    if (n >= NTOK) return;
    int b = n >> 10;
    float tmp = fmaxf(r_temp[0], 0.1f);
    float invt = 1.f / tmp;
    const float* fr = feat + (long)n * 128;
    float lg[8];
    for (int e = 0; e < 8; e++) {
        float s = 0.f;
        for (int c = 0; c < 128; c++) s += fr[c] * r_comb_mu[(long)c * 8 + e];
        lg[e] = (s + tp[b * 8 + e]) * invt;
    }
    float best = lg[0]; int bi = 0;
    for (int e = 1; e < 8; e++) { if (lg[e] > best) { best = lg[e]; bi = e; } }
    for (int e = 0; e < 8; e++) onehot[(long)n * 8 + e] = (e == bi) ? 1.f : 0.f;
    idx[n] = bi;
    atomicAdd(&cnt[bi], 1);
}

__global__ void offsets_kernel(const int* __restrict__ cnt, int* __restrict__ cursor,
                               int* __restrict__ ntiles, int* __restrict__ table) {
    if (threadIdx.x != 0) return;
    int po = 0, nt = 0;
    for (int e = 0; e < NE; e++) {
        cursor[e] = po;
        int tiles = (cnt[e] + 63) >> 6;
        for (int j = 0; j < tiles; j++) { table[2 * nt] = e; table[2 * nt + 1] = po + j * 64; nt++; }
        po += tiles * 64;
    }
    ntiles[0] = nt;
}

__global__ void scatter_kernel(const int* __restrict__ idx, int* __restrict__ cursor,
                               int* __restrict__ perm) {
    int n = blockIdx.x * blockDim.x + threadIdx.x;
    if (n >= NTOK) return;
    int e = idx[n];
    int pos = atomicAdd(&cursor[e], 1);
    perm[pos] = n;
}

// -------- MoE GEMM1: hid[tok, :] = gelu(xn[tok, :] @ w1[e] + b1[e]) --------
__global__ void moe_gemm1_kernel(const float* __restrict__ xn, const float* __restrict__ e_w1,
                                 const float* __restrict__ e_b1,
                                 const int* __restrict__ table, const int* __restrict__ ntiles,
                                 const int* __restrict__ perm, float* __restrict__ hid) {
    int by = blockIdx.y;
    if (by >= ntiles[0]) return;
    int e = table[2 * by], row0 = table[2 * by + 1];
    int bn = blockIdx.x * 64;
    __shared__ float As[16][68];
    __shared__ float Bs[16][68];
    __shared__ int rows[64];
    int t = threadIdx.x;
    if (t < 64) rows[t] = perm[row0 + t];
    __syncthreads();
    const float* W = e_w1 + (long)e * DIMC * HIDC;   // [DIMC, HIDC] k-major
    int tx = t & 15, ty = t >> 4;
    float acc[4][4] = {};
    for (int k0 = 0; k0 < DIMC; k0 += 16) {
        #pragma unroll
        for (int j = 0; j < 4; j++) {
            int ea = t + j * 256;
            int mi = ea >> 4, ki = ea & 15;              // A: 64 rows x 16 k, k fastest
            int r = rows[mi];
            As[ki][mi] = (r >= 0) ? xn[(long)r * DIMC + k0 + ki] : 0.f;
            int kb = ea >> 6, nb = ea & 63;              // B: 16 k x 64 n, n fastest (coalesced)
            Bs[kb][nb] = W[(long)(k0 + kb) * HIDC + bn + nb];
        }
        __syncthreads();
        #pragma unroll
        for (int kk = 0; kk < 16; kk++) {
            float a[4], b[4];
            #pragma unroll
            for (int i = 0; i < 4; i++) { a[i] = As[kk][ty * 4 + i]; b[i] = Bs[kk][tx * 4 + i]; }
            #pragma unroll
            for (int i = 0; i < 4; i++)
            #pragma unroll
            for (int j2 = 0; j2 < 4; j2++) acc[i][j2] += a[i] * b[j2];
        }
        __syncthreads();
    }
    #pragma unroll
    for (int i = 0; i < 4; i++) {
        int r = rows[ty * 4 + i];
        if (r < 0) continue;
        #pragma unroll
        for (int j2 = 0; j2 < 4; j2++) {
            int n = bn + tx * 4 + j2;
            float v = acc[i][j2] + e_b1[(long)e * HIDC + n];
            hid[(long)r * HIDC + n] = 0.5f * v * (1.f + erff(v * 0.70710678f));
        }
    }
}

// -------- MoE GEMM2: x_flat[tok, :] += hid[tok, :] @ w2[e] + b2[e] --------
__global__ void moe_gemm2_kernel(const float* __restrict__ hid, const float* __restrict__ e_w2,
                                 const float* __restrict__ e_b2,
                                 const int* __restrict__ table, const int* __restrict__ ntiles,
                                 const int* __restrict__ perm, float* __restrict__ x_flat) {
    int by = blockIdx.y;
    if (by >= ntiles[0]) return;
    int e = table[2 * by], row0 = table[2 * by + 1];
    int bn = blockIdx.x * 64;
    __shared__ float As[16][68];
    __shared__ float Bs[16][68];
    __shared__ int rows[64];
    int t = threadIdx.x;
    if (t < 64) rows[t] = perm[row0 + t];
    __syncthreads();
    const float* W = e_w2 + (long)e * HIDC * DIMC;   // [HIDC, DIMC] k-major
    int tx = t & 15, ty = t >> 4;
    float acc[4][4] = {};
    for (int k0 = 0; k0 < HIDC; k0 += 16) {
        #pragma unroll
        for (int j = 0; j < 4; j++) {
            int ea = t + j * 256;
            int mi = ea >> 4, ki = ea & 15;
            int r = rows[mi];
            As[ki][mi] = (r >= 0) ? hid[(long)r * HIDC + k0 + ki] : 0.f;
            int kb = ea >> 6, nb = ea & 63;
            Bs[kb][nb] = W[(long)(k0 + kb) * DIMC + bn + nb];
        }
        __syncthreads();
        #pragma unroll
        for (int kk = 0; kk < 16; kk++) {
            float a[4], b[4];
            #pragma unroll
            for (int i = 0; i < 4; i++) { a[i] = As[kk][ty * 4 + i]; b[i] = Bs[kk][tx * 4 + i]; }
            #pragma unroll
            for (int i = 0; i < 4; i++)
            #pragma unroll
            for (int j2 = 0; j2 < 4; j2++) acc[i][j2] += a[i] * b[j2];
        }
        __syncthreads();
    }
    #pragma unroll
    for (int i = 0; i < 4; i++) {
        int r = rows[ty * 4 + i];
        if (r < 0) continue;
        #pragma unroll
        for (int j2 = 0; j2 < 4; j2++) {
            int n = bn + tx * 4 + j2;
            float v = acc[i][j2] + e_b2[(long)e * DIMC + n];
            x_flat[(long)r * DIMC + n] += v;
        }
    }
}

extern "C" void kernel_launch(void* const* d_in, const int* in_sizes, int n_in,
                              void* d_out, int out_size, void* d_ws, size_t ws_size,
                              hipStream_t stream) {
    const float* x        = (const float*)d_in[0];
    const float* w        = (const float*)d_in[1];
    const float* text     = (const float*)d_in[2];
    const float* pin_w    = (const float*)d_in[3];
    const float* pin_mw   = (const float*)d_in[4];
    const float* pin_mb   = (const float*)d_in[5];
    const float* pout_w   = (const float*)d_in[6];
    const float* pout_mw  = (const float*)d_in[7];
    const float* pout_mb  = (const float*)d_in[8];
    const float* ln1g     = (const float*)d_in[9];
    const float* ln1b     = (const float*)d_in[10];
    const float* ln2g     = (const float*)d_in[11];
    const float* ln2b     = (const float*)d_in[12];
    const float* ln3g     = (const float*)d_in[13];
    const float* ln3b     = (const float*)d_in[14];
    const float* sa_in_w  = (const float*)d_in[15];
    const float* sa_in_b  = (const float*)d_in[16];
    const float* sa_out_w = (const float*)d_in[17];
    const float* sa_out_b = (const float*)d_in[18];
    const float* ca_in_w  = (const float*)d_in[19];
    const float* ca_in_b  = (const float*)d_in[20];
    const float* ca_out_w = (const float*)d_in[21];
    const float* ca_out_b = (const float*)d_in[22];
    const float* r_feat   = (const float*)d_in[23];
    const float* r_text   = (const float*)d_in[24];
    const float* r_comb   = (const float*)d_in[25];
    const float* r_temp   = (const float*)d_in[26];
    const float* e_w1     = (const float*)d_in[27];
    const float* e_b1     = (const float*)d_in[28];
    const float* e_w2     = (const float*)d_in[29];
    const float* e_b2     = (const float*)d_in[30];

    float* out    = (float*)d_out;               // [B, DIM, H, W] = 2097152
    float* onehot = out + (long)BB * DIMC * HWX; // [4096, 8]

    float* ws = (float*)d_ws;
    float* style_in  = ws;                         // 2048
    float* style_out = style_in + 2048;            // 2048
    float* wtmod     = style_out + 2048;           // 1048576 (reused in/out)
    float* x_flat    = wtmod + 1048576;            // 2097152  [B, HW, DIM]
    float* xn        = x_flat + 2097152;           // 2097152
    float* qkv       = xn + 2097152;               // 6291456  (SA qkv; CA q; later reused as hid)
    float* obuf      = qkv + 6291456;              // 2097152  (contiguous with qkv)
    float* kvtext    = obuf + 2097152;             // 315392   [B*77, 1024]
    float* feat      = kvtext + 315392;            // 524288   [4096, 128]
    float* tp        = feat + 524288;              // 32
    int*   idx       = (int*)(tp + 32);            // 4096
    int*   cnt       = idx + 4096;                 // 8
    int*   cursor    = cnt + 8;                    // 8
    int*   ntiles    = cursor + 8;                 // 4
    int*   table     = ntiles + 4;                 // 144
    int*   perm      = table + 144;                // 4608
    float* hid       = qkv;                        // reuse qkv+obuf: 8388608 = 4096*2048

    auto gemm = [&](const float* A, const float* Bm, const float* bias, const float* resid, float* C,
                    int M, int N, int K,
                    long as_m, long as_k, long a_bat,
                    long bs_n, long bs_k, long b_bat,
                    long cs_m, long cs_n, long c_bat, int nbat) {
        dim3 g((N + 63) / 64, (M + 63) / 64, nbat);
        hipLaunchKernelGGL(gemm_kernel, g, dim3(256), 0, stream,
                           A, Bm, bias, resid, C, M, N, K,
                           as_m, as_k, a_bat, bs_n, bs_k, b_bat, cs_m, cs_n, c_bat);
    };

    // ---- modconv in ----
    hipLaunchKernelGGL(style_kernel, dim3(8), dim3(256), 0, stream, w, pin_mw, pin_mb, style_in);
    hipLaunchKernelGGL(wtmod_kernel, dim3(BB * DIMC), dim3(256), 0, stream, pin_w, style_in, wtmod);
    gemm(x, wtmod, nullptr, nullptr, x_flat,
         HWX, DIMC, DIMC,
         1, HWX, (long)DIMC * HWX,
         DIMC, 1, (long)DIMC * DIMC,
         DIMC, 1, (long)HWX * DIMC, BB);

    // ---- LN1 + self-attention ----
    hipLaunchKernelGGL(ln_kernel, dim3(NTOK), dim3(256), 0, stream, x_flat, ln1g, ln1b, xn);
    gemm(xn, sa_in_w, sa_in_b, nullptr, qkv,
         NTOK, 1536, DIMC,
         DIMC, 1, 0, DIMC, 1, 0, 1536, 1, 0, 1);
    hipLaunchKernelGGL(sa_flash_kernel, dim3(16, HEADS, BB), dim3(256), 0, stream, qkv, obuf);
    gemm(obuf, sa_out_w, sa_out_b, x_flat, x_flat,
         NTOK, DIMC, DIMC,
         DIMC, 1, 0, DIMC, 1, 0, DIMC, 1, 0, 1);

    // ---- LN2 + cross-attention ----
    hipLaunchKernelGGL(ln_kernel, dim3(NTOK), dim3(256), 0, stream, x_flat, ln2g, ln2b, xn);
    gemm(xn, ca_in_w, ca_in_b, nullptr, qkv,
         NTOK, DIMC, DIMC,
         DIMC, 1, 0, DIMC, 1, 0, DIMC, 1, 0, 1);
    gemm(text, ca_in_w + (long)DIMC * DIMC, ca_in_b + DIMC, nullptr, kvtext,
         BB * TXT, 1024, DIMC,
         DIMC, 1, 0, DIMC, 1, 0, 1024, 1, 0, 1);
    hipLaunchKernelGGL(ca_attn_kernel, dim3(NTOK, HEADS), dim3(128), 0, stream, qkv, kvtext, obuf);
    gemm(obuf, ca_out_w, ca_out_b, x_flat, x_flat,
         NTOK, DIMC, DIMC,
         DIMC, 1, 0, DIMC, 1, 0, DIMC, 1, 0, 1);

    // ---- LN3 + router ----
    hipLaunchKernelGGL(ln_kernel, dim3(NTOK), dim3(256), 0, stream, x_flat, ln3g, ln3b, xn);
    gemm(xn, r_feat, nullptr, nullptr, feat,
         NTOK, 128, DIMC,
         DIMC, 1, 0, 1, 128, 0, 128, 1, 0, 1);
    hipLaunchKernelGGL(textpart_kernel, dim3(1), dim3(256), 0, stream, w, r_text, r_comb, tp);
    hipLaunchKernelGGL(moe_init_kernel, dim3(18), dim3(256), 0, stream, cnt, perm);
    hipLaunchKernelGGL(route_kernel, dim3(16), dim3(256), 0, stream, feat, tp, r_comb, r_temp, onehot, idx, cnt);
    hipLaunchKernelGGL(offsets_kernel, dim3(1), dim3(64), 0, stream, cnt, cursor, ntiles, table);
    hipLaunchKernelGGL(scatter_kernel, dim3(16), dim3(256), 0, stream, idx, cursor, perm);

    // ---- MoE grouped GEMMs (only the selected expert per token) ----
    hipLaunchKernelGGL(moe_gemm1_kernel, dim3(HIDC / 64, MAXTILES), dim3(256), 0, stream,
                       xn, e_w1, e_b1, table, ntiles, perm, hid);
    hipLaunchKernelGGL(moe_gemm2_kernel, dim3(DIMC / 64, MAXTILES), dim3(256), 0, stream,
                       hid, e_w2, e_b2, table, ntiles, perm, x_flat);

    // ---- modconv out -> d_out ----
    hipLaunchKernelGGL(style_kernel, dim3(8), dim3(256), 0, stream, w, pout_mw, pout_mb, style_out);
    hipLaunchKernelGGL(wtmod_kernel, dim3(BB * DIMC), dim3(256), 0, stream, pout_w, style_out, wtmod);
    gemm(x_flat, wtmod, nullptr, nullptr, out,
         HWX, DIMC, DIMC,
         DIMC, 1, (long)HWX * DIMC,
         DIMC, 1, (long)DIMC * DIMC,
         1, HWX, (long)DIMC * HWX, BB);
}

// Round 5
// 1129.372 us; speedup vs baseline: 4.9012x; 1.4611x over previous
//
#include <hip/hip_runtime.h>
#include <hip/hip_bf16.h>
#include <math.h>

#define DIMC 512
#define HEADS 8
#define HD 64
#define BB 4
#define HWX 1024
#define TXT 77
#define LATC 512
#define NE 8
#define HIDC 2048
#define NTOK 4096
#define MAXT 40

typedef __attribute__((ext_vector_type(8))) short bf16x8;
typedef __attribute__((ext_vector_type(4))) float f32x4;
typedef __hip_bfloat16 bf16;

__device__ __forceinline__ void split2(float v, bf16& h, bf16& l) {
    h = __float2bfloat16(v);
    l = __float2bfloat16(v - __bfloat162float(h));
}

// ---------------- style = w @ mod_w.T + mod_b ----------------
__global__ void style_kernel(const float* __restrict__ w, const float* __restrict__ mod_w,
                             const float* __restrict__ mod_b, float* __restrict__ style) {
    int t = blockIdx.x * blockDim.x + threadIdx.x;
    if (t >= BB * DIMC) return;
    int b = t / DIMC, i = t % DIMC;
    const float* wr = w + (long)b * LATC;
    const float* mr = mod_w + (long)i * LATC;
    float s = 0.f;
    #pragma unroll 8
    for (int l = 0; l < LATC; l++) s += wr[l] * mr[l];
    style[t] = s + mod_b[i];
}

// ------- wtmod[b,o,i] -> bf16 hi/lo (demodulated per-sample weight) -------
__global__ void wtmod_kernel(const float* __restrict__ weight, const float* __restrict__ style,
                             bf16* __restrict__ wh, bf16* __restrict__ wl) {
    int bo = blockIdx.x;
    int b = bo / DIMC, o = bo % DIMC;
    const float* wr = weight + (long)o * DIMC;
    const float* sr = style + (long)b * DIMC;
    int t = threadIdx.x;
    float vals[2]; float part = 0.f;
    for (int j = 0; j < 2; j++) {
        int i = t + j * 256;
        float v = wr[i] * sr[i];
        vals[j] = v; part += v * v;
    }
    __shared__ float red[256];
    red[t] = part; __syncthreads();
    for (int s = 128; s > 0; s >>= 1) { if (t < s) red[t] += red[t + s]; __syncthreads(); }
    float d = rsqrtf(red[0] + 1e-8f);
    for (int j = 0; j < 2; j++) {
        int i = t + j * 256;
        bf16 h, l; split2(vals[j] * d, h, l);
        wh[(long)bo * DIMC + i] = h; wl[(long)bo * DIMC + i] = l;
    }
}

// ---------------- fp32 -> bf16 hi/lo convert (flat) ----------------
__global__ void cvt2_kernel(const float* __restrict__ in, bf16* __restrict__ hi,
                            bf16* __restrict__ lo, int n) {
    int i = (blockIdx.x * blockDim.x + threadIdx.x) * 4;
    if (i >= n) return;
    float4 v = *(const float4*)(in + i);
    float a[4] = {v.x, v.y, v.z, v.w};
    #pragma unroll
    for (int j = 0; j < 4; j++) { bf16 h, l; split2(a[j], h, l); hi[i + j] = h; lo[i + j] = l; }
}

// ---------------- fp32 [R][C] -> bf16 [C][R] transpose hi/lo ----------------
__global__ void trcvt2_kernel(const float* __restrict__ in, bf16* __restrict__ hi,
                              bf16* __restrict__ lo, int R, int C, long in_bat, long out_bat) {
    __shared__ float tile[32][33];
    in += (long)blockIdx.z * in_bat; hi += (long)blockIdx.z * out_bat; lo += (long)blockIdx.z * out_bat;
    int c0 = blockIdx.x * 32, r0 = blockIdx.y * 32;
    int tc = threadIdx.x & 31, tr = threadIdx.x >> 5;
    #pragma unroll
    for (int i = 0; i < 4; i++) {
        int r = tr + i * 8;
        tile[r][tc] = in[(long)(r0 + r) * C + c0 + tc];
    }
    __syncthreads();
    #pragma unroll
    for (int i = 0; i < 4; i++) {
        int r = tr + i * 8;
        bf16 h, l; split2(tile[tc][r], h, l);
        hi[(long)(c0 + r) * R + r0 + tc] = h;
        lo[(long)(c0 + r) * R + r0 + tc] = l;
    }
}

// ---------------- fp32 [R][C] -> bf16 [C][R] transpose (single) ----------------
__global__ void trcvt_kernel(const float* __restrict__ in, bf16* __restrict__ out,
                             int R, int C, long in_bat, long out_bat) {
    __shared__ float tile[32][33];
    in += (long)blockIdx.z * in_bat; out += (long)blockIdx.z * out_bat;
    int c0 = blockIdx.x * 32, r0 = blockIdx.y * 32;
    int tc = threadIdx.x & 31, tr = threadIdx.x >> 5;
    #pragma unroll
    for (int i = 0; i < 4; i++) {
        int r = tr + i * 8;
        tile[r][tc] = in[(long)(r0 + r) * C + c0 + tc];
    }
    __syncthreads();
    #pragma unroll
    for (int i = 0; i < 4; i++) {
        int r = tr + i * 8;
        out[(long)(c0 + r) * R + r0 + tc] = __float2bfloat16(tile[tc][r]);
    }
}

// ---- split-precision bf16 MFMA GEMM: C = A·B^T with A=Ah+Al, B=Bh+Bl ----
// acc += Ah·Bh + Ah·Bl + Al·Bh  (fp32 accumulate). K%32==0, N%128==0.
__global__ __launch_bounds__(256) void mgemm_kernel(
    const bf16* __restrict__ Ah, const bf16* __restrict__ Al,
    const bf16* __restrict__ Bh, const bf16* __restrict__ Bl,
    const float* __restrict__ bias, const float* __restrict__ resid, float* __restrict__ C,
    int M, int N, int K, long a_bat, long b_bat, long c_bat, int cs_m, int cs_n) {
    __shared__ short AsH[128 * 32];
    __shared__ short AsL[128 * 32];
    __shared__ short BsH[128 * 32];
    __shared__ short BsL[128 * 32];
    int bat = blockIdx.z;
    const short* AbH = (const short*)(Ah + (long)bat * a_bat);
    const short* AbL = (const short*)(Al + (long)bat * a_bat);
    const short* BbH = (const short*)(Bh + (long)bat * b_bat);
    const short* BbL = (const short*)(Bl + (long)bat * b_bat);
    float* Cb = C + (long)bat * c_bat;
    const float* Rb = resid ? resid + (long)bat * c_bat : nullptr;
    int bm = blockIdx.y * 128, bn = blockIdx.x * 128;
    int t = threadIdx.x, lane = t & 63, w = t >> 6;
    int wm = (w >> 1) * 64, wn = (w & 1) * 64;
    int p0 = t, p1 = t + 256;
    int r0 = p0 >> 2, k0s = (p0 & 3) ^ ((r0 >> 1) & 3);
    int r1 = p1 >> 2, k1s = (p1 & 3) ^ ((r1 >> 1) & 3);
    int ar0 = bm + r0; if (ar0 > M - 1) ar0 = M - 1;
    int ar1 = bm + r1; if (ar1 > M - 1) ar1 = M - 1;
    long aoff0 = (long)ar0 * K + k0s * 8, aoff1 = (long)ar1 * K + k1s * 8;
    long boff0 = (long)(bn + r0) * K + k0s * 8, boff1 = (long)(bn + r1) * K + k1s * 8;
    int fr = lane & 15, fq = lane >> 4;
    int aOff[4], bOff[4];
    #pragma unroll
    for (int i = 0; i < 4; i++) {
        int row = wm + i * 16 + fr;
        aOff[i] = row * 32 + ((fq ^ ((row >> 1) & 3)) * 8);
        int col = wn + i * 16 + fr;
        bOff[i] = col * 32 + ((fq ^ ((col >> 1) & 3)) * 8);
    }
    f32x4 acc[4][4] = {};
    for (int kk = 0; kk < K; kk += 32) {
        bf16x8 vah0 = *(const bf16x8*)(AbH + aoff0 + kk);
        bf16x8 vah1 = *(const bf16x8*)(AbH + aoff1 + kk);
        bf16x8 val0 = *(const bf16x8*)(AbL + aoff0 + kk);
        bf16x8 val1 = *(const bf16x8*)(AbL + aoff1 + kk);
        bf16x8 vbh0 = *(const bf16x8*)(BbH + boff0 + kk);
        bf16x8 vbh1 = *(const bf16x8*)(BbH + boff1 + kk);
        bf16x8 vbl0 = *(const bf16x8*)(BbL + boff0 + kk);
        bf16x8 vbl1 = *(const bf16x8*)(BbL + boff1 + kk);
        __syncthreads();
        *(bf16x8*)&AsH[p0 * 8] = vah0;  *(bf16x8*)&AsH[p1 * 8] = vah1;
        *(bf16x8*)&AsL[p0 * 8] = val0;  *(bf16x8*)&AsL[p1 * 8] = val1;
        *(bf16x8*)&BsH[p0 * 8] = vbh0;  *(bf16x8*)&BsH[p1 * 8] = vbh1;
        *(bf16x8*)&BsL[p0 * 8] = vbl0;  *(bf16x8*)&BsL[p1 * 8] = vbl1;
        __syncthreads();
        bf16x8 aH[4], aL[4], bH[4], bL[4];
        #pragma unroll
        for (int i = 0; i < 4; i++) {
            aH[i] = *(const bf16x8*)&AsH[aOff[i]];
            aL[i] = *(const bf16x8*)&AsL[aOff[i]];
            bH[i] = *(const bf16x8*)&BsH[bOff[i]];
            bL[i] = *(const bf16x8*)&BsL[bOff[i]];
        }
        #pragma unroll
        for (int i = 0; i < 4; i++)
        #pragma unroll
        for (int j = 0; j < 4; j++) {
            acc[i][j] = __builtin_amdgcn_mfma_f32_16x16x32_bf16(aH[i], bH[j], acc[i][j], 0, 0, 0);
            acc[i][j] = __builtin_amdgcn_mfma_f32_16x16x32_bf16(aH[i], bL[j], acc[i][j], 0, 0, 0);
            acc[i][j] = __builtin_amdgcn_mfma_f32_16x16x32_bf16(aL[i], bH[j], acc[i][j], 0, 0, 0);
        }
    }
    #pragma unroll
    for (int i = 0; i < 4; i++)
    #pragma unroll
    for (int j = 0; j < 4; j++)
    #pragma unroll
    for (int r = 0; r < 4; r++) {
        int row = bm + wm + i * 16 + fq * 4 + r;
        int col = bn + wn + j * 16 + fr;
        if (row < M) {
            long off = (long)row * cs_m + (long)col * cs_n;
            float v = acc[i][j][r];
            if (bias) v += bias[col];
            if (Rb) v += Rb[off];
            Cb[off] = v;
        }
    }
}

// ---- MoE grouped MFMA GEMM1 (plain bf16): hid = gelu(xn·w1 + b1), K=512 ----
__global__ __launch_bounds__(256) void moe_mfma1_kernel(
    const bf16* __restrict__ xn_b, const bf16* __restrict__ e1T, const float* __restrict__ e_b1,
    const int* __restrict__ table, const int* __restrict__ ntiles, const int* __restrict__ perm,
    bf16* __restrict__ hid_b) {
    if (blockIdx.y >= ntiles[0]) return;
    int e = table[2 * blockIdx.y], row0 = table[2 * blockIdx.y + 1];
    int bn = blockIdx.x * 128;
    __shared__ short As[128 * 32];
    __shared__ short Bs[128 * 32];
    __shared__ int rowsS[128];
    int t = threadIdx.x, lane = t & 63, w = t >> 6;
    if (t < 128) rowsS[t] = perm[row0 + t];
    __syncthreads();
    int wm = (w >> 1) * 64, wn = (w & 1) * 64;
    int p0 = t, p1 = t + 256;
    int r0 = p0 >> 2, k0s = (p0 & 3) ^ ((r0 >> 1) & 3);
    int r1 = p1 >> 2, k1s = (p1 & 3) ^ ((r1 >> 1) & 3);
    int tok0 = rowsS[r0]; if (tok0 < 0) tok0 = 0;
    int tok1 = rowsS[r1]; if (tok1 < 0) tok1 = 0;
    const short* Xs = (const short*)xn_b;
    const short* Ws = (const short*)(e1T + (long)e * HIDC * DIMC);
    const short* a0 = Xs + (long)tok0 * DIMC + k0s * 8;
    const short* a1 = Xs + (long)tok1 * DIMC + k1s * 8;
    const short* b0 = Ws + (long)(bn + r0) * DIMC + k0s * 8;
    const short* b1 = Ws + (long)(bn + r1) * DIMC + k1s * 8;
    int fr = lane & 15, fq = lane >> 4;
    int aOff[4], bOff[4];
    #pragma unroll
    for (int i = 0; i < 4; i++) {
        int row = wm + i * 16 + fr;
        aOff[i] = row * 32 + ((fq ^ ((row >> 1) & 3)) * 8);
        int col = wn + i * 16 + fr;
        bOff[i] = col * 32 + ((fq ^ ((col >> 1) & 3)) * 8);
    }
    f32x4 acc[4][4] = {};
    for (int kk = 0; kk < DIMC; kk += 32) {
        bf16x8 va0 = *(const bf16x8*)(a0 + kk);
        bf16x8 va1 = *(const bf16x8*)(a1 + kk);
        bf16x8 vb0 = *(const bf16x8*)(b0 + kk);
        bf16x8 vb1 = *(const bf16x8*)(b1 + kk);
        __syncthreads();
        *(bf16x8*)&As[p0 * 8] = va0;  *(bf16x8*)&As[p1 * 8] = va1;
        *(bf16x8*)&Bs[p0 * 8] = vb0;  *(bf16x8*)&Bs[p1 * 8] = vb1;
        __syncthreads();
        bf16x8 aF[4], bF[4];
        #pragma unroll
        for (int i = 0; i < 4; i++) {
            aF[i] = *(const bf16x8*)&As[aOff[i]];
            bF[i] = *(const bf16x8*)&Bs[bOff[i]];
        }
        #pragma unroll
        for (int i = 0; i < 4; i++)
        #pragma unroll
        for (int j = 0; j < 4; j++)
            acc[i][j] = __builtin_amdgcn_mfma_f32_16x16x32_bf16(aF[i], bF[j], acc[i][j], 0, 0, 0);
    }
    const float* bb = e_b1 + (long)e * HIDC;
    #pragma unroll
    for (int i = 0; i < 4; i++)
    #pragma unroll
    for (int r = 0; r < 4; r++) {
        int tok = rowsS[wm + i * 16 + fq * 4 + r];
        if (tok < 0) continue;
        #pragma unroll
        for (int j = 0; j < 4; j++) {
            int col = bn + wn + j * 16 + fr;
            float v = acc[i][j][r] + bb[col];
            v = 0.5f * v * (1.f + erff(v * 0.70710678f));
            hid_b[(long)tok * HIDC + col] = __float2bfloat16(v);
        }
    }
}

// ---- MoE grouped MFMA GEMM2 (plain bf16): x_flat += hid·w2 + b2, K=2048 ----
__global__ __launch_bounds__(256) void moe_mfma2_kernel(
    const bf16* __restrict__ hid_b, const bf16* __restrict__ e2T, const float* __restrict__ e_b2,
    const int* __restrict__ table, const int* __restrict__ ntiles, const int* __restrict__ perm,
    float* __restrict__ x_flat) {
    if (blockIdx.y >= ntiles[0]) return;
    int e = table[2 * blockIdx.y], row0 = table[2 * blockIdx.y + 1];
    int bn = blockIdx.x * 128;
    __shared__ short As[128 * 32];
    __shared__ short Bs[128 * 32];
    __shared__ int rowsS[128];
    int t = threadIdx.x, lane = t & 63, w = t >> 6;
    if (t < 128) rowsS[t] = perm[row0 + t];
    __syncthreads();
    int wm = (w >> 1) * 64, wn = (w & 1) * 64;
    int p0 = t, p1 = t + 256;
    int r0 = p0 >> 2, k0s = (p0 & 3) ^ ((r0 >> 1) & 3);
    int r1 = p1 >> 2, k1s = (p1 & 3) ^ ((r1 >> 1) & 3);
    int tok0 = rowsS[r0]; if (tok0 < 0) tok0 = 0;
    int tok1 = rowsS[r1]; if (tok1 < 0) tok1 = 0;
    const short* Hs = (const short*)hid_b;
    const short* Ws = (const short*)(e2T + (long)e * DIMC * HIDC);
    const short* a0 = Hs + (long)tok0 * HIDC + k0s * 8;
    const short* a1 = Hs + (long)tok1 * HIDC + k1s * 8;
    const short* b0 = Ws + (long)(bn + r0) * HIDC + k0s * 8;
    const short* b1 = Ws + (long)(bn + r1) * HIDC + k1s * 8;
    int fr = lane & 15, fq = lane >> 4;
    int aOff[4], bOff[4];
    #pragma unroll
    for (int i = 0; i < 4; i++) {
        int row = wm + i * 16 + fr;
        aOff[i] = row * 32 + ((fq ^ ((row >> 1) & 3)) * 8);
        int col = wn + i * 16 + fr;
        bOff[i] = col * 32 + ((fq ^ ((col >> 1) & 3)) * 8);
    }
    f32x4 acc[4][4] = {};
    for (int kk = 0; kk < HIDC; kk += 32) {
        bf16x8 va0 = *(const bf16x8*)(a0 + kk);
        bf16x8 va1 = *(const bf16x8*)(a1 + kk);
        bf16x8 vb0 = *(const bf16x8*)(b0 + kk);
        bf16x8 vb1 = *(const bf16x8*)(b1 + kk);
        __syncthreads();
        *(bf16x8*)&As[p0 * 8] = va0;  *(bf16x8*)&As[p1 * 8] = va1;
        *(bf16x8*)&Bs[p0 * 8] = vb0;  *(bf16x8*)&Bs[p1 * 8] = vb1;
        __syncthreads();
        bf16x8 aF[4], bF[4];
        #pragma unroll
        for (int i = 0; i < 4; i++) {
            aF[i] = *(const bf16x8*)&As[aOff[i]];
            bF[i] = *(const bf16x8*)&Bs[bOff[i]];
        }
        #pragma unroll
        for (int i = 0; i < 4; i++)
        #pragma unroll
        for (int j = 0; j < 4; j++)
            acc[i][j] = __builtin_amdgcn_mfma_f32_16x16x32_bf16(aF[i], bF[j], acc[i][j], 0, 0, 0);
    }
    const float* bb = e_b2 + (long)e * DIMC;
    #pragma unroll
    for (int i = 0; i < 4; i++)
    #pragma unroll
    for (int r = 0; r < 4; r++) {
        int tok = rowsS[wm + i * 16 + fq * 4 + r];
        if (tok < 0) continue;
        #pragma unroll
        for (int j = 0; j < 4; j++) {
            int col = bn + wn + j * 16 + fr;
            x_flat[(long)tok * DIMC + col] += acc[i][j][r] + bb[col];
        }
    }
}

// ---- fp32 vector GEMM (router feat projection only) ----
__global__ void gemm_kernel(const float* __restrict__ A, const float* __restrict__ Bm,
                            float* __restrict__ C, int M, int N, int K,
                            long as_m, long as_k, long bs_n, long bs_k, long cs_m) {
    __shared__ float As[16][68];
    __shared__ float Bs[16][68];
    int bm = blockIdx.y * 64, bn = blockIdx.x * 64;
    int t = threadIdx.x;
    int tx = t & 15, ty = t >> 4;
    float acc[4][4] = {};
    for (int k0 = 0; k0 < K; k0 += 16) {
        #pragma unroll
        for (int j = 0; j < 4; j++) {
            int e = t + j * 256;
            int mi = e >> 4, ki = e & 15;
            int m = bm + mi, k = k0 + ki;
            As[ki][mi] = (m < M) ? A[(long)m * as_m + (long)k * as_k] : 0.f;
            int n = bn + mi;
            Bs[ki][mi] = (n < N) ? Bm[(long)n * bs_n + (long)k * bs_k] : 0.f;
        }
        __syncthreads();
        #pragma unroll
        for (int kk = 0; kk < 16; kk++) {
            float a[4], b[4];
            #pragma unroll
            for (int i = 0; i < 4; i++) { a[i] = As[kk][ty * 4 + i]; b[i] = Bs[kk][tx * 4 + i]; }
            #pragma unroll
            for (int i = 0; i < 4; i++)
            #pragma unroll
            for (int j2 = 0; j2 < 4; j2++) acc[i][j2] += a[i] * b[j2];
        }
        __syncthreads();
    }
    #pragma unroll
    for (int i = 0; i < 4; i++) {
        int m = bm + ty * 4 + i;
        if (m >= M) continue;
        #pragma unroll
        for (int j2 = 0; j2 < 4; j2++) {
            int n = bn + tx * 4 + j2;
            if (n < N) C[(long)m * cs_m + n] = acc[i][j2];
        }
    }
}

// ---------------- LayerNorm: fp32 + bf16 hi/lo outputs ----------------
__global__ void ln_kernel(const float* __restrict__ x, const float* __restrict__ g,
                          const float* __restrict__ b, float* __restrict__ y,
                          bf16* __restrict__ yh, bf16* __restrict__ yl) {
    int tok = blockIdx.x;
    int t = threadIdx.x;
    const float* xr = x + (long)tok * DIMC;
    float v0 = xr[t], v1 = xr[t + 256];
    __shared__ float red[256];
    red[t] = v0 + v1; __syncthreads();
    for (int s = 128; s > 0; s >>= 1) { if (t < s) red[t] += red[t + s]; __syncthreads(); }
    float mu = red[0] * (1.f / DIMC);
    __syncthreads();
    float d0 = v0 - mu, d1 = v1 - mu;
    red[t] = d0 * d0 + d1 * d1; __syncthreads();
    for (int s = 128; s > 0; s >>= 1) { if (t < s) red[t] += red[t + s]; __syncthreads(); }
    float rs = rsqrtf(red[0] * (1.f / DIMC) + 1e-5f);
    float o0 = d0 * rs * g[t] + b[t];
    float o1 = d1 * rs * g[t + 256] + b[t + 256];
    y[(long)tok * DIMC + t] = o0; y[(long)tok * DIMC + t + 256] = o1;
    bf16 h, l;
    split2(o0, h, l); yh[(long)tok * DIMC + t] = h;       yl[(long)tok * DIMC + t] = l;
    split2(o1, h, l); yh[(long)tok * DIMC + t + 256] = h; yl[(long)tok * DIMC + t + 256] = l;
}

// ---- flash self-attention (fp32 compute, hi/lo bf16 output) ----
__global__ __launch_bounds__(256) void sa_flash_kernel(const float* __restrict__ qkv,
                                                       bf16* __restrict__ oh,
                                                       bf16* __restrict__ ol) {
    int qt = blockIdx.x, h = blockIdx.y, b = blockIdx.z;
    __shared__ float Qs[64][68];
    __shared__ float KVs[64][68];
    __shared__ float Pt[64][68];
    int t = threadIdx.x;
    int tx = t & 15, ty = t >> 4;
    long qbase = ((long)(b * 1024 + qt * 64)) * 1536 + h * 64;
    #pragma unroll
    for (int j = 0; j < 16; j++) {
        int e = t + j * 256;
        int r = e >> 6, d = e & 63;
        Qs[d][r] = qkv[qbase + (long)r * 1536 + d] * 0.125f;
    }
    float m_i[4], l_i[4], o_acc[4][4] = {};
    #pragma unroll
    for (int i = 0; i < 4; i++) { m_i[i] = -1e30f; l_i[i] = 0.f; }
    long kbase = ((long)b * 1024) * 1536 + 512 + h * 64;
    long vbase = kbase + 512;
    for (int kt = 0; kt < 16; kt++) {
        __syncthreads();
        #pragma unroll
        for (int j = 0; j < 16; j++) {
            int e = t + j * 256;
            int r = e >> 6, d = e & 63;
            KVs[d][r] = qkv[kbase + (long)(kt * 64 + r) * 1536 + d];
        }
        __syncthreads();
        float s[4][4] = {};
        #pragma unroll
        for (int kk = 0; kk < 64; kk++) {
            float a[4], bv[4];
            #pragma unroll
            for (int i = 0; i < 4; i++) { a[i] = Qs[kk][ty * 4 + i]; bv[i] = KVs[kk][tx * 4 + i]; }
            #pragma unroll
            for (int i = 0; i < 4; i++)
            #pragma unroll
            for (int j2 = 0; j2 < 4; j2++) s[i][j2] += a[i] * bv[j2];
        }
        float sc_i[4];
        #pragma unroll
        for (int i = 0; i < 4; i++) {
            float mx = fmaxf(fmaxf(s[i][0], s[i][1]), fmaxf(s[i][2], s[i][3]));
            mx = fmaxf(mx, __shfl_xor(mx, 1));
            mx = fmaxf(mx, __shfl_xor(mx, 2));
            mx = fmaxf(mx, __shfl_xor(mx, 4));
            mx = fmaxf(mx, __shfl_xor(mx, 8));
            float mn = fmaxf(m_i[i], mx);
            sc_i[i] = __expf(m_i[i] - mn);
            m_i[i] = mn;
            float rs = 0.f;
            #pragma unroll
            for (int j2 = 0; j2 < 4; j2++) { s[i][j2] = __expf(s[i][j2] - mn); rs += s[i][j2]; }
            rs += __shfl_xor(rs, 1);
            rs += __shfl_xor(rs, 2);
            rs += __shfl_xor(rs, 4);
            rs += __shfl_xor(rs, 8);
            l_i[i] = l_i[i] * sc_i[i] + rs;
        }
        __syncthreads();
        #pragma unroll
        for (int i = 0; i < 4; i++)
        #pragma unroll
        for (int j2 = 0; j2 < 4; j2++) Pt[tx * 4 + j2][ty * 4 + i] = s[i][j2];
        #pragma unroll
        for (int j = 0; j < 16; j++) {
            int e = t + j * 256;
            int r = e >> 6, d = e & 63;
            KVs[r][d] = qkv[vbase + (long)(kt * 64 + r) * 1536 + d];
        }
        __syncthreads();
        #pragma unroll
        for (int i = 0; i < 4; i++)
        #pragma unroll
        for (int j2 = 0; j2 < 4; j2++) o_acc[i][j2] *= sc_i[i];
        #pragma unroll
        for (int kk = 0; kk < 64; kk++) {
            float a[4], bv[4];
            #pragma unroll
            for (int i = 0; i < 4; i++) { a[i] = Pt[kk][ty * 4 + i]; bv[i] = KVs[kk][tx * 4 + i]; }
            #pragma unroll
            for (int i = 0; i < 4; i++)
            #pragma unroll
            for (int j2 = 0; j2 < 4; j2++) o_acc[i][j2] += a[i] * bv[j2];
        }
    }
    #pragma unroll
    for (int i = 0; i < 4; i++) {
        float inv = 1.f / l_i[i];
        long m = b * 1024 + qt * 64 + ty * 4 + i;
        #pragma unroll
        for (int j2 = 0; j2 < 4; j2++) {
            bf16 hh, ll; split2(o_acc[i][j2] * inv, hh, ll);
            oh[m * DIMC + h * 64 + tx * 4 + j2] = hh;
            ol[m * DIMC + h * 64 + tx * 4 + j2] = ll;
        }
    }
}

// ---------------- cross-attention (77 keys), hi/lo output ----------------
__global__ void ca_attn_kernel(const float* __restrict__ q, const float* __restrict__ kv,
                               bf16* __restrict__ oh, bf16* __restrict__ ol) {
    int m = blockIdx.x; int h = blockIdx.y; int b = m >> 10;
    int t = threadIdx.x;    // 128
    __shared__ float qs[64];
    __shared__ float sc[77];
    __shared__ float red[128];
    if (t < 64) qs[t] = q[(long)m * DIMC + h * 64 + t];
    __syncthreads();
    float lm = -1e30f;
    if (t < 77) {
        const float* kr = kv + ((long)(b * 77 + t)) * 1024 + h * 64;
        float s = 0.f;
        #pragma unroll 8
        for (int d = 0; d < 64; d++) s += qs[d] * kr[d];
        s *= 0.125f;
        sc[t] = s; lm = s;
    }
    red[t] = lm; __syncthreads();
    for (int s = 64; s > 0; s >>= 1) { if (t < s) red[t] = fmaxf(red[t], red[t + s]); __syncthreads(); }
    float mx = red[0]; __syncthreads();
    float ls = 0.f;
    if (t < 77) { float e = __expf(sc[t] - mx); sc[t] = e; ls = e; }
    red[t] = ls; __syncthreads();
    for (int s = 64; s > 0; s >>= 1) { if (t < s) red[t] += red[t + s]; __syncthreads(); }
    float inv = 1.f / red[0];
    __syncthreads();
    if (t < 64) {
        float acc = 0.f;
        for (int kk = 0; kk < 77; kk++)
            acc += sc[kk] * kv[((long)(b * 77 + kk)) * 1024 + 512 + h * 64 + t];
        bf16 hh, ll; split2(acc * inv, hh, ll);
        oh[(long)m * DIMC + h * 64 + t] = hh;
        ol[(long)m * DIMC + h * 64 + t] = ll;
    }
}

// ---------------- router text part ----------------
__global__ void textpart_kernel(const float* __restrict__ w, const float* __restrict__ r_text_mu,
                                const float* __restrict__ r_comb_mu, float* __restrict__ tp) {
    __shared__ float tw[4][128];
    int t = threadIdx.x;
    for (int j = 0; j < 2; j++) {
        int idx = t + j * 256; int b = idx >> 7, c = idx & 127;
        const float* wr = w + (long)b * LATC;
        float s = 0.f;
        for (int k = 0; k < LATC; k++) s += wr[k] * r_text_mu[(long)k * 128 + c];
        tw[b][c] = s;
    }
    __syncthreads();
    if (t < 32) {
        int b = t >> 3, e = t & 7;
        float s = 0.f;
        for (int c = 0; c < 128; c++) s += tw[b][c] * r_comb_mu[(long)(128 + c) * 8 + e];
        tp[t] = s;
    }
}

// ---------------- MoE meta ----------------
__global__ void moe_init_kernel(int* __restrict__ cnt, int* __restrict__ perm) {
    int g = blockIdx.x * blockDim.x + threadIdx.x;
    if (g < MAXT * 128) perm[g] = -1;
    if (g < NE) cnt[g] = 0;
}

__global__ void route_kernel(const float* __restrict__ feat, const float* __restrict__ tp,
                             const float* __restrict__ r_comb_mu, const float* __restrict__ r_temp,
                             float* __restrict__ onehot, int* __restrict__ idx, int* __restrict__ cnt) {
    int n = blockIdx.x * blockDim.x + threadIdx.x;
    if (n >= NTOK) return;
    int b = n >> 10;
    float tmp = fmaxf(r_temp[0], 0.1f);
    float invt = 1.f / tmp;
    const float* fr = feat + (long)n * 128;
    float lg[8];
    for (int e = 0; e < 8; e++) {
        float s = 0.f;
        for (int c = 0; c < 128; c++) s += fr[c] * r_comb_mu[(long)c * 8 + e];
        lg[e] = (s + tp[b * 8 + e]) * invt;
    }
    float best = lg[0]; int bi = 0;
    for (int e = 1; e < 8; e++) { if (lg[e] > best) { best = lg[e]; bi = e; } }
    for (int e = 0; e < 8; e++) onehot[(long)n * 8 + e] = (e == bi) ? 1.f : 0.f;
    idx[n] = bi;
    atomicAdd(&cnt[bi], 1);
}

__global__ void offsets_kernel(const int* __restrict__ cnt, int* __restrict__ cursor,
                               int* __restrict__ ntiles, int* __restrict__ table) {
    if (threadIdx.x != 0) return;
    int po = 0, nt = 0;
    for (int e = 0; e < NE; e++) {
        cursor[e] = po;
        int tiles = (cnt[e] + 127) >> 7;
        for (int j = 0; j < tiles; j++) { table[2 * nt] = e; table[2 * nt + 1] = po + j * 128; nt++; }
        po += tiles * 128;
    }
    ntiles[0] = nt;
}

__global__ void scatter_kernel(const int* __restrict__ idx, int* __restrict__ cursor,
                               int* __restrict__ perm) {
    int n = blockIdx.x * blockDim.x + threadIdx.x;
    if (n >= NTOK) return;
    int e = idx[n];
    int pos = atomicAdd(&cursor[e], 1);
    perm[pos] = n;
}

extern "C" void kernel_launch(void* const* d_in, const int* in_sizes, int n_in,
                              void* d_out, int out_size, void* d_ws, size_t ws_size,
                              hipStream_t stream) {
    const float* x        = (const float*)d_in[0];
    const float* w        = (const float*)d_in[1];
    const float* text     = (const float*)d_in[2];
    const float* pin_w    = (const float*)d_in[3];
    const float* pin_mw   = (const float*)d_in[4];
    const float* pin_mb   = (const float*)d_in[5];
    const float* pout_w   = (const float*)d_in[6];
    const float* pout_mw  = (const float*)d_in[7];
    const float* pout_mb  = (const float*)d_in[8];
    const float* ln1g     = (const float*)d_in[9];
    const float* ln1b     = (const float*)d_in[10];
    const float* ln2g     = (const float*)d_in[11];
    const float* ln2b     = (const float*)d_in[12];
    const float* ln3g     = (const float*)d_in[13];
    const float* ln3b     = (const float*)d_in[14];
    const float* sa_in_w  = (const float*)d_in[15];
    const float* sa_in_b  = (const float*)d_in[16];
    const float* sa_out_w = (const float*)d_in[17];
    const float* sa_out_b = (const float*)d_in[18];
    const float* ca_in_w  = (const float*)d_in[19];
    const float* ca_in_b  = (const float*)d_in[20];
    const float* ca_out_w = (const float*)d_in[21];
    const float* ca_out_b = (const float*)d_in[22];
    const float* r_feat   = (const float*)d_in[23];
    const float* r_text   = (const float*)d_in[24];
    const float* r_comb   = (const float*)d_in[25];
    const float* r_temp   = (const float*)d_in[26];
    const float* e_w1     = (const float*)d_in[27];
    const float* e_b1     = (const float*)d_in[28];
    const float* e_w2     = (const float*)d_in[29];
    const float* e_b2     = (const float*)d_in[30];

    float* out    = (float*)d_out;               // [B, DIM, H, W]
    float* onehot = out + (long)BB * DIMC * HWX; // [4096, 8]

    // ---------------- workspace: fp32 pool ----------------
    float* f32p = (float*)d_ws;
    float* style_in  = f32p;                 // 2048
    float* style_out = f32p + 2048;          // 2048
    float* tp        = f32p + 4096;          // 32
    int*   idx       = (int*)(f32p + 4128);  // 4096
    int*   cnt       = (int*)(f32p + 8224);  // 8
    int*   cursor    = (int*)(f32p + 8232);  // 8
    int*   ntiles    = (int*)(f32p + 8240);  // 8
    int*   table     = (int*)(f32p + 8248);  // 128
    int*   perm      = (int*)(f32p + 8376);  // 5120 -> ends 13496
    float* x_flat    = f32p + 13496;         // 2097152
    float* xn        = x_flat + 2097152;     // 2097152
    float* qkv       = xn + 2097152;         // 6291456
    float* spill     = qkv + 6291456;        // 2097152 (e2T tail)
    // fp32 pool ends at f32p + 12596408  (50.4 MB)

    // ---------------- bf16 pool (phase-aliased) ----------------
    bf16* bp = (bf16*)(f32p + 12596408);
    bf16* R1 = bp;                           // 6291456 elems (12 MB), 3 phases
    // phase A: x^T + modconv-in weights
    bf16* xT_h  = R1;
    bf16* xT_l  = R1 + 2097152;
    bf16* wtA_h = R1 + 4194304;
    bf16* wtA_l = R1 + 5242880;
    // phase B: attention outputs + kvtext/feat (tail)
    bf16* obuf_h = R1;
    bf16* obuf_l = R1 + 2097152;
    float* kvtext = (float*)(R1 + 4194304);            // 315392 fp32
    float* feat   = (float*)(R1 + 4194304 + 630784);   // 524288 fp32
    // phase C: modconv-out weights
    bf16* wtC_h = R1;
    bf16* wtC_l = R1 + 1048576;
    bf16* xn_h = R1 + 6291456;               // 2097152
    bf16* xn_l = xn_h + 2097152;             // 2097152
    bf16* WB   = xn_l + 2097152;             // 8388608: weights (early) / hid_b (late)
    bf16* text_h   = WB;
    bf16* text_l   = text_h + 157696;
    bf16* sawin_h  = text_l + 157696;
    bf16* sawin_l  = sawin_h + 786432;
    bf16* sawout_h = sawin_l + 786432;
    bf16* sawout_l = sawout_h + 262144;
    bf16* caw_h    = sawout_l + 262144;
    bf16* caw_l    = caw_h + 786432;
    bf16* cawout_h = caw_l + 786432;
    bf16* cawout_l = cawout_h + 262144;
    bf16* hid_b    = WB;                     // overlays weights after ca_out
    bf16* e1T = (bf16*)qkv;                  // [8][2048][512] in qkv+spill (exact fit)
    bf16* e2T = e1T + 8388608;
    bf16* xfl_h = xn_h;                      // x_flat split, post-MoE
    bf16* xfl_l = xn_l;
    (void)ws_size; (void)spill;

    auto mg = [&](const bf16* Ah, const bf16* Al, const bf16* Bh, const bf16* Bl,
                  const float* bias, const float* resid, float* C,
                  int M, int N, int K, long ab, long bb, long cb, int csm, int csn, int nb) {
        dim3 g(N / 128, (M + 127) / 128, nb);
        hipLaunchKernelGGL(mgemm_kernel, g, dim3(256), 0, stream,
                           Ah, Al, Bh, Bl, bias, resid, C, M, N, K, ab, bb, cb, csm, csn);
    };
    auto cvt2 = [&](const float* in, bf16* h2, bf16* l2, int n) {
        hipLaunchKernelGGL(cvt2_kernel, dim3((n / 4 + 255) / 256), dim3(256), 0, stream, in, h2, l2, n);
    };

    // ---- input conversions (hi/lo) ----
    cvt2(sa_in_w, sawin_h, sawin_l, 1536 * 512);
    cvt2(sa_out_w, sawout_h, sawout_l, 512 * 512);
    cvt2(ca_in_w, caw_h, caw_l, 1536 * 512);
    cvt2(ca_out_w, cawout_h, cawout_l, 512 * 512);
    cvt2(text, text_h, text_l, BB * TXT * 512);
    hipLaunchKernelGGL(trcvt2_kernel, dim3(32, 16, BB), dim3(256), 0, stream,
                       x, xT_h, xT_l, 512, 1024, (long)512 * 1024, (long)1024 * 512);

    // ---- modconv in ----
    hipLaunchKernelGGL(style_kernel, dim3(8), dim3(256), 0, stream, w, pin_mw, pin_mb, style_in);
    hipLaunchKernelGGL(wtmod_kernel, dim3(BB * DIMC), dim3(256), 0, stream, pin_w, style_in, wtA_h, wtA_l);
    mg(xT_h, xT_l, wtA_h, wtA_l, nullptr, nullptr, x_flat,
       HWX, DIMC, DIMC, (long)HWX * DIMC, (long)DIMC * DIMC, (long)HWX * DIMC, DIMC, 1, BB);

    // ---- LN1 + self-attention ----
    hipLaunchKernelGGL(ln_kernel, dim3(NTOK), dim3(256), 0, stream, x_flat, ln1g, ln1b, xn, xn_h, xn_l);
    mg(xn_h, xn_l, sawin_h, sawin_l, sa_in_b, nullptr, qkv, NTOK, 1536, 512, 0, 0, 0, 1536, 1, 1);
    hipLaunchKernelGGL(sa_flash_kernel, dim3(16, HEADS, BB), dim3(256), 0, stream, qkv, obuf_h, obuf_l);
    mg(obuf_h, obuf_l, sawout_h, sawout_l, sa_out_b, x_flat, x_flat, NTOK, 512, 512, 0, 0, 0, 512, 1, 1);

    // ---- LN2 + cross-attention ----
    hipLaunchKernelGGL(ln_kernel, dim3(NTOK), dim3(256), 0, stream, x_flat, ln2g, ln2b, xn, xn_h, xn_l);
    mg(xn_h, xn_l, caw_h, caw_l, ca_in_b, nullptr, qkv, NTOK, 512, 512, 0, 0, 0, 512, 1, 1);
    mg(text_h, text_l, caw_h + 512 * 512, caw_l + 512 * 512, ca_in_b + 512, nullptr, kvtext,
       BB * TXT, 1024, 512, 0, 0, 0, 1024, 1, 1);
    hipLaunchKernelGGL(ca_attn_kernel, dim3(NTOK, HEADS), dim3(128), 0, stream, qkv, kvtext, obuf_h, obuf_l);
    // qkv fp32 dead after ca_attn -> build expert weight transposes there
    hipLaunchKernelGGL(trcvt_kernel, dim3(64, 16, NE), dim3(256), 0, stream,
                       e_w1, e1T, 512, 2048, (long)512 * 2048, (long)2048 * 512);
    hipLaunchKernelGGL(trcvt_kernel, dim3(16, 64, NE), dim3(256), 0, stream,
                       e_w2, e2T, 2048, 512, (long)2048 * 512, (long)512 * 2048);
    mg(obuf_h, obuf_l, cawout_h, cawout_l, ca_out_b, x_flat, x_flat, NTOK, 512, 512, 0, 0, 0, 512, 1, 1);

    // ---- LN3 + router ----
    hipLaunchKernelGGL(ln_kernel, dim3(NTOK), dim3(256), 0, stream, x_flat, ln3g, ln3b, xn, xn_h, xn_l);
    hipLaunchKernelGGL(gemm_kernel, dim3(2, 64, 1), dim3(256), 0, stream,
                       xn, r_feat, feat, NTOK, 128, 512, 512L, 1L, 1L, 128L, 128L);
    hipLaunchKernelGGL(textpart_kernel, dim3(1), dim3(256), 0, stream, w, r_text, r_comb, tp);
    hipLaunchKernelGGL(moe_init_kernel, dim3((MAXT * 128 + 255) / 256), dim3(256), 0, stream, cnt, perm);
    hipLaunchKernelGGL(route_kernel, dim3(16), dim3(256), 0, stream, feat, tp, r_comb, r_temp, onehot, idx, cnt);
    hipLaunchKernelGGL(offsets_kernel, dim3(1), dim3(64), 0, stream, cnt, cursor, ntiles, table);
    hipLaunchKernelGGL(scatter_kernel, dim3(16), dim3(256), 0, stream, idx, cursor, perm);

    // ---- MoE grouped MFMA GEMMs (plain bf16; hid_b overlays weight buffers) ----
    hipLaunchKernelGGL(moe_mfma1_kernel, dim3(HIDC / 128, MAXT), dim3(256), 0, stream,
                       xn_h, e1T, e_b1, table, ntiles, perm, hid_b);
    hipLaunchKernelGGL(moe_mfma2_kernel, dim3(DIMC / 128, MAXT), dim3(256), 0, stream,
                       hid_b, e2T, e_b2, table, ntiles, perm, x_flat);

    // ---- modconv out (split both sides) ----
    cvt2(x_flat, xfl_h, xfl_l, NTOK * DIMC);
    hipLaunchKernelGGL(style_kernel, dim3(8), dim3(256), 0, stream, w, pout_mw, pout_mb, style_out);
    hipLaunchKernelGGL(wtmod_kernel, dim3(BB * DIMC), dim3(256), 0, stream, pout_w, style_out, wtC_h, wtC_l);
    mg(wtC_h, wtC_l, xfl_h, xfl_l, nullptr, nullptr, out,
       DIMC, HWX, DIMC, (long)DIMC * DIMC, (long)HWX * DIMC, (long)DIMC * HWX, HWX, 1, BB);
}

// Round 6
// 942.369 us; speedup vs baseline: 5.8738x; 1.1984x over previous
//
#include <hip/hip_runtime.h>
#include <hip/hip_bf16.h>
#include <math.h>

#define DIMC 512
#define HEADS 8
#define HD 64
#define BB 4
#define HWX 1024
#define TXT 77
#define LATC 512
#define NE 8
#define HIDC 2048
#define NTOK 4096
#define MAXT 40

typedef __attribute__((ext_vector_type(8))) short bf16x8;
typedef __attribute__((ext_vector_type(4))) float f32x4;
typedef __hip_bfloat16 bf16;

__device__ __forceinline__ void split2(float v, bf16& h, bf16& l) {
    h = __float2bfloat16(v);
    l = __float2bfloat16(v - __bfloat162float(h));
}
__device__ __forceinline__ void split2s(float v, short& h, short& l) {
    bf16 hb, lb; split2(v, hb, lb);
    h = *(short*)&hb; l = *(short*)&lb;
}

// ---------------- style = w @ mod_w.T + mod_b ----------------
__global__ void style_kernel(const float* __restrict__ w, const float* __restrict__ mod_w,
                             const float* __restrict__ mod_b, float* __restrict__ style) {
    int t = blockIdx.x * blockDim.x + threadIdx.x;
    if (t >= BB * DIMC) return;
    int b = t / DIMC, i = t % DIMC;
    const float* wr = w + (long)b * LATC;
    const float* mr = mod_w + (long)i * LATC;
    float s = 0.f;
    #pragma unroll 8
    for (int l = 0; l < LATC; l++) s += wr[l] * mr[l];
    style[t] = s + mod_b[i];
}

// ------- wtmod[b,o,i] -> bf16 hi/lo (demodulated per-sample weight) -------
__global__ void wtmod_kernel(const float* __restrict__ weight, const float* __restrict__ style,
                             bf16* __restrict__ wh, bf16* __restrict__ wl) {
    int bo = blockIdx.x;
    int b = bo / DIMC, o = bo % DIMC;
    const float* wr = weight + (long)o * DIMC;
    const float* sr = style + (long)b * DIMC;
    int t = threadIdx.x;
    float vals[2]; float part = 0.f;
    for (int j = 0; j < 2; j++) {
        int i = t + j * 256;
        float v = wr[i] * sr[i];
        vals[j] = v; part += v * v;
    }
    __shared__ float red[256];
    red[t] = part; __syncthreads();
    for (int s = 128; s > 0; s >>= 1) { if (t < s) red[t] += red[t + s]; __syncthreads(); }
    float d = rsqrtf(red[0] + 1e-8f);
    for (int j = 0; j < 2; j++) {
        int i = t + j * 256;
        bf16 h, l; split2(vals[j] * d, h, l);
        wh[(long)bo * DIMC + i] = h; wl[(long)bo * DIMC + i] = l;
    }
}

// ---------------- fp32 -> bf16 hi/lo convert (flat) ----------------
__global__ void cvt2_kernel(const float* __restrict__ in, bf16* __restrict__ hi,
                            bf16* __restrict__ lo, int n) {
    int i = (blockIdx.x * blockDim.x + threadIdx.x) * 4;
    if (i >= n) return;
    float4 v = *(const float4*)(in + i);
    float a[4] = {v.x, v.y, v.z, v.w};
    #pragma unroll
    for (int j = 0; j < 4; j++) { bf16 h, l; split2(a[j], h, l); hi[i + j] = h; lo[i + j] = l; }
}

// ---------------- fp32 [R][C] -> bf16 [C][R] transpose hi/lo ----------------
__global__ void trcvt2_kernel(const float* __restrict__ in, bf16* __restrict__ hi,
                              bf16* __restrict__ lo, int R, int C, long in_bat, long out_bat) {
    __shared__ float tile[32][33];
    in += (long)blockIdx.z * in_bat; hi += (long)blockIdx.z * out_bat; lo += (long)blockIdx.z * out_bat;
    int c0 = blockIdx.x * 32, r0 = blockIdx.y * 32;
    int tc = threadIdx.x & 31, tr = threadIdx.x >> 5;
    #pragma unroll
    for (int i = 0; i < 4; i++) {
        int r = tr + i * 8;
        tile[r][tc] = in[(long)(r0 + r) * C + c0 + tc];
    }
    __syncthreads();
    #pragma unroll
    for (int i = 0; i < 4; i++) {
        int r = tr + i * 8;
        bf16 h, l; split2(tile[tc][r], h, l);
        hi[(long)(c0 + r) * R + r0 + tc] = h;
        lo[(long)(c0 + r) * R + r0 + tc] = l;
    }
}

// ---------------- fp32 [R][C] -> bf16 [C][R] transpose (single) ----------------
__global__ void trcvt_kernel(const float* __restrict__ in, bf16* __restrict__ out,
                             int R, int C, long in_bat, long out_bat) {
    __shared__ float tile[32][33];
    in += (long)blockIdx.z * in_bat; out += (long)blockIdx.z * out_bat;
    int c0 = blockIdx.x * 32, r0 = blockIdx.y * 32;
    int tc = threadIdx.x & 31, tr = threadIdx.x >> 5;
    #pragma unroll
    for (int i = 0; i < 4; i++) {
        int r = tr + i * 8;
        tile[r][tc] = in[(long)(r0 + r) * C + c0 + tc];
    }
    __syncthreads();
    #pragma unroll
    for (int i = 0; i < 4; i++) {
        int r = tr + i * 8;
        out[(long)(c0 + r) * R + r0 + tc] = __float2bfloat16(tile[tc][r]);
    }
}

// ---- split-precision bf16 MFMA GEMM: C = A·B^T with A=Ah+Al, B=Bh+Bl ----
// acc += Ah·Bh + Ah·Bl + Al·Bh. Output: fp32 C, or split bf16 (Oh/Ol) when Oh!=null.
__global__ __launch_bounds__(256) void mgemm_kernel(
    const bf16* __restrict__ Ah, const bf16* __restrict__ Al,
    const bf16* __restrict__ Bh, const bf16* __restrict__ Bl,
    const float* __restrict__ bias, const float* __restrict__ resid, float* __restrict__ C,
    bf16* __restrict__ Oh, bf16* __restrict__ Ol,
    int M, int N, int K, long a_bat, long b_bat, long c_bat, int cs_m, int cs_n) {
    __shared__ short AsH[128 * 32];
    __shared__ short AsL[128 * 32];
    __shared__ short BsH[128 * 32];
    __shared__ short BsL[128 * 32];
    int bat = blockIdx.z;
    const short* AbH = (const short*)(Ah + (long)bat * a_bat);
    const short* AbL = (const short*)(Al + (long)bat * a_bat);
    const short* BbH = (const short*)(Bh + (long)bat * b_bat);
    const short* BbL = (const short*)(Bl + (long)bat * b_bat);
    float* Cb = C + (long)bat * c_bat;
    const float* Rb = resid ? resid + (long)bat * c_bat : nullptr;
    int bm = blockIdx.y * 128, bn = blockIdx.x * 128;
    int t = threadIdx.x, lane = t & 63, w = t >> 6;
    int wm = (w >> 1) * 64, wn = (w & 1) * 64;
    int p0 = t, p1 = t + 256;
    int r0 = p0 >> 2, k0s = (p0 & 3) ^ ((r0 >> 1) & 3);
    int r1 = p1 >> 2, k1s = (p1 & 3) ^ ((r1 >> 1) & 3);
    int ar0 = bm + r0; if (ar0 > M - 1) ar0 = M - 1;
    int ar1 = bm + r1; if (ar1 > M - 1) ar1 = M - 1;
    long aoff0 = (long)ar0 * K + k0s * 8, aoff1 = (long)ar1 * K + k1s * 8;
    long boff0 = (long)(bn + r0) * K + k0s * 8, boff1 = (long)(bn + r1) * K + k1s * 8;
    int fr = lane & 15, fq = lane >> 4;
    int aOff[4], bOff[4];
    #pragma unroll
    for (int i = 0; i < 4; i++) {
        int row = wm + i * 16 + fr;
        aOff[i] = row * 32 + ((fq ^ ((row >> 1) & 3)) * 8);
        int col = wn + i * 16 + fr;
        bOff[i] = col * 32 + ((fq ^ ((col >> 1) & 3)) * 8);
    }
    f32x4 acc[4][4] = {};
    for (int kk = 0; kk < K; kk += 32) {
        bf16x8 vah0 = *(const bf16x8*)(AbH + aoff0 + kk);
        bf16x8 vah1 = *(const bf16x8*)(AbH + aoff1 + kk);
        bf16x8 val0 = *(const bf16x8*)(AbL + aoff0 + kk);
        bf16x8 val1 = *(const bf16x8*)(AbL + aoff1 + kk);
        bf16x8 vbh0 = *(const bf16x8*)(BbH + boff0 + kk);
        bf16x8 vbh1 = *(const bf16x8*)(BbH + boff1 + kk);
        bf16x8 vbl0 = *(const bf16x8*)(BbL + boff0 + kk);
        bf16x8 vbl1 = *(const bf16x8*)(BbL + boff1 + kk);
        __syncthreads();
        *(bf16x8*)&AsH[p0 * 8] = vah0;  *(bf16x8*)&AsH[p1 * 8] = vah1;
        *(bf16x8*)&AsL[p0 * 8] = val0;  *(bf16x8*)&AsL[p1 * 8] = val1;
        *(bf16x8*)&BsH[p0 * 8] = vbh0;  *(bf16x8*)&BsH[p1 * 8] = vbh1;
        *(bf16x8*)&BsL[p0 * 8] = vbl0;  *(bf16x8*)&BsL[p1 * 8] = vbl1;
        __syncthreads();
        bf16x8 aH[4], aL[4], bH[4], bL[4];
        #pragma unroll
        for (int i = 0; i < 4; i++) {
            aH[i] = *(const bf16x8*)&AsH[aOff[i]];
            aL[i] = *(const bf16x8*)&AsL[aOff[i]];
            bH[i] = *(const bf16x8*)&BsH[bOff[i]];
            bL[i] = *(const bf16x8*)&BsL[bOff[i]];
        }
        #pragma unroll
        for (int i = 0; i < 4; i++)
        #pragma unroll
        for (int j = 0; j < 4; j++) {
            acc[i][j] = __builtin_amdgcn_mfma_f32_16x16x32_bf16(aH[i], bH[j], acc[i][j], 0, 0, 0);
            acc[i][j] = __builtin_amdgcn_mfma_f32_16x16x32_bf16(aH[i], bL[j], acc[i][j], 0, 0, 0);
            acc[i][j] = __builtin_amdgcn_mfma_f32_16x16x32_bf16(aL[i], bH[j], acc[i][j], 0, 0, 0);
        }
    }
    #pragma unroll
    for (int i = 0; i < 4; i++)
    #pragma unroll
    for (int j = 0; j < 4; j++)
    #pragma unroll
    for (int r = 0; r < 4; r++) {
        int row = bm + wm + i * 16 + fq * 4 + r;
        int col = bn + wn + j * 16 + fr;
        if (row < M) {
            long off = (long)row * cs_m + (long)col * cs_n;
            float v = acc[i][j][r];
            if (bias) v += bias[col];
            if (Oh) {
                bf16 hh, ll; split2(v, hh, ll);
                Oh[off] = hh; Ol[off] = ll;
            } else {
                if (Rb) v += Rb[off];
                Cb[off] = v;
            }
        }
    }
}

// ---- split-precision MFMA flash self-attention ----
// block = (q-tile 64, head, batch), 4 waves x 16 q-rows. S=1024, HD=64.
// QK^T = Qh·Kh+Qh·Kl+Ql·Kh ; softmax fp32 ; PV = Ph·Vh+Ph·Vl+Pl·Vh.
__global__ __launch_bounds__(256) void sa_mfma_kernel(
    const bf16* __restrict__ qh, const bf16* __restrict__ ql,
    bf16* __restrict__ oh, bf16* __restrict__ ol) {
    int qt = blockIdx.x, h = blockIdx.y, b = blockIdx.z;
    __shared__ short KsH[4096], KsL[4096];     // [kv][d], swz: col ^ ((kv&7)<<3)
    __shared__ short VtH[4096], VtL[4096];     // [d][kv], swz: col ^ (((d>>3)&7)<<3)
    __shared__ short PHs[4][1024], PLs[4][1024]; // per-wave P [q][kv], swz: col ^ ((q&7)<<3)
    int t = threadIdx.x, lane = t & 63, w = t >> 6;
    int fr = lane & 15, fq = lane >> 4;
    const short* QH = (const short*)qh;
    const short* QL = (const short*)ql;
    // Q A-frags for this wave (rows w*16+fr), persistent
    long qrow = (long)(b * 1024 + qt * 64 + w * 16 + fr) * 1536 + h * 64;
    bf16x8 Qh2[2], Ql2[2];
    Qh2[0] = *(const bf16x8*)(QH + qrow + fq * 8);
    Qh2[1] = *(const bf16x8*)(QH + qrow + 32 + fq * 8);
    Ql2[0] = *(const bf16x8*)(QL + qrow + fq * 8);
    Ql2[1] = *(const bf16x8*)(QL + qrow + 32 + fq * 8);
    float m_i[4], l_i[4];
    f32x4 o_acc[4] = {};
    #pragma unroll
    for (int i = 0; i < 4; i++) { m_i[i] = -1e30f; l_i[i] = 0.f; }
    // staging: 512 chunks (64 rows x 8 groups of 8), thread covers c0=t, c1=t+256
    int c0 = t, c1 = t + 256;
    int r0 = c0 >> 3, g0 = c0 & 7;
    int r1 = c1 >> 3, g1 = c1 & 7;
    int kd0 = r0 * 64 + ((g0 * 8) ^ ((r0 & 7) << 3));
    int kd1 = r1 * 64 + ((g1 * 8) ^ ((r1 & 7) << 3));
    long kb = (long)(b * 1024) * 1536 + 512 + h * 64;
    long vb = kb + 512;
    short* ph = PHs[w]; short* pl = PLs[w];
    for (int kt = 0; kt < 16; kt++) {
        long ko = kb + (long)(kt * 64) * 1536;
        long vo = vb + (long)(kt * 64) * 1536;
        bf16x8 kh0 = *(const bf16x8*)(QH + ko + (long)r0 * 1536 + g0 * 8);
        bf16x8 kh1 = *(const bf16x8*)(QH + ko + (long)r1 * 1536 + g1 * 8);
        bf16x8 kl0 = *(const bf16x8*)(QL + ko + (long)r0 * 1536 + g0 * 8);
        bf16x8 kl1 = *(const bf16x8*)(QL + ko + (long)r1 * 1536 + g1 * 8);
        bf16x8 vh0 = *(const bf16x8*)(QH + vo + (long)r0 * 1536 + g0 * 8);
        bf16x8 vh1 = *(const bf16x8*)(QH + vo + (long)r1 * 1536 + g1 * 8);
        bf16x8 vl0 = *(const bf16x8*)(QL + vo + (long)r0 * 1536 + g0 * 8);
        bf16x8 vl1 = *(const bf16x8*)(QL + vo + (long)r1 * 1536 + g1 * 8);
        __syncthreads();   // A: previous iteration's Ks/Vt reads complete
        *(bf16x8*)&KsH[kd0] = kh0;  *(bf16x8*)&KsH[kd1] = kh1;
        *(bf16x8*)&KsL[kd0] = kl0;  *(bf16x8*)&KsL[kd1] = kl1;
        #pragma unroll
        for (int j = 0; j < 8; j++) {
            int d0 = g0 * 8 + j;
            int i0 = d0 * 64 + (r0 ^ (((d0 >> 3) & 7) << 3));
            VtH[i0] = ((short*)&vh0)[j];  VtL[i0] = ((short*)&vl0)[j];
            int d1 = g1 * 8 + j;
            int i1 = d1 * 64 + (r1 ^ (((d1 >> 3) & 7) << 3));
            VtH[i1] = ((short*)&vh1)[j];  VtL[i1] = ((short*)&vl1)[j];
        }
        __syncthreads();   // B: staging complete
        // ---- S = Q·K^T ----
        f32x4 s[4] = {};
        #pragma unroll
        for (int cf = 0; cf < 4; cf++) {
            int kvrow = cf * 16 + fr;
            #pragma unroll
            for (int kf = 0; kf < 2; kf++) {
                int idx = kvrow * 64 + ((kf * 32 + fq * 8) ^ ((kvrow & 7) << 3));
                bf16x8 Bh2 = *(const bf16x8*)&KsH[idx];
                bf16x8 Bl2 = *(const bf16x8*)&KsL[idx];
                s[cf] = __builtin_amdgcn_mfma_f32_16x16x32_bf16(Qh2[kf], Bh2, s[cf], 0, 0, 0);
                s[cf] = __builtin_amdgcn_mfma_f32_16x16x32_bf16(Qh2[kf], Bl2, s[cf], 0, 0, 0);
                s[cf] = __builtin_amdgcn_mfma_f32_16x16x32_bf16(Ql2[kf], Bh2, s[cf], 0, 0, 0);
            }
        }
        #pragma unroll
        for (int cf = 0; cf < 4; cf++)
        #pragma unroll
        for (int reg = 0; reg < 4; reg++) s[cf][reg] *= 0.125f;
        // ---- online softmax (row = fq*4+reg, 16 lanes share a row) ----
        float sc_[4];
        #pragma unroll
        for (int reg = 0; reg < 4; reg++) {
            float mx = fmaxf(fmaxf(s[0][reg], s[1][reg]), fmaxf(s[2][reg], s[3][reg]));
            mx = fmaxf(mx, __shfl_xor(mx, 1));
            mx = fmaxf(mx, __shfl_xor(mx, 2));
            mx = fmaxf(mx, __shfl_xor(mx, 4));
            mx = fmaxf(mx, __shfl_xor(mx, 8));
            float mn = fmaxf(m_i[reg], mx);
            sc_[reg] = __expf(m_i[reg] - mn);
            m_i[reg] = mn;
            float rs = 0.f;
            #pragma unroll
            for (int cf = 0; cf < 4; cf++) { s[cf][reg] = __expf(s[cf][reg] - mn); rs += s[cf][reg]; }
            rs += __shfl_xor(rs, 1);
            rs += __shfl_xor(rs, 2);
            rs += __shfl_xor(rs, 4);
            rs += __shfl_xor(rs, 8);
            l_i[reg] = l_i[reg] * sc_[reg] + rs;
        }
        #pragma unroll
        for (int cf = 0; cf < 4; cf++)
        #pragma unroll
        for (int reg = 0; reg < 4; reg++) o_acc[cf][reg] *= sc_[reg];
        // ---- stage P split (per-wave LDS) ----
        #pragma unroll
        for (int cf = 0; cf < 4; cf++)
        #pragma unroll
        for (int reg = 0; reg < 4; reg++) {
            int q = fq * 4 + reg, kv = cf * 16 + fr;
            int idx = q * 64 + (kv ^ ((q & 7) << 3));
            split2s(s[cf][reg], ph[idx], pl[idx]);
        }
        __syncthreads();   // C: P writes visible/ordered before reads
        // ---- O += P·V ----
        bf16x8 Pf_h[2], Pf_l[2];
        #pragma unroll
        for (int kf = 0; kf < 2; kf++) {
            int idx = fr * 64 + ((kf * 32 + fq * 8) ^ ((fr & 7) << 3));
            Pf_h[kf] = *(const bf16x8*)&ph[idx];
            Pf_l[kf] = *(const bf16x8*)&pl[idx];
        }
        #pragma unroll
        for (int cf = 0; cf < 4; cf++) {
            int d = cf * 16 + fr;
            #pragma unroll
            for (int kf = 0; kf < 2; kf++) {
                int idx = d * 64 + ((kf * 32 + fq * 8) ^ (((d >> 3) & 7) << 3));
                bf16x8 Vh2 = *(const bf16x8*)&VtH[idx];
                bf16x8 Vl2 = *(const bf16x8*)&VtL[idx];
                o_acc[cf] = __builtin_amdgcn_mfma_f32_16x16x32_bf16(Pf_h[kf], Vh2, o_acc[cf], 0, 0, 0);
                o_acc[cf] = __builtin_amdgcn_mfma_f32_16x16x32_bf16(Pf_h[kf], Vl2, o_acc[cf], 0, 0, 0);
                o_acc[cf] = __builtin_amdgcn_mfma_f32_16x16x32_bf16(Pf_l[kf], Vh2, o_acc[cf], 0, 0, 0);
            }
        }
    }
    // ---- epilogue: normalize, split, store ----
    #pragma unroll
    for (int reg = 0; reg < 4; reg++) {
        float inv = 1.f / l_i[reg];
        long m = (long)(b * 1024 + qt * 64 + w * 16 + fq * 4 + reg);
        #pragma unroll
        for (int cf = 0; cf < 4; cf++) {
            float v = o_acc[cf][reg] * inv;
            bf16 hh, ll; split2(v, hh, ll);
            long off = m * DIMC + h * 64 + cf * 16 + fr;
            oh[off] = hh; ol[off] = ll;
        }
    }
}

// ---- MoE grouped MFMA GEMM1 (plain bf16): hid = gelu(xn·w1 + b1), K=512 ----
__global__ __launch_bounds__(256) void moe_mfma1_kernel(
    const bf16* __restrict__ xn_b, const bf16* __restrict__ e1T, const float* __restrict__ e_b1,
    const int* __restrict__ table, const int* __restrict__ ntiles, const int* __restrict__ perm,
    bf16* __restrict__ hid_b) {
    if (blockIdx.y >= ntiles[0]) return;
    int e = table[2 * blockIdx.y], row0 = table[2 * blockIdx.y + 1];
    int bn = blockIdx.x * 128;
    __shared__ short As[128 * 32];
    __shared__ short Bs[128 * 32];
    __shared__ int rowsS[128];
    int t = threadIdx.x, lane = t & 63, w = t >> 6;
    if (t < 128) rowsS[t] = perm[row0 + t];
    __syncthreads();
    int wm = (w >> 1) * 64, wn = (w & 1) * 64;
    int p0 = t, p1 = t + 256;
    int r0 = p0 >> 2, k0s = (p0 & 3) ^ ((r0 >> 1) & 3);
    int r1 = p1 >> 2, k1s = (p1 & 3) ^ ((r1 >> 1) & 3);
    int tok0 = rowsS[r0]; if (tok0 < 0) tok0 = 0;
    int tok1 = rowsS[r1]; if (tok1 < 0) tok1 = 0;
    const short* Xs = (const short*)xn_b;
    const short* Ws = (const short*)(e1T + (long)e * HIDC * DIMC);
    const short* a0 = Xs + (long)tok0 * DIMC + k0s * 8;
    const short* a1 = Xs + (long)tok1 * DIMC + k1s * 8;
    const short* b0 = Ws + (long)(bn + r0) * DIMC + k0s * 8;
    const short* b1 = Ws + (long)(bn + r1) * DIMC + k1s * 8;
    int fr = lane & 15, fq = lane >> 4;
    int aOff[4], bOff[4];
    #pragma unroll
    for (int i = 0; i < 4; i++) {
        int row = wm + i * 16 + fr;
        aOff[i] = row * 32 + ((fq ^ ((row >> 1) & 3)) * 8);
        int col = wn + i * 16 + fr;
        bOff[i] = col * 32 + ((fq ^ ((col >> 1) & 3)) * 8);
    }
    f32x4 acc[4][4] = {};
    for (int kk = 0; kk < DIMC; kk += 32) {
        bf16x8 va0 = *(const bf16x8*)(a0 + kk);
        bf16x8 va1 = *(const bf16x8*)(a1 + kk);
        bf16x8 vb0 = *(const bf16x8*)(b0 + kk);
        bf16x8 vb1 = *(const bf16x8*)(b1 + kk);
        __syncthreads();
        *(bf16x8*)&As[p0 * 8] = va0;  *(bf16x8*)&As[p1 * 8] = va1;
        *(bf16x8*)&Bs[p0 * 8] = vb0;  *(bf16x8*)&Bs[p1 * 8] = vb1;
        __syncthreads();
        bf16x8 aF[4], bF[4];
        #pragma unroll
        for (int i = 0; i < 4; i++) {
            aF[i] = *(const bf16x8*)&As[aOff[i]];
            bF[i] = *(const bf16x8*)&Bs[bOff[i]];
        }
        #pragma unroll
        for (int i = 0; i < 4; i++)
        #pragma unroll
        for (int j = 0; j < 4; j++)
            acc[i][j] = __builtin_amdgcn_mfma_f32_16x16x32_bf16(aF[i], bF[j], acc[i][j], 0, 0, 0);
    }
    const float* bb = e_b1 + (long)e * HIDC;
    #pragma unroll
    for (int i = 0; i < 4; i++)
    #pragma unroll
    for (int r = 0; r < 4; r++) {
        int tok = rowsS[wm + i * 16 + fq * 4 + r];
        if (tok < 0) continue;
        #pragma unroll
        for (int j = 0; j < 4; j++) {
            int col = bn + wn + j * 16 + fr;
            float v = acc[i][j][r] + bb[col];
            v = 0.5f * v * (1.f + erff(v * 0.70710678f));
            hid_b[(long)tok * HIDC + col] = __float2bfloat16(v);
        }
    }
}

// ---- MoE grouped MFMA GEMM2 (plain bf16): x_flat += hid·w2 + b2, K=2048 ----
__global__ __launch_bounds__(256) void moe_mfma2_kernel(
    const bf16* __restrict__ hid_b, const bf16* __restrict__ e2T, const float* __restrict__ e_b2,
    const int* __restrict__ table, const int* __restrict__ ntiles, const int* __restrict__ perm,
    float* __restrict__ x_flat) {
    if (blockIdx.y >= ntiles[0]) return;
    int e = table[2 * blockIdx.y], row0 = table[2 * blockIdx.y + 1];
    int bn = blockIdx.x * 128;
    __shared__ short As[128 * 32];
    __shared__ short Bs[128 * 32];
    __shared__ int rowsS[128];
    int t = threadIdx.x, lane = t & 63, w = t >> 6;
    if (t < 128) rowsS[t] = perm[row0 + t];
    __syncthreads();
    int wm = (w >> 1) * 64, wn = (w & 1) * 64;
    int p0 = t, p1 = t + 256;
    int r0 = p0 >> 2, k0s = (p0 & 3) ^ ((r0 >> 1) & 3);
    int r1 = p1 >> 2, k1s = (p1 & 3) ^ ((r1 >> 1) & 3);
    int tok0 = rowsS[r0]; if (tok0 < 0) tok0 = 0;
    int tok1 = rowsS[r1]; if (tok1 < 0) tok1 = 0;
    const short* Hs = (const short*)hid_b;
    const short* Ws = (const short*)(e2T + (long)e * DIMC * HIDC);
    const short* a0 = Hs + (long)tok0 * HIDC + k0s * 8;
    const short* a1 = Hs + (long)tok1 * HIDC + k1s * 8;
    const short* b0 = Ws + (long)(bn + r0) * HIDC + k0s * 8;
    const short* b1 = Ws + (long)(bn + r1) * HIDC + k1s * 8;
    int fr = lane & 15, fq = lane >> 4;
    int aOff[4], bOff[4];
    #pragma unroll
    for (int i = 0; i < 4; i++) {
        int row = wm + i * 16 + fr;
        aOff[i] = row * 32 + ((fq ^ ((row >> 1) & 3)) * 8);
        int col = wn + i * 16 + fr;
        bOff[i] = col * 32 + ((fq ^ ((col >> 1) & 3)) * 8);
    }
    f32x4 acc[4][4] = {};
    for (int kk = 0; kk < HIDC; kk += 32) {
        bf16x8 va0 = *(const bf16x8*)(a0 + kk);
        bf16x8 va1 = *(const bf16x8*)(a1 + kk);
        bf16x8 vb0 = *(const bf16x8*)(b0 + kk);
        bf16x8 vb1 = *(const bf16x8*)(b1 + kk);
        __syncthreads();
        *(bf16x8*)&As[p0 * 8] = va0;  *(bf16x8*)&As[p1 * 8] = va1;
        *(bf16x8*)&Bs[p0 * 8] = vb0;  *(bf16x8*)&Bs[p1 * 8] = vb1;
        __syncthreads();
        bf16x8 aF[4], bF[4];
        #pragma unroll
        for (int i = 0; i < 4; i++) {
            aF[i] = *(const bf16x8*)&As[aOff[i]];
            bF[i] = *(const bf16x8*)&Bs[bOff[i]];
        }
        #pragma unroll
        for (int i = 0; i < 4; i++)
        #pragma unroll
        for (int j = 0; j < 4; j++)
            acc[i][j] = __builtin_amdgcn_mfma_f32_16x16x32_bf16(aF[i], bF[j], acc[i][j], 0, 0, 0);
    }
    const float* bb = e_b2 + (long)e * DIMC;
    #pragma unroll
    for (int i = 0; i < 4; i++)
    #pragma unroll
    for (int r = 0; r < 4; r++) {
        int tok = rowsS[wm + i * 16 + fq * 4 + r];
        if (tok < 0) continue;
        #pragma unroll
        for (int j = 0; j < 4; j++) {
            int col = bn + wn + j * 16 + fr;
            x_flat[(long)tok * DIMC + col] += acc[i][j][r] + bb[col];
        }
    }
}

// ---- fp32 vector GEMM (router feat projection only) ----
__global__ void gemm_kernel(const float* __restrict__ A, const float* __restrict__ Bm,
                            float* __restrict__ C, int M, int N, int K,
                            long as_m, long as_k, long bs_n, long bs_k, long cs_m) {
    __shared__ float As[16][68];
    __shared__ float Bs[16][68];
    int bm = blockIdx.y * 64, bn = blockIdx.x * 64;
    int t = threadIdx.x;
    int tx = t & 15, ty = t >> 4;
    float acc[4][4] = {};
    for (int k0 = 0; k0 < K; k0 += 16) {
        #pragma unroll
        for (int j = 0; j < 4; j++) {
            int e = t + j * 256;
            int mi = e >> 4, ki = e & 15;
            int m = bm + mi, k = k0 + ki;
            As[ki][mi] = (m < M) ? A[(long)m * as_m + (long)k * as_k] : 0.f;
            int n = bn + mi;
            Bs[ki][mi] = (n < N) ? Bm[(long)n * bs_n + (long)k * bs_k] : 0.f;
        }
        __syncthreads();
        #pragma unroll
        for (int kk = 0; kk < 16; kk++) {
            float a[4], b[4];
            #pragma unroll
            for (int i = 0; i < 4; i++) { a[i] = As[kk][ty * 4 + i]; b[i] = Bs[kk][tx * 4 + i]; }
            #pragma unroll
            for (int i = 0; i < 4; i++)
            #pragma unroll
            for (int j2 = 0; j2 < 4; j2++) acc[i][j2] += a[i] * b[j2];
        }
        __syncthreads();
    }
    #pragma unroll
    for (int i = 0; i < 4; i++) {
        int m = bm + ty * 4 + i;
        if (m >= M) continue;
        #pragma unroll
        for (int j2 = 0; j2 < 4; j2++) {
            int n = bn + tx * 4 + j2;
            if (n < N) C[(long)m * cs_m + n] = acc[i][j2];
        }
    }
}

// ---------------- LayerNorm: fp32 + bf16 hi/lo outputs ----------------
__global__ void ln_kernel(const float* __restrict__ x, const float* __restrict__ g,
                          const float* __restrict__ b, float* __restrict__ y,
                          bf16* __restrict__ yh, bf16* __restrict__ yl) {
    int tok = blockIdx.x;
    int t = threadIdx.x;
    const float* xr = x + (long)tok * DIMC;
    float v0 = xr[t], v1 = xr[t + 256];
    __shared__ float red[256];
    red[t] = v0 + v1; __syncthreads();
    for (int s = 128; s > 0; s >>= 1) { if (t < s) red[t] += red[t + s]; __syncthreads(); }
    float mu = red[0] * (1.f / DIMC);
    __syncthreads();
    float d0 = v0 - mu, d1 = v1 - mu;
    red[t] = d0 * d0 + d1 * d1; __syncthreads();
    for (int s = 128; s > 0; s >>= 1) { if (t < s) red[t] += red[t + s]; __syncthreads(); }
    float rs = rsqrtf(red[0] * (1.f / DIMC) + 1e-5f);
    float o0 = d0 * rs * g[t] + b[t];
    float o1 = d1 * rs * g[t + 256] + b[t + 256];
    y[(long)tok * DIMC + t] = o0; y[(long)tok * DIMC + t + 256] = o1;
    bf16 h, l;
    split2(o0, h, l); yh[(long)tok * DIMC + t] = h;       yl[(long)tok * DIMC + t] = l;
    split2(o1, h, l); yh[(long)tok * DIMC + t + 256] = h; yl[(long)tok * DIMC + t + 256] = l;
}

// ---------------- cross-attention (77 keys), hi/lo output ----------------
__global__ void ca_attn_kernel(const float* __restrict__ q, const float* __restrict__ kv,
                               bf16* __restrict__ oh, bf16* __restrict__ ol) {
    int m = blockIdx.x; int h = blockIdx.y; int b = m >> 10;
    int t = threadIdx.x;    // 128
    __shared__ float qs[64];
    __shared__ float sc[77];
    __shared__ float red[128];
    if (t < 64) qs[t] = q[(long)m * DIMC + h * 64 + t];
    __syncthreads();
    float lm = -1e30f;
    if (t < 77) {
        const float* kr = kv + ((long)(b * 77 + t)) * 1024 + h * 64;
        float s = 0.f;
        #pragma unroll 8
        for (int d = 0; d < 64; d++) s += qs[d] * kr[d];
        s *= 0.125f;
        sc[t] = s; lm = s;
    }
    red[t] = lm; __syncthreads();
    for (int s = 64; s > 0; s >>= 1) { if (t < s) red[t] = fmaxf(red[t], red[t + s]); __syncthreads(); }
    float mx = red[0]; __syncthreads();
    float ls = 0.f;
    if (t < 77) { float e = __expf(sc[t] - mx); sc[t] = e; ls = e; }
    red[t] = ls; __syncthreads();
    for (int s = 64; s > 0; s >>= 1) { if (t < s) red[t] += red[t + s]; __syncthreads(); }
    float inv = 1.f / red[0];
    __syncthreads();
    if (t < 64) {
        float acc = 0.f;
        for (int kk = 0; kk < 77; kk++)
            acc += sc[kk] * kv[((long)(b * 77 + kk)) * 1024 + 512 + h * 64 + t];
        bf16 hh, ll; split2(acc * inv, hh, ll);
        oh[(long)m * DIMC + h * 64 + t] = hh;
        ol[(long)m * DIMC + h * 64 + t] = ll;
    }
}

// ---------------- router text part ----------------
__global__ void textpart_kernel(const float* __restrict__ w, const float* __restrict__ r_text_mu,
                                const float* __restrict__ r_comb_mu, float* __restrict__ tp) {
    __shared__ float tw[4][128];
    int t = threadIdx.x;
    for (int j = 0; j < 2; j++) {
        int idx = t + j * 256; int b = idx >> 7, c = idx & 127;
        const float* wr = w + (long)b * LATC;
        float s = 0.f;
        for (int k = 0; k < LATC; k++) s += wr[k] * r_text_mu[(long)k * 128 + c];
        tw[b][c] = s;
    }
    __syncthreads();
    if (t < 32) {
        int b = t >> 3, e = t & 7;
        float s = 0.f;
        for (int c = 0; c < 128; c++) s += tw[b][c] * r_comb_mu[(long)(128 + c) * 8 + e];
        tp[t] = s;
    }
}

// ---------------- MoE meta ----------------
__global__ void moe_init_kernel(int* __restrict__ cnt, int* __restrict__ perm) {
    int g = blockIdx.x * blockDim.x + threadIdx.x;
    if (g < MAXT * 128) perm[g] = -1;
    if (g < NE) cnt[g] = 0;
}

__global__ void route_kernel(const float* __restrict__ feat, const float* __restrict__ tp,
                             const float* __restrict__ r_comb_mu, const float* __restrict__ r_temp,
                             float* __restrict__ onehot, int* __restrict__ idx, int* __restrict__ cnt) {
    int n = blockIdx.x * blockDim.x + threadIdx.x;
    if (n >= NTOK) return;
    int b = n >> 10;
    float tmp = fmaxf(r_temp[0], 0.1f);
    float invt = 1.f / tmp;
    const float* fr = feat + (long)n * 128;
    float lg[8];
    for (int e = 0; e < 8; e++) {
        float s = 0.f;
        for (int c = 0; c < 128; c++) s += fr[c] * r_comb_mu[(long)c * 8 + e];
        lg[e] = (s + tp[b * 8 + e]) * invt;
    }
    float best = lg[0]; int bi = 0;
    for (int e = 1; e < 8; e++) { if (lg[e] > best) { best = lg[e]; bi = e; } }
    for (int e = 0; e < 8; e++) onehot[(long)n * 8 + e] = (e == bi) ? 1.f : 0.f;
    idx[n] = bi;
    atomicAdd(&cnt[bi], 1);
}

__global__ void offsets_kernel(const int* __restrict__ cnt, int* __restrict__ cursor,
                               int* __restrict__ ntiles, int* __restrict__ table) {
    if (threadIdx.x != 0) return;
    int po = 0, nt = 0;
    for (int e = 0; e < NE; e++) {
        cursor[e] = po;
        int tiles = (cnt[e] + 127) >> 7;
        for (int j = 0; j < tiles; j++) { table[2 * nt] = e; table[2 * nt + 1] = po + j * 128; nt++; }
        po += tiles * 128;
    }
    ntiles[0] = nt;
}

__global__ void scatter_kernel(const int* __restrict__ idx, int* __restrict__ cursor,
                               int* __restrict__ perm) {
    int n = blockIdx.x * blockDim.x + threadIdx.x;
    if (n >= NTOK) return;
    int e = idx[n];
    int pos = atomicAdd(&cursor[e], 1);
    perm[pos] = n;
}

extern "C" void kernel_launch(void* const* d_in, const int* in_sizes, int n_in,
                              void* d_out, int out_size, void* d_ws, size_t ws_size,
                              hipStream_t stream) {
    const float* x        = (const float*)d_in[0];
    const float* w        = (const float*)d_in[1];
    const float* text     = (const float*)d_in[2];
    const float* pin_w    = (const float*)d_in[3];
    const float* pin_mw   = (const float*)d_in[4];
    const float* pin_mb   = (const float*)d_in[5];
    const float* pout_w   = (const float*)d_in[6];
    const float* pout_mw  = (const float*)d_in[7];
    const float* pout_mb  = (const float*)d_in[8];
    const float* ln1g     = (const float*)d_in[9];
    const float* ln1b     = (const float*)d_in[10];
    const float* ln2g     = (const float*)d_in[11];
    const float* ln2b     = (const float*)d_in[12];
    const float* ln3g     = (const float*)d_in[13];
    const float* ln3b     = (const float*)d_in[14];
    const float* sa_in_w  = (const float*)d_in[15];
    const float* sa_in_b  = (const float*)d_in[16];
    const float* sa_out_w = (const float*)d_in[17];
    const float* sa_out_b = (const float*)d_in[18];
    const float* ca_in_w  = (const float*)d_in[19];
    const float* ca_in_b  = (const float*)d_in[20];
    const float* ca_out_w = (const float*)d_in[21];
    const float* ca_out_b = (const float*)d_in[22];
    const float* r_feat   = (const float*)d_in[23];
    const float* r_text   = (const float*)d_in[24];
    const float* r_comb   = (const float*)d_in[25];
    const float* r_temp   = (const float*)d_in[26];
    const float* e_w1     = (const float*)d_in[27];
    const float* e_b1     = (const float*)d_in[28];
    const float* e_w2     = (const float*)d_in[29];
    const float* e_b2     = (const float*)d_in[30];

    float* out    = (float*)d_out;               // [B, DIM, H, W]
    float* onehot = out + (long)BB * DIMC * HWX; // [4096, 8]

    // ---------------- workspace: fp32 pool ----------------
    float* f32p = (float*)d_ws;
    float* style_in  = f32p;                 // 2048
    float* style_out = f32p + 2048;          // 2048
    float* tp        = f32p + 4096;          // 32
    int*   idx       = (int*)(f32p + 4128);  // 4096
    int*   cnt       = (int*)(f32p + 8224);  // 8
    int*   cursor    = (int*)(f32p + 8232);  // 8
    int*   ntiles    = (int*)(f32p + 8240);  // 8
    int*   table     = (int*)(f32p + 8248);  // 128
    int*   perm      = (int*)(f32p + 8376);  // 5120 -> ends 13496
    float* x_flat    = f32p + 13496;         // 2097152
    float* xn        = x_flat + 2097152;     // 2097152
    float* qkv       = xn + 2097152;         // 6291456 (fp32 CA q; SA-phase: qh/ql split home)
    float* spill     = qkv + 6291456;        // 2097152 (e2T tail)

    // ---------------- bf16 pool (phase-aliased) ----------------
    bf16* bp = (bf16*)(f32p + 12596408);
    bf16* R1 = bp;                           // 6291456 elems, 3 phases
    bf16* xT_h  = R1;
    bf16* xT_l  = R1 + 2097152;
    bf16* wtA_h = R1 + 4194304;
    bf16* wtA_l = R1 + 5242880;
    bf16* obuf_h = R1;
    bf16* obuf_l = R1 + 2097152;
    float* kvtext = (float*)(R1 + 4194304);            // 315392 fp32
    float* feat   = (float*)(R1 + 4194304 + 630784);   // 524288 fp32
    bf16* wtC_h = R1;
    bf16* wtC_l = R1 + 1048576;
    bf16* xn_h = R1 + 6291456;               // 2097152
    bf16* xn_l = xn_h + 2097152;             // 2097152
    bf16* WB   = xn_l + 2097152;             // 8388608: weights (early) / hid_b (late)
    bf16* text_h   = WB;
    bf16* text_l   = text_h + 157696;
    bf16* sawin_h  = text_l + 157696;
    bf16* sawin_l  = sawin_h + 786432;
    bf16* sawout_h = sawin_l + 786432;
    bf16* sawout_l = sawout_h + 262144;
    bf16* caw_h    = sawout_l + 262144;
    bf16* caw_l    = caw_h + 786432;
    bf16* cawout_h = caw_l + 786432;
    bf16* cawout_l = cawout_h + 262144;
    bf16* hid_b    = WB;                     // overlays weights after ca_out
    bf16* e1T = (bf16*)qkv;                  // [8][2048][512] in qkv+spill
    bf16* e2T = e1T + 8388608;
    bf16* xfl_h = xn_h;
    bf16* xfl_l = xn_l;
    // SA-phase split qkv (aliases the fp32 qkv region exactly)
    bf16* q_h = (bf16*)qkv;                  // [4096][1536]
    bf16* q_l = q_h + 6291456;
    (void)ws_size; (void)spill;

    auto mg = [&](const bf16* Ah, const bf16* Al, const bf16* Bh, const bf16* Bl,
                  const float* bias, const float* resid, float* C, bf16* Oh, bf16* Ol,
                  int M, int N, int K, long ab, long bb, long cb, int csm, int csn, int nb) {
        dim3 g(N / 128, (M + 127) / 128, nb);
        hipLaunchKernelGGL(mgemm_kernel, g, dim3(256), 0, stream,
                           Ah, Al, Bh, Bl, bias, resid, C, Oh, Ol, M, N, K, ab, bb, cb, csm, csn);
    };
    auto cvt2 = [&](const float* in, bf16* h2, bf16* l2, int n) {
        hipLaunchKernelGGL(cvt2_kernel, dim3((n / 4 + 255) / 256), dim3(256), 0, stream, in, h2, l2, n);
    };

    // ---- input conversions (hi/lo) ----
    cvt2(sa_in_w, sawin_h, sawin_l, 1536 * 512);
    cvt2(sa_out_w, sawout_h, sawout_l, 512 * 512);
    cvt2(ca_in_w, caw_h, caw_l, 1536 * 512);
    cvt2(ca_out_w, cawout_h, cawout_l, 512 * 512);
    cvt2(text, text_h, text_l, BB * TXT * 512);
    hipLaunchKernelGGL(trcvt2_kernel, dim3(32, 16, BB), dim3(256), 0, stream,
                       x, xT_h, xT_l, 512, 1024, (long)512 * 1024, (long)1024 * 512);

    // ---- modconv in ----
    hipLaunchKernelGGL(style_kernel, dim3(8), dim3(256), 0, stream, w, pin_mw, pin_mb, style_in);
    hipLaunchKernelGGL(wtmod_kernel, dim3(BB * DIMC), dim3(256), 0, stream, pin_w, style_in, wtA_h, wtA_l);
    mg(xT_h, xT_l, wtA_h, wtA_l, nullptr, nullptr, x_flat, nullptr, nullptr,
       HWX, DIMC, DIMC, (long)HWX * DIMC, (long)DIMC * DIMC, (long)HWX * DIMC, DIMC, 1, BB);

    // ---- LN1 + self-attention (split MFMA path) ----
    hipLaunchKernelGGL(ln_kernel, dim3(NTOK), dim3(256), 0, stream, x_flat, ln1g, ln1b, xn, xn_h, xn_l);
    mg(xn_h, xn_l, sawin_h, sawin_l, sa_in_b, nullptr, nullptr, q_h, q_l,
       NTOK, 1536, 512, 0, 0, 0, 1536, 1, 1);
    hipLaunchKernelGGL(sa_mfma_kernel, dim3(16, HEADS, BB), dim3(256), 0, stream,
                       q_h, q_l, obuf_h, obuf_l);
    mg(obuf_h, obuf_l, sawout_h, sawout_l, sa_out_b, x_flat, x_flat, nullptr, nullptr,
       NTOK, 512, 512, 0, 0, 0, 512, 1, 1);

    // ---- LN2 + cross-attention ----
    hipLaunchKernelGGL(ln_kernel, dim3(NTOK), dim3(256), 0, stream, x_flat, ln2g, ln2b, xn, xn_h, xn_l);
    mg(xn_h, xn_l, caw_h, caw_l, ca_in_b, nullptr, qkv, nullptr, nullptr,
       NTOK, 512, 512, 0, 0, 0, 512, 1, 1);
    mg(text_h, text_l, caw_h + 512 * 512, caw_l + 512 * 512, ca_in_b + 512, nullptr, kvtext,
       nullptr, nullptr, BB * TXT, 1024, 512, 0, 0, 0, 1024, 1, 1);
    hipLaunchKernelGGL(ca_attn_kernel, dim3(NTOK, HEADS), dim3(128), 0, stream, qkv, kvtext, obuf_h, obuf_l);
    // qkv fp32 dead after ca_attn -> build expert weight transposes there
    hipLaunchKernelGGL(trcvt_kernel, dim3(64, 16, NE), dim3(256), 0, stream,
                       e_w1, e1T, 512, 2048, (long)512 * 2048, (long)2048 * 512);
    hipLaunchKernelGGL(trcvt_kernel, dim3(16, 64, NE), dim3(256), 0, stream,
                       e_w2, e2T, 2048, 512, (long)2048 * 512, (long)512 * 2048);
    mg(obuf_h, obuf_l, cawout_h, cawout_l, ca_out_b, x_flat, x_flat, nullptr, nullptr,
       NTOK, 512, 512, 0, 0, 0, 512, 1, 1);

    // ---- LN3 + router ----
    hipLaunchKernelGGL(ln_kernel, dim3(NTOK), dim3(256), 0, stream, x_flat, ln3g, ln3b, xn, xn_h, xn_l);
    hipLaunchKernelGGL(gemm_kernel, dim3(2, 64, 1), dim3(256), 0, stream,
                       xn, r_feat, feat, NTOK, 128, 512, 512L, 1L, 1L, 128L, 128L);
    hipLaunchKernelGGL(textpart_kernel, dim3(1), dim3(256), 0, stream, w, r_text, r_comb, tp);
    hipLaunchKernelGGL(moe_init_kernel, dim3((MAXT * 128 + 255) / 256), dim3(256), 0, stream, cnt, perm);
    hipLaunchKernelGGL(route_kernel, dim3(16), dim3(256), 0, stream, feat, tp, r_comb, r_temp, onehot, idx, cnt);
    hipLaunchKernelGGL(offsets_kernel, dim3(1), dim3(64), 0, stream, cnt, cursor, ntiles, table);
    hipLaunchKernelGGL(scatter_kernel, dim3(16), dim3(256), 0, stream, idx, cursor, perm);

    // ---- MoE grouped MFMA GEMMs ----
    hipLaunchKernelGGL(moe_mfma1_kernel, dim3(HIDC / 128, MAXT), dim3(256), 0, stream,
                       xn_h, e1T, e_b1, table, ntiles, perm, hid_b);
    hipLaunchKernelGGL(moe_mfma2_kernel, dim3(DIMC / 128, MAXT), dim3(256), 0, stream,
                       hid_b, e2T, e_b2, table, ntiles, perm, x_flat);

    // ---- modconv out (split both sides) ----
    cvt2(x_flat, xfl_h, xfl_l, NTOK * DIMC);
    hipLaunchKernelGGL(style_kernel, dim3(8), dim3(256), 0, stream, w, pout_mw, pout_mb, style_out);
    hipLaunchKernelGGL(wtmod_kernel, dim3(BB * DIMC), dim3(256), 0, stream, pout_w, style_out, wtC_h, wtC_l);
    mg(wtC_h, wtC_l, xfl_h, xfl_l, nullptr, nullptr, out, nullptr, nullptr,
       DIMC, HWX, DIMC, (long)DIMC * DIMC, (long)HWX * DIMC, (long)DIMC * HWX, HWX, 1, BB);
}

// Round 7
// 774.380 us; speedup vs baseline: 7.1481x; 1.2169x over previous
//
#include <hip/hip_runtime.h>
#include <hip/hip_bf16.h>
#include <math.h>

#define DIMC 512
#define HEADS 8
#define HD 64
#define BB 4
#define HWX 1024
#define TXT 77
#define LATC 512
#define NE 8
#define HIDC 2048
#define NTOK 4096
#define MAXT 40

typedef __attribute__((ext_vector_type(8))) short bf16x8;
typedef __attribute__((ext_vector_type(4))) float f32x4;
typedef __hip_bfloat16 bf16;

__device__ __forceinline__ void split2(float v, bf16& h, bf16& l) {
    h = __float2bfloat16(v);
    l = __float2bfloat16(v - __bfloat162float(h));
}
__device__ __forceinline__ void split2s(float v, short& h, short& l) {
    bf16 hb, lb; split2(v, hb, lb);
    h = *(short*)&hb; l = *(short*)&lb;
}

// ---------------- style = w @ mod_w.T + mod_b ----------------
__global__ void style_kernel(const float* __restrict__ w, const float* __restrict__ mod_w,
                             const float* __restrict__ mod_b, float* __restrict__ style) {
    int t = blockIdx.x * blockDim.x + threadIdx.x;
    if (t >= BB * DIMC) return;
    int b = t / DIMC, i = t % DIMC;
    const float* wr = w + (long)b * LATC;
    const float* mr = mod_w + (long)i * LATC;
    float s = 0.f;
    #pragma unroll 8
    for (int l = 0; l < LATC; l++) s += wr[l] * mr[l];
    style[t] = s + mod_b[i];
}

// ------- wtmod[b,o,i] -> bf16 hi/lo (demodulated per-sample weight) -------
__global__ void wtmod_kernel(const float* __restrict__ weight, const float* __restrict__ style,
                             bf16* __restrict__ wh, bf16* __restrict__ wl) {
    int bo = blockIdx.x;
    int b = bo / DIMC, o = bo % DIMC;
    const float* wr = weight + (long)o * DIMC;
    const float* sr = style + (long)b * DIMC;
    int t = threadIdx.x;
    float vals[2]; float part = 0.f;
    for (int j = 0; j < 2; j++) {
        int i = t + j * 256;
        float v = wr[i] * sr[i];
        vals[j] = v; part += v * v;
    }
    __shared__ float red[256];
    red[t] = part; __syncthreads();
    for (int s = 128; s > 0; s >>= 1) { if (t < s) red[t] += red[t + s]; __syncthreads(); }
    float d = rsqrtf(red[0] + 1e-8f);
    for (int j = 0; j < 2; j++) {
        int i = t + j * 256;
        bf16 h, l; split2(vals[j] * d, h, l);
        wh[(long)bo * DIMC + i] = h; wl[(long)bo * DIMC + i] = l;
    }
}

// ---------------- fp32 -> bf16 hi/lo convert (flat) ----------------
__global__ void cvt2_kernel(const float* __restrict__ in, bf16* __restrict__ hi,
                            bf16* __restrict__ lo, int n) {
    int i = (blockIdx.x * blockDim.x + threadIdx.x) * 4;
    if (i >= n) return;
    float4 v = *(const float4*)(in + i);
    float a[4] = {v.x, v.y, v.z, v.w};
    #pragma unroll
    for (int j = 0; j < 4; j++) { bf16 h, l; split2(a[j], h, l); hi[i + j] = h; lo[i + j] = l; }
}

// ---------------- fp32 [R][C] -> bf16 [C][R] transpose hi/lo ----------------
__global__ void trcvt2_kernel(const float* __restrict__ in, bf16* __restrict__ hi,
                              bf16* __restrict__ lo, int R, int C, long in_bat, long out_bat) {
    __shared__ float tile[32][33];
    in += (long)blockIdx.z * in_bat; hi += (long)blockIdx.z * out_bat; lo += (long)blockIdx.z * out_bat;
    int c0 = blockIdx.x * 32, r0 = blockIdx.y * 32;
    int tc = threadIdx.x & 31, tr = threadIdx.x >> 5;
    #pragma unroll
    for (int i = 0; i < 4; i++) {
        int r = tr + i * 8;
        tile[r][tc] = in[(long)(r0 + r) * C + c0 + tc];
    }
    __syncthreads();
    #pragma unroll
    for (int i = 0; i < 4; i++) {
        int r = tr + i * 8;
        bf16 h, l; split2(tile[tc][r], h, l);
        hi[(long)(c0 + r) * R + r0 + tc] = h;
        lo[(long)(c0 + r) * R + r0 + tc] = l;
    }
}

// ---------------- fp32 [R][C] -> bf16 [C][R] transpose (single) ----------------
__global__ void trcvt_kernel(const float* __restrict__ in, bf16* __restrict__ out,
                             int R, int C, long in_bat, long out_bat) {
    __shared__ float tile[32][33];
    in += (long)blockIdx.z * in_bat; out += (long)blockIdx.z * out_bat;
    int c0 = blockIdx.x * 32, r0 = blockIdx.y * 32;
    int tc = threadIdx.x & 31, tr = threadIdx.x >> 5;
    #pragma unroll
    for (int i = 0; i < 4; i++) {
        int r = tr + i * 8;
        tile[r][tc] = in[(long)(r0 + r) * C + c0 + tc];
    }
    __syncthreads();
    #pragma unroll
    for (int i = 0; i < 4; i++) {
        int r = tr + i * 8;
        out[(long)(c0 + r) * R + r0 + tc] = __float2bfloat16(tile[tc][r]);
    }
}

// ---- split-precision bf16 MFMA GEMM: C = A·B^T with A=Ah+Al, B=Bh+Bl ----
// acc += Ah·Bh + Ah·Bl + Al·Bh. Output: fp32 C, or split bf16 (Oh/Ol) when Oh!=null.
__global__ __launch_bounds__(256) void mgemm_kernel(
    const bf16* __restrict__ Ah, const bf16* __restrict__ Al,
    const bf16* __restrict__ Bh, const bf16* __restrict__ Bl,
    const float* __restrict__ bias, const float* __restrict__ resid, float* __restrict__ C,
    bf16* __restrict__ Oh, bf16* __restrict__ Ol,
    int M, int N, int K, long a_bat, long b_bat, long c_bat, int cs_m, int cs_n) {
    __shared__ short AsH[128 * 32];
    __shared__ short AsL[128 * 32];
    __shared__ short BsH[128 * 32];
    __shared__ short BsL[128 * 32];
    int bat = blockIdx.z;
    const short* AbH = (const short*)(Ah + (long)bat * a_bat);
    const short* AbL = (const short*)(Al + (long)bat * a_bat);
    const short* BbH = (const short*)(Bh + (long)bat * b_bat);
    const short* BbL = (const short*)(Bl + (long)bat * b_bat);
    float* Cb = C + (long)bat * c_bat;
    const float* Rb = resid ? resid + (long)bat * c_bat : nullptr;
    int bm = blockIdx.y * 128, bn = blockIdx.x * 128;
    int t = threadIdx.x, lane = t & 63, w = t >> 6;
    int wm = (w >> 1) * 64, wn = (w & 1) * 64;
    int p0 = t, p1 = t + 256;
    int r0 = p0 >> 2, k0s = (p0 & 3) ^ ((r0 >> 1) & 3);
    int r1 = p1 >> 2, k1s = (p1 & 3) ^ ((r1 >> 1) & 3);
    int ar0 = bm + r0; if (ar0 > M - 1) ar0 = M - 1;
    int ar1 = bm + r1; if (ar1 > M - 1) ar1 = M - 1;
    long aoff0 = (long)ar0 * K + k0s * 8, aoff1 = (long)ar1 * K + k1s * 8;
    long boff0 = (long)(bn + r0) * K + k0s * 8, boff1 = (long)(bn + r1) * K + k1s * 8;
    int fr = lane & 15, fq = lane >> 4;
    int aOff[4], bOff[4];
    #pragma unroll
    for (int i = 0; i < 4; i++) {
        int row = wm + i * 16 + fr;
        aOff[i] = row * 32 + ((fq ^ ((row >> 1) & 3)) * 8);
        int col = wn + i * 16 + fr;
        bOff[i] = col * 32 + ((fq ^ ((col >> 1) & 3)) * 8);
    }
    f32x4 acc[4][4] = {};
    for (int kk = 0; kk < K; kk += 32) {
        bf16x8 vah0 = *(const bf16x8*)(AbH + aoff0 + kk);
        bf16x8 vah1 = *(const bf16x8*)(AbH + aoff1 + kk);
        bf16x8 val0 = *(const bf16x8*)(AbL + aoff0 + kk);
        bf16x8 val1 = *(const bf16x8*)(AbL + aoff1 + kk);
        bf16x8 vbh0 = *(const bf16x8*)(BbH + boff0 + kk);
        bf16x8 vbh1 = *(const bf16x8*)(BbH + boff1 + kk);
        bf16x8 vbl0 = *(const bf16x8*)(BbL + boff0 + kk);
        bf16x8 vbl1 = *(const bf16x8*)(BbL + boff1 + kk);
        __syncthreads();
        *(bf16x8*)&AsH[p0 * 8] = vah0;  *(bf16x8*)&AsH[p1 * 8] = vah1;
        *(bf16x8*)&AsL[p0 * 8] = val0;  *(bf16x8*)&AsL[p1 * 8] = val1;
        *(bf16x8*)&BsH[p0 * 8] = vbh0;  *(bf16x8*)&BsH[p1 * 8] = vbh1;
        *(bf16x8*)&BsL[p0 * 8] = vbl0;  *(bf16x8*)&BsL[p1 * 8] = vbl1;
        __syncthreads();
        bf16x8 aH[4], aL[4], bH[4], bL[4];
        #pragma unroll
        for (int i = 0; i < 4; i++) {
            aH[i] = *(const bf16x8*)&AsH[aOff[i]];
            aL[i] = *(const bf16x8*)&AsL[aOff[i]];
            bH[i] = *(const bf16x8*)&BsH[bOff[i]];
            bL[i] = *(const bf16x8*)&BsL[bOff[i]];
        }
        #pragma unroll
        for (int i = 0; i < 4; i++)
        #pragma unroll
        for (int j = 0; j < 4; j++) {
            acc[i][j] = __builtin_amdgcn_mfma_f32_16x16x32_bf16(aH[i], bH[j], acc[i][j], 0, 0, 0);
            acc[i][j] = __builtin_amdgcn_mfma_f32_16x16x32_bf16(aH[i], bL[j], acc[i][j], 0, 0, 0);
            acc[i][j] = __builtin_amdgcn_mfma_f32_16x16x32_bf16(aL[i], bH[j], acc[i][j], 0, 0, 0);
        }
    }
    #pragma unroll
    for (int i = 0; i < 4; i++)
    #pragma unroll
    for (int j = 0; j < 4; j++)
    #pragma unroll
    for (int r = 0; r < 4; r++) {
        int row = bm + wm + i * 16 + fq * 4 + r;
        int col = bn + wn + j * 16 + fr;
        if (row < M) {
            long off = (long)row * cs_m + (long)col * cs_n;
            float v = acc[i][j][r];
            if (bias) v += bias[col];
            if (Oh) {
                bf16 hh, ll; split2(v, hh, ll);
                Oh[off] = hh; Ol[off] = ll;
            } else {
                if (Rb) v += Rb[off];
                Cb[off] = v;
            }
        }
    }
}

// ---- split-precision MFMA flash self-attention ----
__global__ __launch_bounds__(256) void sa_mfma_kernel(
    const bf16* __restrict__ qh, const bf16* __restrict__ ql,
    bf16* __restrict__ oh, bf16* __restrict__ ol) {
    int qt = blockIdx.x, h = blockIdx.y, b = blockIdx.z;
    __shared__ short KsH[4096], KsL[4096];     // [kv][d], swz: col ^ ((kv&7)<<3)
    __shared__ short VtH[4096], VtL[4096];     // [d][kv], swz: col ^ (((d>>3)&7)<<3)
    __shared__ short PHs[4][1024], PLs[4][1024]; // per-wave P [q][kv], swz: col ^ ((q&7)<<3)
    int t = threadIdx.x, lane = t & 63, w = t >> 6;
    int fr = lane & 15, fq = lane >> 4;
    const short* QH = (const short*)qh;
    const short* QL = (const short*)ql;
    long qrow = (long)(b * 1024 + qt * 64 + w * 16 + fr) * 1536 + h * 64;
    bf16x8 Qh2[2], Ql2[2];
    Qh2[0] = *(const bf16x8*)(QH + qrow + fq * 8);
    Qh2[1] = *(const bf16x8*)(QH + qrow + 32 + fq * 8);
    Ql2[0] = *(const bf16x8*)(QL + qrow + fq * 8);
    Ql2[1] = *(const bf16x8*)(QL + qrow + 32 + fq * 8);
    float m_i[4], l_i[4];
    f32x4 o_acc[4] = {};
    #pragma unroll
    for (int i = 0; i < 4; i++) { m_i[i] = -1e30f; l_i[i] = 0.f; }
    int c0 = t, c1 = t + 256;
    int r0 = c0 >> 3, g0 = c0 & 7;
    int r1 = c1 >> 3, g1 = c1 & 7;
    int kd0 = r0 * 64 + ((g0 * 8) ^ ((r0 & 7) << 3));
    int kd1 = r1 * 64 + ((g1 * 8) ^ ((r1 & 7) << 3));
    long kb = (long)(b * 1024) * 1536 + 512 + h * 64;
    long vb = kb + 512;
    short* ph = PHs[w]; short* pl = PLs[w];
    for (int kt = 0; kt < 16; kt++) {
        long ko = kb + (long)(kt * 64) * 1536;
        long vo = vb + (long)(kt * 64) * 1536;
        bf16x8 kh0 = *(const bf16x8*)(QH + ko + (long)r0 * 1536 + g0 * 8);
        bf16x8 kh1 = *(const bf16x8*)(QH + ko + (long)r1 * 1536 + g1 * 8);
        bf16x8 kl0 = *(const bf16x8*)(QL + ko + (long)r0 * 1536 + g0 * 8);
        bf16x8 kl1 = *(const bf16x8*)(QL + ko + (long)r1 * 1536 + g1 * 8);
        bf16x8 vh0 = *(const bf16x8*)(QH + vo + (long)r0 * 1536 + g0 * 8);
        bf16x8 vh1 = *(const bf16x8*)(QH + vo + (long)r1 * 1536 + g1 * 8);
        bf16x8 vl0 = *(const bf16x8*)(QL + vo + (long)r0 * 1536 + g0 * 8);
        bf16x8 vl1 = *(const bf16x8*)(QL + vo + (long)r1 * 1536 + g1 * 8);
        __syncthreads();
        *(bf16x8*)&KsH[kd0] = kh0;  *(bf16x8*)&KsH[kd1] = kh1;
        *(bf16x8*)&KsL[kd0] = kl0;  *(bf16x8*)&KsL[kd1] = kl1;
        #pragma unroll
        for (int j = 0; j < 8; j++) {
            int d0 = g0 * 8 + j;
            int i0 = d0 * 64 + (r0 ^ (((d0 >> 3) & 7) << 3));
            VtH[i0] = ((short*)&vh0)[j];  VtL[i0] = ((short*)&vl0)[j];
            int d1 = g1 * 8 + j;
            int i1 = d1 * 64 + (r1 ^ (((d1 >> 3) & 7) << 3));
            VtH[i1] = ((short*)&vh1)[j];  VtL[i1] = ((short*)&vl1)[j];
        }
        __syncthreads();
        f32x4 s[4] = {};
        #pragma unroll
        for (int cf = 0; cf < 4; cf++) {
            int kvrow = cf * 16 + fr;
            #pragma unroll
            for (int kf = 0; kf < 2; kf++) {
                int idx = kvrow * 64 + ((kf * 32 + fq * 8) ^ ((kvrow & 7) << 3));
                bf16x8 Bh2 = *(const bf16x8*)&KsH[idx];
                bf16x8 Bl2 = *(const bf16x8*)&KsL[idx];
                s[cf] = __builtin_amdgcn_mfma_f32_16x16x32_bf16(Qh2[kf], Bh2, s[cf], 0, 0, 0);
                s[cf] = __builtin_amdgcn_mfma_f32_16x16x32_bf16(Qh2[kf], Bl2, s[cf], 0, 0, 0);
                s[cf] = __builtin_amdgcn_mfma_f32_16x16x32_bf16(Ql2[kf], Bh2, s[cf], 0, 0, 0);
            }
        }
        #pragma unroll
        for (int cf = 0; cf < 4; cf++)
        #pragma unroll
        for (int reg = 0; reg < 4; reg++) s[cf][reg] *= 0.125f;
        float sc_[4];
        #pragma unroll
        for (int reg = 0; reg < 4; reg++) {
            float mx = fmaxf(fmaxf(s[0][reg], s[1][reg]), fmaxf(s[2][reg], s[3][reg]));
            mx = fmaxf(mx, __shfl_xor(mx, 1));
            mx = fmaxf(mx, __shfl_xor(mx, 2));
            mx = fmaxf(mx, __shfl_xor(mx, 4));
            mx = fmaxf(mx, __shfl_xor(mx, 8));
            float mn = fmaxf(m_i[reg], mx);
            sc_[reg] = __expf(m_i[reg] - mn);
            m_i[reg] = mn;
            float rs = 0.f;
            #pragma unroll
            for (int cf = 0; cf < 4; cf++) { s[cf][reg] = __expf(s[cf][reg] - mn); rs += s[cf][reg]; }
            rs += __shfl_xor(rs, 1);
            rs += __shfl_xor(rs, 2);
            rs += __shfl_xor(rs, 4);
            rs += __shfl_xor(rs, 8);
            l_i[reg] = l_i[reg] * sc_[reg] + rs;
        }
        #pragma unroll
        for (int cf = 0; cf < 4; cf++)
        #pragma unroll
        for (int reg = 0; reg < 4; reg++) o_acc[cf][reg] *= sc_[reg];
        #pragma unroll
        for (int cf = 0; cf < 4; cf++)
        #pragma unroll
        for (int reg = 0; reg < 4; reg++) {
            int q = fq * 4 + reg, kv = cf * 16 + fr;
            int idx = q * 64 + (kv ^ ((q & 7) << 3));
            split2s(s[cf][reg], ph[idx], pl[idx]);
        }
        __syncthreads();
        bf16x8 Pf_h[2], Pf_l[2];
        #pragma unroll
        for (int kf = 0; kf < 2; kf++) {
            int idx = fr * 64 + ((kf * 32 + fq * 8) ^ ((fr & 7) << 3));
            Pf_h[kf] = *(const bf16x8*)&ph[idx];
            Pf_l[kf] = *(const bf16x8*)&pl[idx];
        }
        #pragma unroll
        for (int cf = 0; cf < 4; cf++) {
            int d = cf * 16 + fr;
            #pragma unroll
            for (int kf = 0; kf < 2; kf++) {
                int idx = d * 64 + ((kf * 32 + fq * 8) ^ (((d >> 3) & 7) << 3));
                bf16x8 Vh2 = *(const bf16x8*)&VtH[idx];
                bf16x8 Vl2 = *(const bf16x8*)&VtL[idx];
                o_acc[cf] = __builtin_amdgcn_mfma_f32_16x16x32_bf16(Pf_h[kf], Vh2, o_acc[cf], 0, 0, 0);
                o_acc[cf] = __builtin_amdgcn_mfma_f32_16x16x32_bf16(Pf_h[kf], Vl2, o_acc[cf], 0, 0, 0);
                o_acc[cf] = __builtin_amdgcn_mfma_f32_16x16x32_bf16(Pf_l[kf], Vh2, o_acc[cf], 0, 0, 0);
            }
        }
    }
    #pragma unroll
    for (int reg = 0; reg < 4; reg++) {
        float inv = 1.f / l_i[reg];
        long m = (long)(b * 1024 + qt * 64 + w * 16 + fq * 4 + reg);
        #pragma unroll
        for (int cf = 0; cf < 4; cf++) {
            float v = o_acc[cf][reg] * inv;
            bf16 hh, ll; split2(v, hh, ll);
            long off = m * DIMC + h * 64 + cf * 16 + fr;
            oh[off] = hh; ol[off] = ll;
        }
    }
}

// ---- split-precision MFMA cross-attention: 77 keys padded to 96, single tile ----
// block = (q-tile 64, head, batch), 4 waves x 16 q-rows. Exact softmax, 1/l folded into P.
__global__ __launch_bounds__(256) void ca_mfma_kernel(
    const bf16* __restrict__ qh, const bf16* __restrict__ ql,
    const bf16* __restrict__ kvh, const bf16* __restrict__ kvl,
    bf16* __restrict__ oh, bf16* __restrict__ ol) {
    int qt = blockIdx.x, h = blockIdx.y, b = blockIdx.z;
    __shared__ short UH[8192], UL[8192];          // K [96][64] swz -> reused as Vt [64][128] swz
    __shared__ short PHs[4][2048], PLs[4][2048];  // per-wave P [16 q][128 kv-padded]
    int t = threadIdx.x, lane = t & 63, w = t >> 6;
    int fr = lane & 15, fq = lane >> 4;
    const short* QH = (const short*)qh;
    const short* QL = (const short*)ql;
    const short* KVH = (const short*)kvh;
    const short* KVL = (const short*)kvl;
    // Q A-frags (rows w*16+fr)
    long qrow = (long)(b * 1024 + qt * 64 + w * 16 + fr) * DIMC + h * 64;
    bf16x8 Qh2[2], Ql2[2];
    Qh2[0] = *(const bf16x8*)(QH + qrow + fq * 8);
    Qh2[1] = *(const bf16x8*)(QH + qrow + 32 + fq * 8);
    Ql2[0] = *(const bf16x8*)(QL + qrow + fq * 8);
    Ql2[1] = *(const bf16x8*)(QL + qrow + 32 + fq * 8);
    // ---- stage K [96][64] (rows >= 77 zero) ----
    for (int c = t; c < 768; c += 256) {
        int r = c >> 3, g = c & 7;
        int idx = r * 64 + ((g * 8) ^ ((r & 7) << 3));
        bf16x8 vh = {}, vl = {};
        if (r < 77) {
            long src = (long)(b * 77 + r) * 1024 + h * 64 + g * 8;
            vh = *(const bf16x8*)(KVH + src);
            vl = *(const bf16x8*)(KVL + src);
        }
        *(bf16x8*)&UH[idx] = vh;
        *(bf16x8*)&UL[idx] = vl;
    }
    __syncthreads();
    // ---- S = Q·K^T (cf 0..4 cover kv 0..79; 80..95 masked) ----
    f32x4 s[5] = {};
    #pragma unroll
    for (int cf = 0; cf < 5; cf++) {
        int kvrow = cf * 16 + fr;
        #pragma unroll
        for (int kf = 0; kf < 2; kf++) {
            int idx = kvrow * 64 + ((kf * 32 + fq * 8) ^ ((kvrow & 7) << 3));
            bf16x8 Bh2 = *(const bf16x8*)&UH[idx];
            bf16x8 Bl2 = *(const bf16x8*)&UL[idx];
            s[cf] = __builtin_amdgcn_mfma_f32_16x16x32_bf16(Qh2[kf], Bh2, s[cf], 0, 0, 0);
            s[cf] = __builtin_amdgcn_mfma_f32_16x16x32_bf16(Qh2[kf], Bl2, s[cf], 0, 0, 0);
            s[cf] = __builtin_amdgcn_mfma_f32_16x16x32_bf16(Ql2[kf], Bh2, s[cf], 0, 0, 0);
        }
    }
    #pragma unroll
    for (int cf = 0; cf < 5; cf++) {
        int kv = cf * 16 + fr;
        #pragma unroll
        for (int reg = 0; reg < 4; reg++)
            s[cf][reg] = (kv < 77) ? s[cf][reg] * 0.125f : -1e30f;
    }
    // ---- exact softmax per q-row (row = fq*4+reg, 16 lanes share a row) ----
    float inv[4];
    #pragma unroll
    for (int reg = 0; reg < 4; reg++) {
        float mx = s[0][reg];
        #pragma unroll
        for (int cf = 1; cf < 5; cf++) mx = fmaxf(mx, s[cf][reg]);
        mx = fmaxf(mx, __shfl_xor(mx, 1));
        mx = fmaxf(mx, __shfl_xor(mx, 2));
        mx = fmaxf(mx, __shfl_xor(mx, 4));
        mx = fmaxf(mx, __shfl_xor(mx, 8));
        float rs = 0.f;
        #pragma unroll
        for (int cf = 0; cf < 5; cf++) { s[cf][reg] = __expf(s[cf][reg] - mx); rs += s[cf][reg]; }
        rs += __shfl_xor(rs, 1);
        rs += __shfl_xor(rs, 2);
        rs += __shfl_xor(rs, 4);
        rs += __shfl_xor(rs, 8);
        inv[reg] = 1.f / rs;
    }
    // ---- stage P (normalized), cols 80..127 zero ----
    short* ph = PHs[w]; short* pl = PLs[w];
    #pragma unroll
    for (int cf = 0; cf < 6; cf++)
    #pragma unroll
    for (int reg = 0; reg < 4; reg++) {
        int q = fq * 4 + reg, kv = cf * 16 + fr;
        int idx = q * 128 + (kv ^ ((q & 7) << 3));
        float pv = (cf < 5) ? s[cf][reg] * inv[reg] : 0.f;
        split2s(pv, ph[idx], pl[idx]);
    }
    __syncthreads();    // all K reads done; P visible
    // ---- re-stage U as V^T [64][128] (kv >= 77 zero) ----
    for (int c = t; c < 768; c += 256) {
        int r = c >> 3, g = c & 7;
        bf16x8 vh = {}, vl = {};
        if (r < 77) {
            long src = (long)(b * 77 + r) * 1024 + 512 + h * 64 + g * 8;
            vh = *(const bf16x8*)(KVH + src);
            vl = *(const bf16x8*)(KVL + src);
        }
        #pragma unroll
        for (int j = 0; j < 8; j++) {
            int d = g * 8 + j;
            int idx = d * 128 + (r ^ (((d >> 3) & 7) << 3));
            UH[idx] = ((short*)&vh)[j];
            UL[idx] = ((short*)&vl)[j];
        }
    }
    __syncthreads();
    // ---- O = P·V ----
    f32x4 o_acc[4] = {};
    bf16x8 Pf_h[3], Pf_l[3];
    #pragma unroll
    for (int kf = 0; kf < 3; kf++) {
        int idx = fr * 128 + ((kf * 32 + fq * 8) ^ ((fr & 7) << 3));
        Pf_h[kf] = *(const bf16x8*)&ph[idx];
        Pf_l[kf] = *(const bf16x8*)&pl[idx];
    }
    #pragma unroll
    for (int cf = 0; cf < 4; cf++) {
        int d = cf * 16 + fr;
        #pragma unroll
        for (int kf = 0; kf < 3; kf++) {
            int idx = d * 128 + ((kf * 32 + fq * 8) ^ (((d >> 3) & 7) << 3));
            bf16x8 Vh2 = *(const bf16x8*)&UH[idx];
            bf16x8 Vl2 = *(const bf16x8*)&UL[idx];
            o_acc[cf] = __builtin_amdgcn_mfma_f32_16x16x32_bf16(Pf_h[kf], Vh2, o_acc[cf], 0, 0, 0);
            o_acc[cf] = __builtin_amdgcn_mfma_f32_16x16x32_bf16(Pf_h[kf], Vl2, o_acc[cf], 0, 0, 0);
            o_acc[cf] = __builtin_amdgcn_mfma_f32_16x16x32_bf16(Pf_l[kf], Vh2, o_acc[cf], 0, 0, 0);
        }
    }
    // ---- epilogue: split store ----
    #pragma unroll
    for (int reg = 0; reg < 4; reg++) {
        long m = (long)(b * 1024 + qt * 64 + w * 16 + fq * 4 + reg);
        #pragma unroll
        for (int cf = 0; cf < 4; cf++) {
            bf16 hh, ll; split2(o_acc[cf][reg], hh, ll);
            long off = m * DIMC + h * 64 + cf * 16 + fr;
            oh[off] = hh; ol[off] = ll;
        }
    }
}

// ---- MoE grouped MFMA GEMM1 (plain bf16): hid = gelu(xn·w1 + b1), K=512 ----
__global__ __launch_bounds__(256) void moe_mfma1_kernel(
    const bf16* __restrict__ xn_b, const bf16* __restrict__ e1T, const float* __restrict__ e_b1,
    const int* __restrict__ table, const int* __restrict__ ntiles, const int* __restrict__ perm,
    bf16* __restrict__ hid_b) {
    if (blockIdx.y >= ntiles[0]) return;
    int e = table[2 * blockIdx.y], row0 = table[2 * blockIdx.y + 1];
    int bn = blockIdx.x * 128;
    __shared__ short As[128 * 32];
    __shared__ short Bs[128 * 32];
    __shared__ int rowsS[128];
    int t = threadIdx.x, lane = t & 63, w = t >> 6;
    if (t < 128) rowsS[t] = perm[row0 + t];
    __syncthreads();
    int wm = (w >> 1) * 64, wn = (w & 1) * 64;
    int p0 = t, p1 = t + 256;
    int r0 = p0 >> 2, k0s = (p0 & 3) ^ ((r0 >> 1) & 3);
    int r1 = p1 >> 2, k1s = (p1 & 3) ^ ((r1 >> 1) & 3);
    int tok0 = rowsS[r0]; if (tok0 < 0) tok0 = 0;
    int tok1 = rowsS[r1]; if (tok1 < 0) tok1 = 0;
    const short* Xs = (const short*)xn_b;
    const short* Ws = (const short*)(e1T + (long)e * HIDC * DIMC);
    const short* a0 = Xs + (long)tok0 * DIMC + k0s * 8;
    const short* a1 = Xs + (long)tok1 * DIMC + k1s * 8;
    const short* b0 = Ws + (long)(bn + r0) * DIMC + k0s * 8;
    const short* b1 = Ws + (long)(bn + r1) * DIMC + k1s * 8;
    int fr = lane & 15, fq = lane >> 4;
    int aOff[4], bOff[4];
    #pragma unroll
    for (int i = 0; i < 4; i++) {
        int row = wm + i * 16 + fr;
        aOff[i] = row * 32 + ((fq ^ ((row >> 1) & 3)) * 8);
        int col = wn + i * 16 + fr;
        bOff[i] = col * 32 + ((fq ^ ((col >> 1) & 3)) * 8);
    }
    f32x4 acc[4][4] = {};
    for (int kk = 0; kk < DIMC; kk += 32) {
        bf16x8 va0 = *(const bf16x8*)(a0 + kk);
        bf16x8 va1 = *(const bf16x8*)(a1 + kk);
        bf16x8 vb0 = *(const bf16x8*)(b0 + kk);
        bf16x8 vb1 = *(const bf16x8*)(b1 + kk);
        __syncthreads();
        *(bf16x8*)&As[p0 * 8] = va0;  *(bf16x8*)&As[p1 * 8] = va1;
        *(bf16x8*)&Bs[p0 * 8] = vb0;  *(bf16x8*)&Bs[p1 * 8] = vb1;
        __syncthreads();
        bf16x8 aF[4], bF[4];
        #pragma unroll
        for (int i = 0; i < 4; i++) {
            aF[i] = *(const bf16x8*)&As[aOff[i]];
            bF[i] = *(const bf16x8*)&Bs[bOff[i]];
        }
        #pragma unroll
        for (int i = 0; i < 4; i++)
        #pragma unroll
        for (int j = 0; j < 4; j++)
            acc[i][j] = __builtin_amdgcn_mfma_f32_16x16x32_bf16(aF[i], bF[j], acc[i][j], 0, 0, 0);
    }
    const float* bb = e_b1 + (long)e * HIDC;
    #pragma unroll
    for (int i = 0; i < 4; i++)
    #pragma unroll
    for (int r = 0; r < 4; r++) {
        int tok = rowsS[wm + i * 16 + fq * 4 + r];
        if (tok < 0) continue;
        #pragma unroll
        for (int j = 0; j < 4; j++) {
            int col = bn + wn + j * 16 + fr;
            float v = acc[i][j][r] + bb[col];
            v = 0.5f * v * (1.f + erff(v * 0.70710678f));
            hid_b[(long)tok * HIDC + col] = __float2bfloat16(v);
        }
    }
}

// ---- MoE grouped MFMA GEMM2 (plain bf16): x_flat += hid·w2 + b2, K=2048 ----
__global__ __launch_bounds__(256) void moe_mfma2_kernel(
    const bf16* __restrict__ hid_b, const bf16* __restrict__ e2T, const float* __restrict__ e_b2,
    const int* __restrict__ table, const int* __restrict__ ntiles, const int* __restrict__ perm,
    float* __restrict__ x_flat) {
    if (blockIdx.y >= ntiles[0]) return;
    int e = table[2 * blockIdx.y], row0 = table[2 * blockIdx.y + 1];
    int bn = blockIdx.x * 128;
    __shared__ short As[128 * 32];
    __shared__ short Bs[128 * 32];
    __shared__ int rowsS[128];
    int t = threadIdx.x, lane = t & 63, w = t >> 6;
    if (t < 128) rowsS[t] = perm[row0 + t];
    __syncthreads();
    int wm = (w >> 1) * 64, wn = (w & 1) * 64;
    int p0 = t, p1 = t + 256;
    int r0 = p0 >> 2, k0s = (p0 & 3) ^ ((r0 >> 1) & 3);
    int r1 = p1 >> 2, k1s = (p1 & 3) ^ ((r1 >> 1) & 3);
    int tok0 = rowsS[r0]; if (tok0 < 0) tok0 = 0;
    int tok1 = rowsS[r1]; if (tok1 < 0) tok1 = 0;
    const short* Hs = (const short*)hid_b;
    const short* Ws = (const short*)(e2T + (long)e * DIMC * HIDC);
    const short* a0 = Hs + (long)tok0 * HIDC + k0s * 8;
    const short* a1 = Hs + (long)tok1 * HIDC + k1s * 8;
    const short* b0 = Ws + (long)(bn + r0) * HIDC + k0s * 8;
    const short* b1 = Ws + (long)(bn + r1) * HIDC + k1s * 8;
    int fr = lane & 15, fq = lane >> 4;
    int aOff[4], bOff[4];
    #pragma unroll
    for (int i = 0; i < 4; i++) {
        int row = wm + i * 16 + fr;
        aOff[i] = row * 32 + ((fq ^ ((row >> 1) & 3)) * 8);
        int col = wn + i * 16 + fr;
        bOff[i] = col * 32 + ((fq ^ ((col >> 1) & 3)) * 8);
    }
    f32x4 acc[4][4] = {};
    for (int kk = 0; kk < HIDC; kk += 32) {
        bf16x8 va0 = *(const bf16x8*)(a0 + kk);
        bf16x8 va1 = *(const bf16x8*)(a1 + kk);
        bf16x8 vb0 = *(const bf16x8*)(b0 + kk);
        bf16x8 vb1 = *(const bf16x8*)(b1 + kk);
        __syncthreads();
        *(bf16x8*)&As[p0 * 8] = va0;  *(bf16x8*)&As[p1 * 8] = va1;
        *(bf16x8*)&Bs[p0 * 8] = vb0;  *(bf16x8*)&Bs[p1 * 8] = vb1;
        __syncthreads();
        bf16x8 aF[4], bF[4];
        #pragma unroll
        for (int i = 0; i < 4; i++) {
            aF[i] = *(const bf16x8*)&As[aOff[i]];
            bF[i] = *(const bf16x8*)&Bs[bOff[i]];
        }
        #pragma unroll
        for (int i = 0; i < 4; i++)
        #pragma unroll
        for (int j = 0; j < 4; j++)
            acc[i][j] = __builtin_amdgcn_mfma_f32_16x16x32_bf16(aF[i], bF[j], acc[i][j], 0, 0, 0);
    }
    const float* bb = e_b2 + (long)e * DIMC;
    #pragma unroll
    for (int i = 0; i < 4; i++)
    #pragma unroll
    for (int r = 0; r < 4; r++) {
        int tok = rowsS[wm + i * 16 + fq * 4 + r];
        if (tok < 0) continue;
        #pragma unroll
        for (int j = 0; j < 4; j++) {
            int col = bn + wn + j * 16 + fr;
            x_flat[(long)tok * DIMC + col] += acc[i][j][r] + bb[col];
        }
    }
}

// ---- fp32 vector GEMM (router feat projection only) ----
__global__ void gemm_kernel(const float* __restrict__ A, const float* __restrict__ Bm,
                            float* __restrict__ C, int M, int N, int K,
                            long as_m, long as_k, long bs_n, long bs_k, long cs_m) {
    __shared__ float As[16][68];
    __shared__ float Bs[16][68];
    int bm = blockIdx.y * 64, bn = blockIdx.x * 64;
    int t = threadIdx.x;
    int tx = t & 15, ty = t >> 4;
    float acc[4][4] = {};
    for (int k0 = 0; k0 < K; k0 += 16) {
        #pragma unroll
        for (int j = 0; j < 4; j++) {
            int e = t + j * 256;
            int mi = e >> 4, ki = e & 15;
            int m = bm + mi, k = k0 + ki;
            As[ki][mi] = (m < M) ? A[(long)m * as_m + (long)k * as_k] : 0.f;
            int n = bn + mi;
            Bs[ki][mi] = (n < N) ? Bm[(long)n * bs_n + (long)k * bs_k] : 0.f;
        }
        __syncthreads();
        #pragma unroll
        for (int kk = 0; kk < 16; kk++) {
            float a[4], b[4];
            #pragma unroll
            for (int i = 0; i < 4; i++) { a[i] = As[kk][ty * 4 + i]; b[i] = Bs[kk][tx * 4 + i]; }
            #pragma unroll
            for (int i = 0; i < 4; i++)
            #pragma unroll
            for (int j2 = 0; j2 < 4; j2++) acc[i][j2] += a[i] * b[j2];
        }
        __syncthreads();
    }
    #pragma unroll
    for (int i = 0; i < 4; i++) {
        int m = bm + ty * 4 + i;
        if (m >= M) continue;
        #pragma unroll
        for (int j2 = 0; j2 < 4; j2++) {
            int n = bn + tx * 4 + j2;
            if (n < N) C[(long)m * cs_m + n] = acc[i][j2];
        }
    }
}

// ---------------- LayerNorm: fp32 + bf16 hi/lo outputs ----------------
__global__ void ln_kernel(const float* __restrict__ x, const float* __restrict__ g,
                          const float* __restrict__ b, float* __restrict__ y,
                          bf16* __restrict__ yh, bf16* __restrict__ yl) {
    int tok = blockIdx.x;
    int t = threadIdx.x;
    const float* xr = x + (long)tok * DIMC;
    float v0 = xr[t], v1 = xr[t + 256];
    __shared__ float red[256];
    red[t] = v0 + v1; __syncthreads();
    for (int s = 128; s > 0; s >>= 1) { if (t < s) red[t] += red[t + s]; __syncthreads(); }
    float mu = red[0] * (1.f / DIMC);
    __syncthreads();
    float d0 = v0 - mu, d1 = v1 - mu;
    red[t] = d0 * d0 + d1 * d1; __syncthreads();
    for (int s = 128; s > 0; s >>= 1) { if (t < s) red[t] += red[t + s]; __syncthreads(); }
    float rs = rsqrtf(red[0] * (1.f / DIMC) + 1e-5f);
    float o0 = d0 * rs * g[t] + b[t];
    float o1 = d1 * rs * g[t + 256] + b[t + 256];
    y[(long)tok * DIMC + t] = o0; y[(long)tok * DIMC + t + 256] = o1;
    bf16 h, l;
    split2(o0, h, l); yh[(long)tok * DIMC + t] = h;       yl[(long)tok * DIMC + t] = l;
    split2(o1, h, l); yh[(long)tok * DIMC + t + 256] = h; yl[(long)tok * DIMC + t + 256] = l;
}

// ---------------- router text part ----------------
__global__ void textpart_kernel(const float* __restrict__ w, const float* __restrict__ r_text_mu,
                                const float* __restrict__ r_comb_mu, float* __restrict__ tp) {
    __shared__ float tw[4][128];
    int t = threadIdx.x;
    for (int j = 0; j < 2; j++) {
        int idx = t + j * 256; int b = idx >> 7, c = idx & 127;
        const float* wr = w + (long)b * LATC;
        float s = 0.f;
        for (int k = 0; k < LATC; k++) s += wr[k] * r_text_mu[(long)k * 128 + c];
        tw[b][c] = s;
    }
    __syncthreads();
    if (t < 32) {
        int b = t >> 3, e = t & 7;
        float s = 0.f;
        for (int c = 0; c < 128; c++) s += tw[b][c] * r_comb_mu[(long)(128 + c) * 8 + e];
        tp[t] = s;
    }
}

// ---------------- MoE meta ----------------
__global__ void moe_init_kernel(int* __restrict__ cnt, int* __restrict__ perm) {
    int g = blockIdx.x * blockDim.x + threadIdx.x;
    if (g < MAXT * 128) perm[g] = -1;
    if (g < NE) cnt[g] = 0;
}

__global__ void route_kernel(const float* __restrict__ feat, const float* __restrict__ tp,
                             const float* __restrict__ r_comb_mu, const float* __restrict__ r_temp,
                             float* __restrict__ onehot, int* __restrict__ idx, int* __restrict__ cnt) {
    int n = blockIdx.x * blockDim.x + threadIdx.x;
    if (n >= NTOK) return;
    int b = n >> 10;
    float tmp = fmaxf(r_temp[0], 0.1f);
    float invt = 1.f / tmp;
    const float* fr = feat + (long)n * 128;
    float lg[8];
    for (int e = 0; e < 8; e++) {
        float s = 0.f;
        for (int c = 0; c < 128; c++) s += fr[c] * r_comb_mu[(long)c * 8 + e];
        lg[e] = (s + tp[b * 8 + e]) * invt;
    }
    float best = lg[0]; int bi = 0;
    for (int e = 1; e < 8; e++) { if (lg[e] > best) { best = lg[e]; bi = e; } }
    for (int e = 0; e < 8; e++) onehot[(long)n * 8 + e] = (e == bi) ? 1.f : 0.f;
    idx[n] = bi;
    atomicAdd(&cnt[bi], 1);
}

__global__ void offsets_kernel(const int* __restrict__ cnt, int* __restrict__ cursor,
                               int* __restrict__ ntiles, int* __restrict__ table) {
    if (threadIdx.x != 0) return;
    int po = 0, nt = 0;
    for (int e = 0; e < NE; e++) {
        cursor[e] = po;
        int tiles = (cnt[e] + 127) >> 7;
        for (int j = 0; j < tiles; j++) { table[2 * nt] = e; table[2 * nt + 1] = po + j * 128; nt++; }
        po += tiles * 128;
    }
    ntiles[0] = nt;
}

__global__ void scatter_kernel(const int* __restrict__ idx, int* __restrict__ cursor,
                               int* __restrict__ perm) {
    int n = blockIdx.x * blockDim.x + threadIdx.x;
    if (n >= NTOK) return;
    int e = idx[n];
    int pos = atomicAdd(&cursor[e], 1);
    perm[pos] = n;
}

extern "C" void kernel_launch(void* const* d_in, const int* in_sizes, int n_in,
                              void* d_out, int out_size, void* d_ws, size_t ws_size,
                              hipStream_t stream) {
    const float* x        = (const float*)d_in[0];
    const float* w        = (const float*)d_in[1];
    const float* text     = (const float*)d_in[2];
    const float* pin_w    = (const float*)d_in[3];
    const float* pin_mw   = (const float*)d_in[4];
    const float* pin_mb   = (const float*)d_in[5];
    const float* pout_w   = (const float*)d_in[6];
    const float* pout_mw  = (const float*)d_in[7];
    const float* pout_mb  = (const float*)d_in[8];
    const float* ln1g     = (const float*)d_in[9];
    const float* ln1b     = (const float*)d_in[10];
    const float* ln2g     = (const float*)d_in[11];
    const float* ln2b     = (const float*)d_in[12];
    const float* ln3g     = (const float*)d_in[13];
    const float* ln3b     = (const float*)d_in[14];
    const float* sa_in_w  = (const float*)d_in[15];
    const float* sa_in_b  = (const float*)d_in[16];
    const float* sa_out_w = (const float*)d_in[17];
    const float* sa_out_b = (const float*)d_in[18];
    const float* ca_in_w  = (const float*)d_in[19];
    const float* ca_in_b  = (const float*)d_in[20];
    const float* ca_out_w = (const float*)d_in[21];
    const float* ca_out_b = (const float*)d_in[22];
    const float* r_feat   = (const float*)d_in[23];
    const float* r_text   = (const float*)d_in[24];
    const float* r_comb   = (const float*)d_in[25];
    const float* r_temp   = (const float*)d_in[26];
    const float* e_w1     = (const float*)d_in[27];
    const float* e_b1     = (const float*)d_in[28];
    const float* e_w2     = (const float*)d_in[29];
    const float* e_b2     = (const float*)d_in[30];

    float* out    = (float*)d_out;               // [B, DIM, H, W]
    float* onehot = out + (long)BB * DIMC * HWX; // [4096, 8]

    // ---------------- workspace: fp32 pool ----------------
    float* f32p = (float*)d_ws;
    float* style_in  = f32p;                 // 2048
    float* style_out = f32p + 2048;          // 2048
    float* tp        = f32p + 4096;          // 32
    int*   idx       = (int*)(f32p + 4128);  // 4096
    int*   cnt       = (int*)(f32p + 8224);  // 8
    int*   cursor    = (int*)(f32p + 8232);  // 8
    int*   ntiles    = (int*)(f32p + 8240);  // 8
    int*   table     = (int*)(f32p + 8248);  // 128
    int*   perm      = (int*)(f32p + 8376);  // 5120 -> ends 13496
    float* x_flat    = f32p + 13496;         // 2097152
    float* xn        = x_flat + 2097152;     // 2097152
    float* qkv       = xn + 2097152;         // 6291456 (SA q split / CA q split home)
    float* spill     = qkv + 6291456;        // 2097152 (e2T tail)

    // ---------------- bf16 pool (phase-aliased) ----------------
    bf16* bp = (bf16*)(f32p + 12596408);
    bf16* R1 = bp;                           // 6291456 elems, 3 phases
    bf16* xT_h  = R1;
    bf16* xT_l  = R1 + 2097152;
    bf16* wtA_h = R1 + 4194304;
    bf16* wtA_l = R1 + 5242880;
    bf16* obuf_h = R1;
    bf16* obuf_l = R1 + 2097152;
    bf16* kvt_h  = R1 + 4194304;                       // [308][1024] split
    bf16* kvt_l  = kvt_h + 315392;
    float* feat  = (float*)(kvt_l + 315392);           // 524288 fp32
    bf16* wtC_h = R1;
    bf16* wtC_l = R1 + 1048576;
    bf16* xn_h = R1 + 6291456;               // 2097152
    bf16* xn_l = xn_h + 2097152;             // 2097152
    bf16* WB   = xn_l + 2097152;             // 8388608: weights (early) / hid_b (late)
    bf16* text_h   = WB;
    bf16* text_l   = text_h + 157696;
    bf16* sawin_h  = text_l + 157696;
    bf16* sawin_l  = sawin_h + 786432;
    bf16* sawout_h = sawin_l + 786432;
    bf16* sawout_l = sawout_h + 262144;
    bf16* caw_h    = sawout_l + 262144;
    bf16* caw_l    = caw_h + 786432;
    bf16* cawout_h = caw_l + 786432;
    bf16* cawout_l = cawout_h + 262144;
    bf16* hid_b    = WB;                     // overlays weights after ca_out
    bf16* e1T = (bf16*)qkv;                  // [8][2048][512] in qkv+spill
    bf16* e2T = e1T + 8388608;
    bf16* xfl_h = xn_h;
    bf16* xfl_l = xn_l;
    // SA-phase split qkv (aliases the fp32 qkv region)
    bf16* q_h = (bf16*)qkv;                  // [4096][1536]
    bf16* q_l = q_h + 6291456;
    // CA-phase split q (re-uses same region; SA q dead by then)
    bf16* ca_qh = (bf16*)qkv;                // [4096][512]
    bf16* ca_ql = ca_qh + 2097152;
    (void)ws_size; (void)spill;

    auto mg = [&](const bf16* Ah, const bf16* Al, const bf16* Bh, const bf16* Bl,
                  const float* bias, const float* resid, float* C, bf16* Oh, bf16* Ol,
                  int M, int N, int K, long ab, long bb, long cb, int csm, int csn, int nb) {
        dim3 g(N / 128, (M + 127) / 128, nb);
        hipLaunchKernelGGL(mgemm_kernel, g, dim3(256), 0, stream,
                           Ah, Al, Bh, Bl, bias, resid, C, Oh, Ol, M, N, K, ab, bb, cb, csm, csn);
    };
    auto cvt2 = [&](const float* in, bf16* h2, bf16* l2, int n) {
        hipLaunchKernelGGL(cvt2_kernel, dim3((n / 4 + 255) / 256), dim3(256), 0, stream, in, h2, l2, n);
    };

    // ---- input conversions (hi/lo) ----
    cvt2(sa_in_w, sawin_h, sawin_l, 1536 * 512);
    cvt2(sa_out_w, sawout_h, sawout_l, 512 * 512);
    cvt2(ca_in_w, caw_h, caw_l, 1536 * 512);
    cvt2(ca_out_w, cawout_h, cawout_l, 512 * 512);
    cvt2(text, text_h, text_l, BB * TXT * 512);
    hipLaunchKernelGGL(trcvt2_kernel, dim3(32, 16, BB), dim3(256), 0, stream,
                       x, xT_h, xT_l, 512, 1024, (long)512 * 1024, (long)1024 * 512);

    // ---- modconv in ----
    hipLaunchKernelGGL(style_kernel, dim3(8), dim3(256), 0, stream, w, pin_mw, pin_mb, style_in);
    hipLaunchKernelGGL(wtmod_kernel, dim3(BB * DIMC), dim3(256), 0, stream, pin_w, style_in, wtA_h, wtA_l);
    mg(xT_h, xT_l, wtA_h, wtA_l, nullptr, nullptr, x_flat, nullptr, nullptr,
       HWX, DIMC, DIMC, (long)HWX * DIMC, (long)DIMC * DIMC, (long)HWX * DIMC, DIMC, 1, BB);

    // ---- LN1 + self-attention (split MFMA) ----
    hipLaunchKernelGGL(ln_kernel, dim3(NTOK), dim3(256), 0, stream, x_flat, ln1g, ln1b, xn, xn_h, xn_l);
    mg(xn_h, xn_l, sawin_h, sawin_l, sa_in_b, nullptr, nullptr, q_h, q_l,
       NTOK, 1536, 512, 0, 0, 0, 1536, 1, 1);
    hipLaunchKernelGGL(sa_mfma_kernel, dim3(16, HEADS, BB), dim3(256), 0, stream,
                       q_h, q_l, obuf_h, obuf_l);
    mg(obuf_h, obuf_l, sawout_h, sawout_l, sa_out_b, x_flat, x_flat, nullptr, nullptr,
       NTOK, 512, 512, 0, 0, 0, 512, 1, 1);

    // ---- LN2 + cross-attention (split MFMA) ----
    hipLaunchKernelGGL(ln_kernel, dim3(NTOK), dim3(256), 0, stream, x_flat, ln2g, ln2b, xn, xn_h, xn_l);
    mg(xn_h, xn_l, caw_h, caw_l, ca_in_b, nullptr, nullptr, ca_qh, ca_ql,
       NTOK, 512, 512, 0, 0, 0, 512, 1, 1);
    mg(text_h, text_l, caw_h + 512 * 512, caw_l + 512 * 512, ca_in_b + 512, nullptr, nullptr,
       kvt_h, kvt_l, BB * TXT, 1024, 512, 0, 0, 0, 1024, 1, 1);
    hipLaunchKernelGGL(ca_mfma_kernel, dim3(16, HEADS, BB), dim3(256), 0, stream,
                       ca_qh, ca_ql, kvt_h, kvt_l, obuf_h, obuf_l);
    // qkv region dead after ca_mfma -> build expert weight transposes there
    hipLaunchKernelGGL(trcvt_kernel, dim3(64, 16, NE), dim3(256), 0, stream,
                       e_w1, e1T, 512, 2048, (long)512 * 2048, (long)2048 * 512);
    hipLaunchKernelGGL(trcvt_kernel, dim3(16, 64, NE), dim3(256), 0, stream,
                       e_w2, e2T, 2048, 512, (long)2048 * 512, (long)512 * 2048);
    mg(obuf_h, obuf_l, cawout_h, cawout_l, ca_out_b, x_flat, x_flat, nullptr, nullptr,
       NTOK, 512, 512, 0, 0, 0, 512, 1, 1);

    // ---- LN3 + router ----
    hipLaunchKernelGGL(ln_kernel, dim3(NTOK), dim3(256), 0, stream, x_flat, ln3g, ln3b, xn, xn_h, xn_l);
    hipLaunchKernelGGL(gemm_kernel, dim3(2, 64, 1), dim3(256), 0, stream,
                       xn, r_feat, feat, NTOK, 128, 512, 512L, 1L, 1L, 128L, 128L);
    hipLaunchKernelGGL(textpart_kernel, dim3(1), dim3(256), 0, stream, w, r_text, r_comb, tp);
    hipLaunchKernelGGL(moe_init_kernel, dim3((MAXT * 128 + 255) / 256), dim3(256), 0, stream, cnt, perm);
    hipLaunchKernelGGL(route_kernel, dim3(16), dim3(256), 0, stream, feat, tp, r_comb, r_temp, onehot, idx, cnt);
    hipLaunchKernelGGL(offsets_kernel, dim3(1), dim3(64), 0, stream, cnt, cursor, ntiles, table);
    hipLaunchKernelGGL(scatter_kernel, dim3(16), dim3(256), 0, stream, idx, cursor, perm);

    // ---- MoE grouped MFMA GEMMs ----
    hipLaunchKernelGGL(moe_mfma1_kernel, dim3(HIDC / 128, MAXT), dim3(256), 0, stream,
                       xn_h, e1T, e_b1, table, ntiles, perm, hid_b);
    hipLaunchKernelGGL(moe_mfma2_kernel, dim3(DIMC / 128, MAXT), dim3(256), 0, stream,
                       hid_b, e2T, e_b2, table, ntiles, perm, x_flat);

    // ---- modconv out (split both sides) ----
    cvt2(x_flat, xfl_h, xfl_l, NTOK * DIMC);
    hipLaunchKernelGGL(style_kernel, dim3(8), dim3(256), 0, stream, w, pout_mw, pout_mb, style_out);
    hipLaunchKernelGGL(wtmod_kernel, dim3(BB * DIMC), dim3(256), 0, stream, pout_w, style_out, wtC_h, wtC_l);
    mg(wtC_h, wtC_l, xfl_h, xfl_l, nullptr, nullptr, out, nullptr, nullptr,
       DIMC, HWX, DIMC, (long)DIMC * DIMC, (long)HWX * DIMC, (long)DIMC * HWX, HWX, 1, BB);
}

// Round 8
// 728.261 us; speedup vs baseline: 7.6007x; 1.0633x over previous
//
#include <hip/hip_runtime.h>
#include <hip/hip_bf16.h>
#include <math.h>

#define DIMC 512
#define HEADS 8
#define HD 64
#define BB 4
#define HWX 1024
#define TXT 77
#define LATC 512
#define NE 8
#define HIDC 2048
#define NTOK 4096
#define MAXT 40

typedef __attribute__((ext_vector_type(8))) short bf16x8;
typedef __attribute__((ext_vector_type(4))) float f32x4;
typedef __hip_bfloat16 bf16;

__device__ __forceinline__ void split2(float v, bf16& h, bf16& l) {
    h = __float2bfloat16(v);
    l = __float2bfloat16(v - __bfloat162float(h));
}
__device__ __forceinline__ void split2s(float v, short& h, short& l) {
    bf16 hb, lb; split2(v, hb, lb);
    h = *(short*)&hb; l = *(short*)&lb;
}

// ---------------- style = w @ mod_w.T + mod_b ----------------
__global__ void style_kernel(const float* __restrict__ w, const float* __restrict__ mod_w,
                             const float* __restrict__ mod_b, float* __restrict__ style) {
    int t = blockIdx.x * blockDim.x + threadIdx.x;
    if (t >= BB * DIMC) return;
    int b = t / DIMC, i = t % DIMC;
    const float* wr = w + (long)b * LATC;
    const float* mr = mod_w + (long)i * LATC;
    float s = 0.f;
    #pragma unroll 8
    for (int l = 0; l < LATC; l++) s += wr[l] * mr[l];
    style[t] = s + mod_b[i];
}

// ------- wtmod[b,o,i] -> bf16 hi/lo (demodulated per-sample weight) -------
__global__ void wtmod_kernel(const float* __restrict__ weight, const float* __restrict__ style,
                             bf16* __restrict__ wh, bf16* __restrict__ wl) {
    int bo = blockIdx.x;
    int b = bo / DIMC, o = bo % DIMC;
    const float* wr = weight + (long)o * DIMC;
    const float* sr = style + (long)b * DIMC;
    int t = threadIdx.x;
    float vals[2]; float part = 0.f;
    for (int j = 0; j < 2; j++) {
        int i = t + j * 256;
        float v = wr[i] * sr[i];
        vals[j] = v; part += v * v;
    }
    __shared__ float red[256];
    red[t] = part; __syncthreads();
    for (int s = 128; s > 0; s >>= 1) { if (t < s) red[t] += red[t + s]; __syncthreads(); }
    float d = rsqrtf(red[0] + 1e-8f);
    for (int j = 0; j < 2; j++) {
        int i = t + j * 256;
        bf16 h, l; split2(vals[j] * d, h, l);
        wh[(long)bo * DIMC + i] = h; wl[(long)bo * DIMC + i] = l;
    }
}

// ---------------- fp32 -> bf16 hi/lo convert (flat) ----------------
__global__ void cvt2_kernel(const float* __restrict__ in, bf16* __restrict__ hi,
                            bf16* __restrict__ lo, int n) {
    int i = (blockIdx.x * blockDim.x + threadIdx.x) * 4;
    if (i >= n) return;
    float4 v = *(const float4*)(in + i);
    float a[4] = {v.x, v.y, v.z, v.w};
    #pragma unroll
    for (int j = 0; j < 4; j++) { bf16 h, l; split2(a[j], h, l); hi[i + j] = h; lo[i + j] = l; }
}

// ---------------- fp32 [R][C] -> bf16 [C][R] transpose hi/lo ----------------
__global__ void trcvt2_kernel(const float* __restrict__ in, bf16* __restrict__ hi,
                              bf16* __restrict__ lo, int R, int C, long in_bat, long out_bat) {
    __shared__ float tile[32][33];
    in += (long)blockIdx.z * in_bat; hi += (long)blockIdx.z * out_bat; lo += (long)blockIdx.z * out_bat;
    int c0 = blockIdx.x * 32, r0 = blockIdx.y * 32;
    int tc = threadIdx.x & 31, tr = threadIdx.x >> 5;
    #pragma unroll
    for (int i = 0; i < 4; i++) {
        int r = tr + i * 8;
        tile[r][tc] = in[(long)(r0 + r) * C + c0 + tc];
    }
    __syncthreads();
    #pragma unroll
    for (int i = 0; i < 4; i++) {
        int r = tr + i * 8;
        bf16 h, l; split2(tile[tc][r], h, l);
        hi[(long)(c0 + r) * R + r0 + tc] = h;
        lo[(long)(c0 + r) * R + r0 + tc] = l;
    }
}

// ---------------- fp32 [R][C] -> bf16 [C][R] transpose (single) ----------------
__global__ void trcvt_kernel(const float* __restrict__ in, bf16* __restrict__ out,
                             int R, int C, long in_bat, long out_bat) {
    __shared__ float tile[32][33];
    in += (long)blockIdx.z * in_bat; out += (long)blockIdx.z * out_bat;
    int c0 = blockIdx.x * 32, r0 = blockIdx.y * 32;
    int tc = threadIdx.x & 31, tr = threadIdx.x >> 5;
    #pragma unroll
    for (int i = 0; i < 4; i++) {
        int r = tr + i * 8;
        tile[r][tc] = in[(long)(r0 + r) * C + c0 + tc];
    }
    __syncthreads();
    #pragma unroll
    for (int i = 0; i < 4; i++) {
        int r = tr + i * 8;
        out[(long)(c0 + r) * R + r0 + tc] = __float2bfloat16(tile[tc][r]);
    }
}

// ---- split-precision bf16 MFMA GEMM: C = A·B^T with A=Ah+Al, B=Bh+Bl ----
// acc += Ah·Bh + Ah·Bl + Al·Bh. Output: fp32 C, or split bf16 (Oh/Ol) when Oh!=null.
__global__ __launch_bounds__(256) void mgemm_kernel(
    const bf16* __restrict__ Ah, const bf16* __restrict__ Al,
    const bf16* __restrict__ Bh, const bf16* __restrict__ Bl,
    const float* __restrict__ bias, const float* __restrict__ resid, float* __restrict__ C,
    bf16* __restrict__ Oh, bf16* __restrict__ Ol,
    int M, int N, int K, long a_bat, long b_bat, long c_bat, int cs_m, int cs_n) {
    __shared__ short AsH[128 * 32];
    __shared__ short AsL[128 * 32];
    __shared__ short BsH[128 * 32];
    __shared__ short BsL[128 * 32];
    int bat = blockIdx.z;
    const short* AbH = (const short*)(Ah + (long)bat * a_bat);
    const short* AbL = (const short*)(Al + (long)bat * a_bat);
    const short* BbH = (const short*)(Bh + (long)bat * b_bat);
    const short* BbL = (const short*)(Bl + (long)bat * b_bat);
    float* Cb = C + (long)bat * c_bat;
    const float* Rb = resid ? resid + (long)bat * c_bat : nullptr;
    int bm = blockIdx.y * 128, bn = blockIdx.x * 128;
    int t = threadIdx.x, lane = t & 63, w = t >> 6;
    int wm = (w >> 1) * 64, wn = (w & 1) * 64;
    int p0 = t, p1 = t + 256;
    int r0 = p0 >> 2, k0s = (p0 & 3) ^ ((r0 >> 1) & 3);
    int r1 = p1 >> 2, k1s = (p1 & 3) ^ ((r1 >> 1) & 3);
    int ar0 = bm + r0; if (ar0 > M - 1) ar0 = M - 1;
    int ar1 = bm + r1; if (ar1 > M - 1) ar1 = M - 1;
    long aoff0 = (long)ar0 * K + k0s * 8, aoff1 = (long)ar1 * K + k1s * 8;
    long boff0 = (long)(bn + r0) * K + k0s * 8, boff1 = (long)(bn + r1) * K + k1s * 8;
    int fr = lane & 15, fq = lane >> 4;
    int aOff[4], bOff[4];
    #pragma unroll
    for (int i = 0; i < 4; i++) {
        int row = wm + i * 16 + fr;
        aOff[i] = row * 32 + ((fq ^ ((row >> 1) & 3)) * 8);
        int col = wn + i * 16 + fr;
        bOff[i] = col * 32 + ((fq ^ ((col >> 1) & 3)) * 8);
    }
    f32x4 acc[4][4] = {};
    for (int kk = 0; kk < K; kk += 32) {
        bf16x8 vah0 = *(const bf16x8*)(AbH + aoff0 + kk);
        bf16x8 vah1 = *(const bf16x8*)(AbH + aoff1 + kk);
        bf16x8 val0 = *(const bf16x8*)(AbL + aoff0 + kk);
        bf16x8 val1 = *(const bf16x8*)(AbL + aoff1 + kk);
        bf16x8 vbh0 = *(const bf16x8*)(BbH + boff0 + kk);
        bf16x8 vbh1 = *(const bf16x8*)(BbH + boff1 + kk);
        bf16x8 vbl0 = *(const bf16x8*)(BbL + boff0 + kk);
        bf16x8 vbl1 = *(const bf16x8*)(BbL + boff1 + kk);
        __syncthreads();
        *(bf16x8*)&AsH[p0 * 8] = vah0;  *(bf16x8*)&AsH[p1 * 8] = vah1;
        *(bf16x8*)&AsL[p0 * 8] = val0;  *(bf16x8*)&AsL[p1 * 8] = val1;
        *(bf16x8*)&BsH[p0 * 8] = vbh0;  *(bf16x8*)&BsH[p1 * 8] = vbh1;
        *(bf16x8*)&BsL[p0 * 8] = vbl0;  *(bf16x8*)&BsL[p1 * 8] = vbl1;
        __syncthreads();
        bf16x8 aH[4], aL[4], bH[4], bL[4];
        #pragma unroll
        for (int i = 0; i < 4; i++) {
            aH[i] = *(const bf16x8*)&AsH[aOff[i]];
            aL[i] = *(const bf16x8*)&AsL[aOff[i]];
            bH[i] = *(const bf16x8*)&BsH[bOff[i]];
            bL[i] = *(const bf16x8*)&BsL[bOff[i]];
        }
        #pragma unroll
        for (int i = 0; i < 4; i++)
        #pragma unroll
        for (int j = 0; j < 4; j++) {
            acc[i][j] = __builtin_amdgcn_mfma_f32_16x16x32_bf16(aH[i], bH[j], acc[i][j], 0, 0, 0);
            acc[i][j] = __builtin_amdgcn_mfma_f32_16x16x32_bf16(aH[i], bL[j], acc[i][j], 0, 0, 0);
            acc[i][j] = __builtin_amdgcn_mfma_f32_16x16x32_bf16(aL[i], bH[j], acc[i][j], 0, 0, 0);
        }
    }
    #pragma unroll
    for (int i = 0; i < 4; i++)
    #pragma unroll
    for (int j = 0; j < 4; j++)
    #pragma unroll
    for (int r = 0; r < 4; r++) {
        int row = bm + wm + i * 16 + fq * 4 + r;
        int col = bn + wn + j * 16 + fr;
        if (row < M) {
            long off = (long)row * cs_m + (long)col * cs_n;
            float v = acc[i][j][r];
            if (bias) v += bias[col];
            if (Oh) {
                bf16 hh, ll; split2(v, hh, ll);
                Oh[off] = hh; Ol[off] = ll;
            } else {
                if (Rb) v += Rb[off];
                Cb[off] = v;
            }
        }
    }
}

// ---- split-precision MFMA flash self-attention ----
__global__ __launch_bounds__(256) void sa_mfma_kernel(
    const bf16* __restrict__ qh, const bf16* __restrict__ ql,
    bf16* __restrict__ oh, bf16* __restrict__ ol) {
    int qt = blockIdx.x, h = blockIdx.y, b = blockIdx.z;
    __shared__ short KsH[4096], KsL[4096];     // [kv][d], swz: col ^ ((kv&7)<<3)
    __shared__ short VtH[4096], VtL[4096];     // [d][kv], swz: col ^ (((d>>3)&7)<<3)
    __shared__ short PHs[4][1024], PLs[4][1024]; // per-wave P [q][kv], swz: col ^ ((q&7)<<3)
    int t = threadIdx.x, lane = t & 63, w = t >> 6;
    int fr = lane & 15, fq = lane >> 4;
    const short* QH = (const short*)qh;
    const short* QL = (const short*)ql;
    long qrow = (long)(b * 1024 + qt * 64 + w * 16 + fr) * 1536 + h * 64;
    bf16x8 Qh2[2], Ql2[2];
    Qh2[0] = *(const bf16x8*)(QH + qrow + fq * 8);
    Qh2[1] = *(const bf16x8*)(QH + qrow + 32 + fq * 8);
    Ql2[0] = *(const bf16x8*)(QL + qrow + fq * 8);
    Ql2[1] = *(const bf16x8*)(QL + qrow + 32 + fq * 8);
    float m_i[4], l_i[4];
    f32x4 o_acc[4] = {};
    #pragma unroll
    for (int i = 0; i < 4; i++) { m_i[i] = -1e30f; l_i[i] = 0.f; }
    int c0 = t, c1 = t + 256;
    int r0 = c0 >> 3, g0 = c0 & 7;
    int r1 = c1 >> 3, g1 = c1 & 7;
    int kd0 = r0 * 64 + ((g0 * 8) ^ ((r0 & 7) << 3));
    int kd1 = r1 * 64 + ((g1 * 8) ^ ((r1 & 7) << 3));
    long kb = (long)(b * 1024) * 1536 + 512 + h * 64;
    long vb = kb + 512;
    short* ph = PHs[w]; short* pl = PLs[w];
    for (int kt = 0; kt < 16; kt++) {
        long ko = kb + (long)(kt * 64) * 1536;
        long vo = vb + (long)(kt * 64) * 1536;
        bf16x8 kh0 = *(const bf16x8*)(QH + ko + (long)r0 * 1536 + g0 * 8);
        bf16x8 kh1 = *(const bf16x8*)(QH + ko + (long)r1 * 1536 + g1 * 8);
        bf16x8 kl0 = *(const bf16x8*)(QL + ko + (long)r0 * 1536 + g0 * 8);
        bf16x8 kl1 = *(const bf16x8*)(QL + ko + (long)r1 * 1536 + g1 * 8);
        bf16x8 vh0 = *(const bf16x8*)(QH + vo + (long)r0 * 1536 + g0 * 8);
        bf16x8 vh1 = *(const bf16x8*)(QH + vo + (long)r1 * 1536 + g1 * 8);
        bf16x8 vl0 = *(const bf16x8*)(QL + vo + (long)r0 * 1536 + g0 * 8);
        bf16x8 vl1 = *(const bf16x8*)(QL + vo + (long)r1 * 1536 + g1 * 8);
        __syncthreads();
        *(bf16x8*)&KsH[kd0] = kh0;  *(bf16x8*)&KsH[kd1] = kh1;
        *(bf16x8*)&KsL[kd0] = kl0;  *(bf16x8*)&KsL[kd1] = kl1;
        #pragma unroll
        for (int j = 0; j < 8; j++) {
            int d0 = g0 * 8 + j;
            int i0 = d0 * 64 + (r0 ^ (((d0 >> 3) & 7) << 3));
            VtH[i0] = ((short*)&vh0)[j];  VtL[i0] = ((short*)&vl0)[j];
            int d1 = g1 * 8 + j;
            int i1 = d1 * 64 + (r1 ^ (((d1 >> 3) & 7) << 3));
            VtH[i1] = ((short*)&vh1)[j];  VtL[i1] = ((short*)&vl1)[j];
        }
        __syncthreads();
        f32x4 s[4] = {};
        #pragma unroll
        for (int cf = 0; cf < 4; cf++) {
            int kvrow = cf * 16 + fr;
            #pragma unroll
            for (int kf = 0; kf < 2; kf++) {
                int idx = kvrow * 64 + ((kf * 32 + fq * 8) ^ ((kvrow & 7) << 3));
                bf16x8 Bh2 = *(const bf16x8*)&KsH[idx];
                bf16x8 Bl2 = *(const bf16x8*)&KsL[idx];
                s[cf] = __builtin_amdgcn_mfma_f32_16x16x32_bf16(Qh2[kf], Bh2, s[cf], 0, 0, 0);
                s[cf] = __builtin_amdgcn_mfma_f32_16x16x32_bf16(Qh2[kf], Bl2, s[cf], 0, 0, 0);
                s[cf] = __builtin_amdgcn_mfma_f32_16x16x32_bf16(Ql2[kf], Bh2, s[cf], 0, 0, 0);
            }
        }
        #pragma unroll
        for (int cf = 0; cf < 4; cf++)
        #pragma unroll
        for (int reg = 0; reg < 4; reg++) s[cf][reg] *= 0.125f;
        float sc_[4];
        #pragma unroll
        for (int reg = 0; reg < 4; reg++) {
            float mx = fmaxf(fmaxf(s[0][reg], s[1][reg]), fmaxf(s[2][reg], s[3][reg]));
            mx = fmaxf(mx, __shfl_xor(mx, 1));
            mx = fmaxf(mx, __shfl_xor(mx, 2));
            mx = fmaxf(mx, __shfl_xor(mx, 4));
            mx = fmaxf(mx, __shfl_xor(mx, 8));
            float mn = fmaxf(m_i[reg], mx);
            sc_[reg] = __expf(m_i[reg] - mn);
            m_i[reg] = mn;
            float rs = 0.f;
            #pragma unroll
            for (int cf = 0; cf < 4; cf++) { s[cf][reg] = __expf(s[cf][reg] - mn); rs += s[cf][reg]; }
            rs += __shfl_xor(rs, 1);
            rs += __shfl_xor(rs, 2);
            rs += __shfl_xor(rs, 4);
            rs += __shfl_xor(rs, 8);
            l_i[reg] = l_i[reg] * sc_[reg] + rs;
        }
        #pragma unroll
        for (int cf = 0; cf < 4; cf++)
        #pragma unroll
        for (int reg = 0; reg < 4; reg++) o_acc[cf][reg] *= sc_[reg];
        #pragma unroll
        for (int cf = 0; cf < 4; cf++)
        #pragma unroll
        for (int reg = 0; reg < 4; reg++) {
            int q = fq * 4 + reg, kv = cf * 16 + fr;
            int idx = q * 64 + (kv ^ ((q & 7) << 3));
            split2s(s[cf][reg], ph[idx], pl[idx]);
        }
        __syncthreads();
        bf16x8 Pf_h[2], Pf_l[2];
        #pragma unroll
        for (int kf = 0; kf < 2; kf++) {
            int idx = fr * 64 + ((kf * 32 + fq * 8) ^ ((fr & 7) << 3));
            Pf_h[kf] = *(const bf16x8*)&ph[idx];
            Pf_l[kf] = *(const bf16x8*)&pl[idx];
        }
        #pragma unroll
        for (int cf = 0; cf < 4; cf++) {
            int d = cf * 16 + fr;
            #pragma unroll
            for (int kf = 0; kf < 2; kf++) {
                int idx = d * 64 + ((kf * 32 + fq * 8) ^ (((d >> 3) & 7) << 3));
                bf16x8 Vh2 = *(const bf16x8*)&VtH[idx];
                bf16x8 Vl2 = *(const bf16x8*)&VtL[idx];
                o_acc[cf] = __builtin_amdgcn_mfma_f32_16x16x32_bf16(Pf_h[kf], Vh2, o_acc[cf], 0, 0, 0);
                o_acc[cf] = __builtin_amdgcn_mfma_f32_16x16x32_bf16(Pf_h[kf], Vl2, o_acc[cf], 0, 0, 0);
                o_acc[cf] = __builtin_amdgcn_mfma_f32_16x16x32_bf16(Pf_l[kf], Vh2, o_acc[cf], 0, 0, 0);
            }
        }
    }
    #pragma unroll
    for (int reg = 0; reg < 4; reg++) {
        float inv = 1.f / l_i[reg];
        long m = (long)(b * 1024 + qt * 64 + w * 16 + fq * 4 + reg);
        #pragma unroll
        for (int cf = 0; cf < 4; cf++) {
            float v = o_acc[cf][reg] * inv;
            bf16 hh, ll; split2(v, hh, ll);
            long off = m * DIMC + h * 64 + cf * 16 + fr;
            oh[off] = hh; ol[off] = ll;
        }
    }
}

// ---- split-precision MFMA cross-attention: 77 keys padded to 96, single tile ----
__global__ __launch_bounds__(256) void ca_mfma_kernel(
    const bf16* __restrict__ qh, const bf16* __restrict__ ql,
    const bf16* __restrict__ kvh, const bf16* __restrict__ kvl,
    bf16* __restrict__ oh, bf16* __restrict__ ol) {
    int qt = blockIdx.x, h = blockIdx.y, b = blockIdx.z;
    __shared__ short UH[8192], UL[8192];          // K [96][64] swz -> reused as Vt [64][128] swz
    __shared__ short PHs[4][2048], PLs[4][2048];  // per-wave P [16 q][128 kv-padded]
    int t = threadIdx.x, lane = t & 63, w = t >> 6;
    int fr = lane & 15, fq = lane >> 4;
    const short* QH = (const short*)qh;
    const short* QL = (const short*)ql;
    const short* KVH = (const short*)kvh;
    const short* KVL = (const short*)kvl;
    long qrow = (long)(b * 1024 + qt * 64 + w * 16 + fr) * DIMC + h * 64;
    bf16x8 Qh2[2], Ql2[2];
    Qh2[0] = *(const bf16x8*)(QH + qrow + fq * 8);
    Qh2[1] = *(const bf16x8*)(QH + qrow + 32 + fq * 8);
    Ql2[0] = *(const bf16x8*)(QL + qrow + fq * 8);
    Ql2[1] = *(const bf16x8*)(QL + qrow + 32 + fq * 8);
    for (int c = t; c < 768; c += 256) {
        int r = c >> 3, g = c & 7;
        int idx = r * 64 + ((g * 8) ^ ((r & 7) << 3));
        bf16x8 vh = {}, vl = {};
        if (r < 77) {
            long src = (long)(b * 77 + r) * 1024 + h * 64 + g * 8;
            vh = *(const bf16x8*)(KVH + src);
            vl = *(const bf16x8*)(KVL + src);
        }
        *(bf16x8*)&UH[idx] = vh;
        *(bf16x8*)&UL[idx] = vl;
    }
    __syncthreads();
    f32x4 s[5] = {};
    #pragma unroll
    for (int cf = 0; cf < 5; cf++) {
        int kvrow = cf * 16 + fr;
        #pragma unroll
        for (int kf = 0; kf < 2; kf++) {
            int idx = kvrow * 64 + ((kf * 32 + fq * 8) ^ ((kvrow & 7) << 3));
            bf16x8 Bh2 = *(const bf16x8*)&UH[idx];
            bf16x8 Bl2 = *(const bf16x8*)&UL[idx];
            s[cf] = __builtin_amdgcn_mfma_f32_16x16x32_bf16(Qh2[kf], Bh2, s[cf], 0, 0, 0);
            s[cf] = __builtin_amdgcn_mfma_f32_16x16x32_bf16(Qh2[kf], Bl2, s[cf], 0, 0, 0);
            s[cf] = __builtin_amdgcn_mfma_f32_16x16x32_bf16(Ql2[kf], Bh2, s[cf], 0, 0, 0);
        }
    }
    #pragma unroll
    for (int cf = 0; cf < 5; cf++) {
        int kv = cf * 16 + fr;
        #pragma unroll
        for (int reg = 0; reg < 4; reg++)
            s[cf][reg] = (kv < 77) ? s[cf][reg] * 0.125f : -1e30f;
    }
    float inv[4];
    #pragma unroll
    for (int reg = 0; reg < 4; reg++) {
        float mx = s[0][reg];
        #pragma unroll
        for (int cf = 1; cf < 5; cf++) mx = fmaxf(mx, s[cf][reg]);
        mx = fmaxf(mx, __shfl_xor(mx, 1));
        mx = fmaxf(mx, __shfl_xor(mx, 2));
        mx = fmaxf(mx, __shfl_xor(mx, 4));
        mx = fmaxf(mx, __shfl_xor(mx, 8));
        float rs = 0.f;
        #pragma unroll
        for (int cf = 0; cf < 5; cf++) { s[cf][reg] = __expf(s[cf][reg] - mx); rs += s[cf][reg]; }
        rs += __shfl_xor(rs, 1);
        rs += __shfl_xor(rs, 2);
        rs += __shfl_xor(rs, 4);
        rs += __shfl_xor(rs, 8);
        inv[reg] = 1.f / rs;
    }
    short* ph = PHs[w]; short* pl = PLs[w];
    #pragma unroll
    for (int cf = 0; cf < 6; cf++)
    #pragma unroll
    for (int reg = 0; reg < 4; reg++) {
        int q = fq * 4 + reg, kv = cf * 16 + fr;
        int idx = q * 128 + (kv ^ ((q & 7) << 3));
        float pv = (cf < 5) ? s[cf][reg] * inv[reg] : 0.f;
        split2s(pv, ph[idx], pl[idx]);
    }
    __syncthreads();
    for (int c = t; c < 768; c += 256) {
        int r = c >> 3, g = c & 7;
        bf16x8 vh = {}, vl = {};
        if (r < 77) {
            long src = (long)(b * 77 + r) * 1024 + 512 + h * 64 + g * 8;
            vh = *(const bf16x8*)(KVH + src);
            vl = *(const bf16x8*)(KVL + src);
        }
        #pragma unroll
        for (int j = 0; j < 8; j++) {
            int d = g * 8 + j;
            int idx = d * 128 + (r ^ (((d >> 3) & 7) << 3));
            UH[idx] = ((short*)&vh)[j];
            UL[idx] = ((short*)&vl)[j];
        }
    }
    __syncthreads();
    f32x4 o_acc[4] = {};
    bf16x8 Pf_h[3], Pf_l[3];
    #pragma unroll
    for (int kf = 0; kf < 3; kf++) {
        int idx = fr * 128 + ((kf * 32 + fq * 8) ^ ((fr & 7) << 3));
        Pf_h[kf] = *(const bf16x8*)&ph[idx];
        Pf_l[kf] = *(const bf16x8*)&pl[idx];
    }
    #pragma unroll
    for (int cf = 0; cf < 4; cf++) {
        int d = cf * 16 + fr;
        #pragma unroll
        for (int kf = 0; kf < 3; kf++) {
            int idx = d * 128 + ((kf * 32 + fq * 8) ^ (((d >> 3) & 7) << 3));
            bf16x8 Vh2 = *(const bf16x8*)&UH[idx];
            bf16x8 Vl2 = *(const bf16x8*)&UL[idx];
            o_acc[cf] = __builtin_amdgcn_mfma_f32_16x16x32_bf16(Pf_h[kf], Vh2, o_acc[cf], 0, 0, 0);
            o_acc[cf] = __builtin_amdgcn_mfma_f32_16x16x32_bf16(Pf_h[kf], Vl2, o_acc[cf], 0, 0, 0);
            o_acc[cf] = __builtin_amdgcn_mfma_f32_16x16x32_bf16(Pf_l[kf], Vh2, o_acc[cf], 0, 0, 0);
        }
    }
    #pragma unroll
    for (int reg = 0; reg < 4; reg++) {
        long m = (long)(b * 1024 + qt * 64 + w * 16 + fq * 4 + reg);
        #pragma unroll
        for (int cf = 0; cf < 4; cf++) {
            bf16 hh, ll; split2(o_acc[cf][reg], hh, ll);
            long off = m * DIMC + h * 64 + cf * 16 + fr;
            oh[off] = hh; ol[off] = ll;
        }
    }
}

// ---- MoE grouped MFMA GEMM1 (plain bf16): hid = gelu(xn·w1 + b1), K=512 ----
__global__ __launch_bounds__(256) void moe_mfma1_kernel(
    const bf16* __restrict__ xn_b, const bf16* __restrict__ e1T, const float* __restrict__ e_b1,
    const int* __restrict__ table, const int* __restrict__ ntiles, const int* __restrict__ perm,
    bf16* __restrict__ hid_b) {
    if (blockIdx.y >= ntiles[0]) return;
    int e = table[2 * blockIdx.y], row0 = table[2 * blockIdx.y + 1];
    int bn = blockIdx.x * 128;
    __shared__ short As[128 * 32];
    __shared__ short Bs[128 * 32];
    __shared__ int rowsS[128];
    int t = threadIdx.x, lane = t & 63, w = t >> 6;
    if (t < 128) rowsS[t] = perm[row0 + t];
    __syncthreads();
    int wm = (w >> 1) * 64, wn = (w & 1) * 64;
    int p0 = t, p1 = t + 256;
    int r0 = p0 >> 2, k0s = (p0 & 3) ^ ((r0 >> 1) & 3);
    int r1 = p1 >> 2, k1s = (p1 & 3) ^ ((r1 >> 1) & 3);
    int tok0 = rowsS[r0]; if (tok0 < 0) tok0 = 0;
    int tok1 = rowsS[r1]; if (tok1 < 0) tok1 = 0;
    const short* Xs = (const short*)xn_b;
    const short* Ws = (const short*)(e1T + (long)e * HIDC * DIMC);
    const short* a0 = Xs + (long)tok0 * DIMC + k0s * 8;
    const short* a1 = Xs + (long)tok1 * DIMC + k1s * 8;
    const short* b0 = Ws + (long)(bn + r0) * DIMC + k0s * 8;
    const short* b1 = Ws + (long)(bn + r1) * DIMC + k1s * 8;
    int fr = lane & 15, fq = lane >> 4;
    int aOff[4], bOff[4];
    #pragma unroll
    for (int i = 0; i < 4; i++) {
        int row = wm + i * 16 + fr;
        aOff[i] = row * 32 + ((fq ^ ((row >> 1) & 3)) * 8);
        int col = wn + i * 16 + fr;
        bOff[i] = col * 32 + ((fq ^ ((col >> 1) & 3)) * 8);
    }
    f32x4 acc[4][4] = {};
    for (int kk = 0; kk < DIMC; kk += 32) {
        bf16x8 va0 = *(const bf16x8*)(a0 + kk);
        bf16x8 va1 = *(const bf16x8*)(a1 + kk);
        bf16x8 vb0 = *(const bf16x8*)(b0 + kk);
        bf16x8 vb1 = *(const bf16x8*)(b1 + kk);
        __syncthreads();
        *(bf16x8*)&As[p0 * 8] = va0;  *(bf16x8*)&As[p1 * 8] = va1;
        *(bf16x8*)&Bs[p0 * 8] = vb0;  *(bf16x8*)&Bs[p1 * 8] = vb1;
        __syncthreads();
        bf16x8 aF[4], bF[4];
        #pragma unroll
        for (int i = 0; i < 4; i++) {
            aF[i] = *(const bf16x8*)&As[aOff[i]];
            bF[i] = *(const bf16x8*)&Bs[bOff[i]];
        }
        #pragma unroll
        for (int i = 0; i < 4; i++)
        #pragma unroll
        for (int j = 0; j < 4; j++)
            acc[i][j] = __builtin_amdgcn_mfma_f32_16x16x32_bf16(aF[i], bF[j], acc[i][j], 0, 0, 0);
    }
    const float* bb = e_b1 + (long)e * HIDC;
    #pragma unroll
    for (int i = 0; i < 4; i++)
    #pragma unroll
    for (int r = 0; r < 4; r++) {
        int tok = rowsS[wm + i * 16 + fq * 4 + r];
        if (tok < 0) continue;
        #pragma unroll
        for (int j = 0; j < 4; j++) {
            int col = bn + wn + j * 16 + fr;
            float v = acc[i][j][r] + bb[col];
            v = 0.5f * v * (1.f + erff(v * 0.70710678f));
            hid_b[(long)tok * HIDC + col] = __float2bfloat16(v);
        }
    }
}

// ---- MoE grouped MFMA GEMM2 (plain bf16): x_flat += hid·w2 + b2, K=2048 ----
__global__ __launch_bounds__(256) void moe_mfma2_kernel(
    const bf16* __restrict__ hid_b, const bf16* __restrict__ e2T, const float* __restrict__ e_b2,
    const int* __restrict__ table, const int* __restrict__ ntiles, const int* __restrict__ perm,
    float* __restrict__ x_flat) {
    if (blockIdx.y >= ntiles[0]) return;
    int e = table[2 * blockIdx.y], row0 = table[2 * blockIdx.y + 1];
    int bn = blockIdx.x * 128;
    __shared__ short As[128 * 32];
    __shared__ short Bs[128 * 32];
    __shared__ int rowsS[128];
    int t = threadIdx.x, lane = t & 63, w = t >> 6;
    if (t < 128) rowsS[t] = perm[row0 + t];
    __syncthreads();
    int wm = (w >> 1) * 64, wn = (w & 1) * 64;
    int p0 = t, p1 = t + 256;
    int r0 = p0 >> 2, k0s = (p0 & 3) ^ ((r0 >> 1) & 3);
    int r1 = p1 >> 2, k1s = (p1 & 3) ^ ((r1 >> 1) & 3);
    int tok0 = rowsS[r0]; if (tok0 < 0) tok0 = 0;
    int tok1 = rowsS[r1]; if (tok1 < 0) tok1 = 0;
    const short* Hs = (const short*)hid_b;
    const short* Ws = (const short*)(e2T + (long)e * DIMC * HIDC);
    const short* a0 = Hs + (long)tok0 * HIDC + k0s * 8;
    const short* a1 = Hs + (long)tok1 * HIDC + k1s * 8;
    const short* b0 = Ws + (long)(bn + r0) * HIDC + k0s * 8;
    const short* b1 = Ws + (long)(bn + r1) * HIDC + k1s * 8;
    int fr = lane & 15, fq = lane >> 4;
    int aOff[4], bOff[4];
    #pragma unroll
    for (int i = 0; i < 4; i++) {
        int row = wm + i * 16 + fr;
        aOff[i] = row * 32 + ((fq ^ ((row >> 1) & 3)) * 8);
        int col = wn + i * 16 + fr;
        bOff[i] = col * 32 + ((fq ^ ((col >> 1) & 3)) * 8);
    }
    f32x4 acc[4][4] = {};
    for (int kk = 0; kk < HIDC; kk += 32) {
        bf16x8 va0 = *(const bf16x8*)(a0 + kk);
        bf16x8 va1 = *(const bf16x8*)(a1 + kk);
        bf16x8 vb0 = *(const bf16x8*)(b0 + kk);
        bf16x8 vb1 = *(const bf16x8*)(b1 + kk);
        __syncthreads();
        *(bf16x8*)&As[p0 * 8] = va0;  *(bf16x8*)&As[p1 * 8] = va1;
        *(bf16x8*)&Bs[p0 * 8] = vb0;  *(bf16x8*)&Bs[p1 * 8] = vb1;
        __syncthreads();
        bf16x8 aF[4], bF[4];
        #pragma unroll
        for (int i = 0; i < 4; i++) {
            aF[i] = *(const bf16x8*)&As[aOff[i]];
            bF[i] = *(const bf16x8*)&Bs[bOff[i]];
        }
        #pragma unroll
        for (int i = 0; i < 4; i++)
        #pragma unroll
        for (int j = 0; j < 4; j++)
            acc[i][j] = __builtin_amdgcn_mfma_f32_16x16x32_bf16(aF[i], bF[j], acc[i][j], 0, 0, 0);
    }
    const float* bb = e_b2 + (long)e * DIMC;
    #pragma unroll
    for (int i = 0; i < 4; i++)
    #pragma unroll
    for (int r = 0; r < 4; r++) {
        int tok = rowsS[wm + i * 16 + fq * 4 + r];
        if (tok < 0) continue;
        #pragma unroll
        for (int j = 0; j < 4; j++) {
            int col = bn + wn + j * 16 + fr;
            x_flat[(long)tok * DIMC + col] += acc[i][j][r] + bb[col];
        }
    }
}

// ---------------- LayerNorm: optional fp32 + bf16 hi/lo outputs ----------------
__global__ void ln_kernel(const float* __restrict__ x, const float* __restrict__ g,
                          const float* __restrict__ b, float* __restrict__ y,
                          bf16* __restrict__ yh, bf16* __restrict__ yl) {
    int tok = blockIdx.x;
    int t = threadIdx.x;
    const float* xr = x + (long)tok * DIMC;
    float v0 = xr[t], v1 = xr[t + 256];
    __shared__ float red[256];
    red[t] = v0 + v1; __syncthreads();
    for (int s = 128; s > 0; s >>= 1) { if (t < s) red[t] += red[t + s]; __syncthreads(); }
    float mu = red[0] * (1.f / DIMC);
    __syncthreads();
    float d0 = v0 - mu, d1 = v1 - mu;
    red[t] = d0 * d0 + d1 * d1; __syncthreads();
    for (int s = 128; s > 0; s >>= 1) { if (t < s) red[t] += red[t + s]; __syncthreads(); }
    float rs = rsqrtf(red[0] * (1.f / DIMC) + 1e-5f);
    float o0 = d0 * rs * g[t] + b[t];
    float o1 = d1 * rs * g[t + 256] + b[t + 256];
    if (y) { y[(long)tok * DIMC + t] = o0; y[(long)tok * DIMC + t + 256] = o1; }
    bf16 h, l;
    split2(o0, h, l); yh[(long)tok * DIMC + t] = h;       yl[(long)tok * DIMC + t] = l;
    split2(o1, h, l); yh[(long)tok * DIMC + t + 256] = h; yl[(long)tok * DIMC + t + 256] = l;
}

// ---------------- router text part ----------------
__global__ void textpart_kernel(const float* __restrict__ w, const float* __restrict__ r_text_mu,
                                const float* __restrict__ r_comb_mu, float* __restrict__ tp) {
    __shared__ float tw[4][128];
    int t = threadIdx.x;
    for (int j = 0; j < 2; j++) {
        int idx = t + j * 256; int b = idx >> 7, c = idx & 127;
        const float* wr = w + (long)b * LATC;
        float s = 0.f;
        for (int k = 0; k < LATC; k++) s += wr[k] * r_text_mu[(long)k * 128 + c];
        tw[b][c] = s;
    }
    __syncthreads();
    if (t < 32) {
        int b = t >> 3, e = t & 7;
        float s = 0.f;
        for (int c = 0; c < 128; c++) s += tw[b][c] * r_comb_mu[(long)(128 + c) * 8 + e];
        tp[t] = s;
    }
}

// ---------------- MoE meta ----------------
__global__ void moe_init_kernel(int* __restrict__ cnt, int* __restrict__ perm) {
    int g = blockIdx.x * blockDim.x + threadIdx.x;
    if (g < MAXT * 128) perm[g] = -1;
    if (g < NE) cnt[g] = 0;
}

__global__ void route_kernel(const float* __restrict__ feat, const float* __restrict__ tp,
                             const float* __restrict__ r_comb_mu, const float* __restrict__ r_temp,
                             float* __restrict__ onehot, int* __restrict__ idx, int* __restrict__ cnt) {
    int n = blockIdx.x * blockDim.x + threadIdx.x;
    if (n >= NTOK) return;
    int b = n >> 10;
    float tmp = fmaxf(r_temp[0], 0.1f);
    float invt = 1.f / tmp;
    const float* fr = feat + (long)n * 128;
    float lg[8];
    for (int e = 0; e < 8; e++) {
        float s = 0.f;
        for (int c = 0; c < 128; c++) s += fr[c] * r_comb_mu[(long)c * 8 + e];
        lg[e] = (s + tp[b * 8 + e]) * invt;
    }
    float best = lg[0]; int bi = 0;
    for (int e = 1; e < 8; e++) { if (lg[e] > best) { best = lg[e]; bi = e; } }
    for (int e = 0; e < 8; e++) onehot[(long)n * 8 + e] = (e == bi) ? 1.f : 0.f;
    idx[n] = bi;
    atomicAdd(&cnt[bi], 1);
}

__global__ void offsets_kernel(const int* __restrict__ cnt, int* __restrict__ cursor,
                               int* __restrict__ ntiles, int* __restrict__ table) {
    if (threadIdx.x != 0) return;
    int po = 0, nt = 0;
    for (int e = 0; e < NE; e++) {
        cursor[e] = po;
        int tiles = (cnt[e] + 127) >> 7;
        for (int j = 0; j < tiles; j++) { table[2 * nt] = e; table[2 * nt + 1] = po + j * 128; nt++; }
        po += tiles * 128;
    }
    ntiles[0] = nt;
}

__global__ void scatter_kernel(const int* __restrict__ idx, int* __restrict__ cursor,
                               int* __restrict__ perm) {
    int n = blockIdx.x * blockDim.x + threadIdx.x;
    if (n >= NTOK) return;
    int e = idx[n];
    int pos = atomicAdd(&cursor[e], 1);
    perm[pos] = n;
}

extern "C" void kernel_launch(void* const* d_in, const int* in_sizes, int n_in,
                              void* d_out, int out_size, void* d_ws, size_t ws_size,
                              hipStream_t stream) {
    const float* x        = (const float*)d_in[0];
    const float* w        = (const float*)d_in[1];
    const float* text     = (const float*)d_in[2];
    const float* pin_w    = (const float*)d_in[3];
    const float* pin_mw   = (const float*)d_in[4];
    const float* pin_mb   = (const float*)d_in[5];
    const float* pout_w   = (const float*)d_in[6];
    const float* pout_mw  = (const float*)d_in[7];
    const float* pout_mb  = (const float*)d_in[8];
    const float* ln1g     = (const float*)d_in[9];
    const float* ln1b     = (const float*)d_in[10];
    const float* ln2g     = (const float*)d_in[11];
    const float* ln2b     = (const float*)d_in[12];
    const float* ln3g     = (const float*)d_in[13];
    const float* ln3b     = (const float*)d_in[14];
    const float* sa_in_w  = (const float*)d_in[15];
    const float* sa_in_b  = (const float*)d_in[16];
    const float* sa_out_w = (const float*)d_in[17];
    const float* sa_out_b = (const float*)d_in[18];
    const float* ca_in_w  = (const float*)d_in[19];
    const float* ca_in_b  = (const float*)d_in[20];
    const float* ca_out_w = (const float*)d_in[21];
    const float* ca_out_b = (const float*)d_in[22];
    const float* r_feat   = (const float*)d_in[23];
    const float* r_text   = (const float*)d_in[24];
    const float* r_comb   = (const float*)d_in[25];
    const float* r_temp   = (const float*)d_in[26];
    const float* e_w1     = (const float*)d_in[27];
    const float* e_b1     = (const float*)d_in[28];
    const float* e_w2     = (const float*)d_in[29];
    const float* e_b2     = (const float*)d_in[30];

    float* out    = (float*)d_out;               // [B, DIM, H, W]
    float* onehot = out + (long)BB * DIMC * HWX; // [4096, 8]

    // ---------------- workspace: fp32 pool ----------------
    float* f32p = (float*)d_ws;
    float* style_in  = f32p;                 // 2048
    float* style_out = f32p + 2048;          // 2048
    float* tp        = f32p + 4096;          // 32
    int*   idx       = (int*)(f32p + 4128);  // 4096
    int*   cnt       = (int*)(f32p + 8224);  // 8
    int*   cursor    = (int*)(f32p + 8232);  // 8
    int*   ntiles    = (int*)(f32p + 8240);  // 8
    int*   table     = (int*)(f32p + 8248);  // 128
    int*   perm      = (int*)(f32p + 8376);  // 5120 -> ends 13496
    float* x_flat    = f32p + 13496;         // 2097152
    float* xn        = x_flat + 2097152;     // 2097152 (dead fp32; kept for layout stability)
    float* qkv       = xn + 2097152;         // 6291456 (SA q split / CA q split home)
    float* spill     = qkv + 6291456;        // 2097152 (e2T tail)

    // ---------------- bf16 pool (phase-aliased) ----------------
    bf16* bp = (bf16*)(f32p + 12596408);
    bf16* R1 = bp;                           // 6291456 elems, 3 phases
    bf16* xT_h  = R1;
    bf16* xT_l  = R1 + 2097152;
    bf16* wtA_h = R1 + 4194304;
    bf16* wtA_l = R1 + 5242880;
    bf16* obuf_h = R1;
    bf16* obuf_l = R1 + 2097152;
    bf16* kvt_h  = R1 + 4194304;                       // [308][1024] split
    bf16* kvt_l  = kvt_h + 315392;
    float* feat  = (float*)(kvt_l + 315392);           // 524288 fp32
    bf16* wtC_h = R1;
    bf16* wtC_l = R1 + 1048576;
    bf16* xn_h = R1 + 6291456;               // 2097152
    bf16* xn_l = xn_h + 2097152;             // 2097152
    bf16* WB   = xn_l + 2097152;             // 8388608: weights (early) / hid_b (late)
    bf16* text_h   = WB;
    bf16* text_l   = text_h + 157696;
    bf16* sawin_h  = text_l + 157696;
    bf16* sawin_l  = sawin_h + 786432;
    bf16* sawout_h = sawin_l + 786432;
    bf16* sawout_l = sawout_h + 262144;
    bf16* caw_h    = sawout_l + 262144;
    bf16* caw_l    = caw_h + 786432;
    bf16* cawout_h = caw_l + 786432;
    bf16* cawout_l = cawout_h + 262144;
    bf16* rfT_h    = cawout_l + 262144;      // [128][512] split r_feat^T (dead before hid_b use)
    bf16* rfT_l    = rfT_h + 65536;
    bf16* hid_b    = WB;                     // overlays weights after ca_out
    bf16* e1T = (bf16*)qkv;                  // [8][2048][512] in qkv+spill
    bf16* e2T = e1T + 8388608;
    bf16* xfl_h = xn_h;
    bf16* xfl_l = xn_l;
    bf16* q_h = (bf16*)qkv;                  // [4096][1536]
    bf16* q_l = q_h + 6291456;
    bf16* ca_qh = (bf16*)qkv;                // [4096][512]
    bf16* ca_ql = ca_qh + 2097152;
    (void)ws_size; (void)spill; (void)xn;

    auto mg = [&](const bf16* Ah, const bf16* Al, const bf16* Bh, const bf16* Bl,
                  const float* bias, const float* resid, float* C, bf16* Oh, bf16* Ol,
                  int M, int N, int K, long ab, long bb, long cb, int csm, int csn, int nb) {
        dim3 g(N / 128, (M + 127) / 128, nb);
        hipLaunchKernelGGL(mgemm_kernel, g, dim3(256), 0, stream,
                           Ah, Al, Bh, Bl, bias, resid, C, Oh, Ol, M, N, K, ab, bb, cb, csm, csn);
    };
    auto cvt2 = [&](const float* in, bf16* h2, bf16* l2, int n) {
        hipLaunchKernelGGL(cvt2_kernel, dim3((n / 4 + 255) / 256), dim3(256), 0, stream, in, h2, l2, n);
    };

    // ---- input conversions (hi/lo) ----
    cvt2(sa_in_w, sawin_h, sawin_l, 1536 * 512);
    cvt2(sa_out_w, sawout_h, sawout_l, 512 * 512);
    cvt2(ca_in_w, caw_h, caw_l, 1536 * 512);
    cvt2(ca_out_w, cawout_h, cawout_l, 512 * 512);
    cvt2(text, text_h, text_l, BB * TXT * 512);
    hipLaunchKernelGGL(trcvt2_kernel, dim3(32, 16, BB), dim3(256), 0, stream,
                       x, xT_h, xT_l, 512, 1024, (long)512 * 1024, (long)1024 * 512);
    // r_feat [512][128] -> rfT [128][512] split
    hipLaunchKernelGGL(trcvt2_kernel, dim3(4, 16, 1), dim3(256), 0, stream,
                       r_feat, rfT_h, rfT_l, 512, 128, 0L, 0L);

    // ---- modconv in ----
    hipLaunchKernelGGL(style_kernel, dim3(8), dim3(256), 0, stream, w, pin_mw, pin_mb, style_in);
    hipLaunchKernelGGL(wtmod_kernel, dim3(BB * DIMC), dim3(256), 0, stream, pin_w, style_in, wtA_h, wtA_l);
    mg(xT_h, xT_l, wtA_h, wtA_l, nullptr, nullptr, x_flat, nullptr, nullptr,
       HWX, DIMC, DIMC, (long)HWX * DIMC, (long)DIMC * DIMC, (long)HWX * DIMC, DIMC, 1, BB);

    // ---- LN1 + self-attention (split MFMA) ----
    hipLaunchKernelGGL(ln_kernel, dim3(NTOK), dim3(256), 0, stream, x_flat, ln1g, ln1b,
                       (float*)nullptr, xn_h, xn_l);
    mg(xn_h, xn_l, sawin_h, sawin_l, sa_in_b, nullptr, nullptr, q_h, q_l,
       NTOK, 1536, 512, 0, 0, 0, 1536, 1, 1);
    hipLaunchKernelGGL(sa_mfma_kernel, dim3(16, HEADS, BB), dim3(256), 0, stream,
                       q_h, q_l, obuf_h, obuf_l);
    mg(obuf_h, obuf_l, sawout_h, sawout_l, sa_out_b, x_flat, x_flat, nullptr, nullptr,
       NTOK, 512, 512, 0, 0, 0, 512, 1, 1);

    // ---- LN2 + cross-attention (split MFMA) ----
    hipLaunchKernelGGL(ln_kernel, dim3(NTOK), dim3(256), 0, stream, x_flat, ln2g, ln2b,
                       (float*)nullptr, xn_h, xn_l);
    mg(xn_h, xn_l, caw_h, caw_l, ca_in_b, nullptr, nullptr, ca_qh, ca_ql,
       NTOK, 512, 512, 0, 0, 0, 512, 1, 1);
    mg(text_h, text_l, caw_h + 512 * 512, caw_l + 512 * 512, ca_in_b + 512, nullptr, nullptr,
       kvt_h, kvt_l, BB * TXT, 1024, 512, 0, 0, 0, 1024, 1, 1);
    hipLaunchKernelGGL(ca_mfma_kernel, dim3(16, HEADS, BB), dim3(256), 0, stream,
                       ca_qh, ca_ql, kvt_h, kvt_l, obuf_h, obuf_l);
    // qkv region dead after ca_mfma -> build expert weight transposes there
    hipLaunchKernelGGL(trcvt_kernel, dim3(64, 16, NE), dim3(256), 0, stream,
                       e_w1, e1T, 512, 2048, (long)512 * 2048, (long)2048 * 512);
    hipLaunchKernelGGL(trcvt_kernel, dim3(16, 64, NE), dim3(256), 0, stream,
                       e_w2, e2T, 2048, 512, (long)2048 * 512, (long)512 * 2048);
    mg(obuf_h, obuf_l, cawout_h, cawout_l, ca_out_b, x_flat, x_flat, nullptr, nullptr,
       NTOK, 512, 512, 0, 0, 0, 512, 1, 1);

    // ---- LN3 + router (feat via split MFMA) ----
    hipLaunchKernelGGL(ln_kernel, dim3(NTOK), dim3(256), 0, stream, x_flat, ln3g, ln3b,
                       (float*)nullptr, xn_h, xn_l);
    mg(xn_h, xn_l, rfT_h, rfT_l, nullptr, nullptr, feat, nullptr, nullptr,
       NTOK, 128, 512, 0, 0, 0, 128, 1, 1);
    hipLaunchKernelGGL(textpart_kernel, dim3(1), dim3(256), 0, stream, w, r_text, r_comb, tp);
    hipLaunchKernelGGL(moe_init_kernel, dim3((MAXT * 128 + 255) / 256), dim3(256), 0, stream, cnt, perm);
    hipLaunchKernelGGL(route_kernel, dim3(16), dim3(256), 0, stream, feat, tp, r_comb, r_temp, onehot, idx, cnt);
    hipLaunchKernelGGL(offsets_kernel, dim3(1), dim3(64), 0, stream, cnt, cursor, ntiles, table);
    hipLaunchKernelGGL(scatter_kernel, dim3(16), dim3(256), 0, stream, idx, cursor, perm);

    // ---- MoE grouped MFMA GEMMs ----
    hipLaunchKernelGGL(moe_mfma1_kernel, dim3(HIDC / 128, MAXT), dim3(256), 0, stream,
                       xn_h, e1T, e_b1, table, ntiles, perm, hid_b);
    hipLaunchKernelGGL(moe_mfma2_kernel, dim3(DIMC / 128, MAXT), dim3(256), 0, stream,
                       hid_b, e2T, e_b2, table, ntiles, perm, x_flat);

    // ---- modconv out (split both sides) ----
    cvt2(x_flat, xfl_h, xfl_l, NTOK * DIMC);
    hipLaunchKernelGGL(style_kernel, dim3(8), dim3(256), 0, stream, w, pout_mw, pout_mb, style_out);
    hipLaunchKernelGGL(wtmod_kernel, dim3(BB * DIMC), dim3(256), 0, stream, pout_w, style_out, wtC_h, wtC_l);
    mg(wtC_h, wtC_l, xfl_h, xfl_l, nullptr, nullptr, out, nullptr, nullptr,
       DIMC, HWX, DIMC, (long)DIMC * DIMC, (long)HWX * DIMC, (long)DIMC * HWX, HWX, 1, BB);
}

// Round 9
// 701.448 us; speedup vs baseline: 7.8913x; 1.0382x over previous
//
#include <hip/hip_runtime.h>
#include <hip/hip_bf16.h>
#include <math.h>

#define DIMC 512
#define HEADS 8
#define HD 64
#define BB 4
#define HWX 1024
#define TXT 77
#define LATC 512
#define NE 8
#define HIDC 2048
#define NTOK 4096
#define MAXT 40

typedef __attribute__((ext_vector_type(8))) short bf16x8;
typedef __attribute__((ext_vector_type(4))) float f32x4;
typedef __hip_bfloat16 bf16;

__device__ __forceinline__ void split2(float v, bf16& h, bf16& l) {
    h = __float2bfloat16(v);
    l = __float2bfloat16(v - __bfloat162float(h));
}
__device__ __forceinline__ void split2s(float v, short& h, short& l) {
    bf16 hb, lb; split2(v, hb, lb);
    h = *(short*)&hb; l = *(short*)&lb;
}

// ---------------- style = w @ mod_w.T + mod_b ----------------
__global__ void style_kernel(const float* __restrict__ w, const float* __restrict__ mod_w,
                             const float* __restrict__ mod_b, float* __restrict__ style) {
    int t = blockIdx.x * blockDim.x + threadIdx.x;
    if (t >= BB * DIMC) return;
    int b = t / DIMC, i = t % DIMC;
    const float* wr = w + (long)b * LATC;
    const float* mr = mod_w + (long)i * LATC;
    float s = 0.f;
    #pragma unroll 8
    for (int l = 0; l < LATC; l++) s += wr[l] * mr[l];
    style[t] = s + mod_b[i];
}

// ------- wtmod[b,o,i] -> bf16 hi/lo (demodulated per-sample weight) -------
__global__ void wtmod_kernel(const float* __restrict__ weight, const float* __restrict__ style,
                             bf16* __restrict__ wh, bf16* __restrict__ wl) {
    int bo = blockIdx.x;
    int b = bo / DIMC, o = bo % DIMC;
    const float* wr = weight + (long)o * DIMC;
    const float* sr = style + (long)b * DIMC;
    int t = threadIdx.x;
    float vals[2]; float part = 0.f;
    for (int j = 0; j < 2; j++) {
        int i = t + j * 256;
        float v = wr[i] * sr[i];
        vals[j] = v; part += v * v;
    }
    __shared__ float red[256];
    red[t] = part; __syncthreads();
    for (int s = 128; s > 0; s >>= 1) { if (t < s) red[t] += red[t + s]; __syncthreads(); }
    float d = rsqrtf(red[0] + 1e-8f);
    for (int j = 0; j < 2; j++) {
        int i = t + j * 256;
        bf16 h, l; split2(vals[j] * d, h, l);
        wh[(long)bo * DIMC + i] = h; wl[(long)bo * DIMC + i] = l;
    }
}

// ---------------- fp32 -> bf16 hi/lo convert (flat) ----------------
__global__ void cvt2_kernel(const float* __restrict__ in, bf16* __restrict__ hi,
                            bf16* __restrict__ lo, int n) {
    int i = (blockIdx.x * blockDim.x + threadIdx.x) * 4;
    if (i >= n) return;
    float4 v = *(const float4*)(in + i);
    float a[4] = {v.x, v.y, v.z, v.w};
    #pragma unroll
    for (int j = 0; j < 4; j++) { bf16 h, l; split2(a[j], h, l); hi[i + j] = h; lo[i + j] = l; }
}

// ---------------- fp32 [R][C] -> bf16 [C][R] transpose hi/lo ----------------
__global__ void trcvt2_kernel(const float* __restrict__ in, bf16* __restrict__ hi,
                              bf16* __restrict__ lo, int R, int C, long in_bat, long out_bat) {
    __shared__ float tile[32][33];
    in += (long)blockIdx.z * in_bat; hi += (long)blockIdx.z * out_bat; lo += (long)blockIdx.z * out_bat;
    int c0 = blockIdx.x * 32, r0 = blockIdx.y * 32;
    int tc = threadIdx.x & 31, tr = threadIdx.x >> 5;
    #pragma unroll
    for (int i = 0; i < 4; i++) {
        int r = tr + i * 8;
        tile[r][tc] = in[(long)(r0 + r) * C + c0 + tc];
    }
    __syncthreads();
    #pragma unroll
    for (int i = 0; i < 4; i++) {
        int r = tr + i * 8;
        bf16 h, l; split2(tile[tc][r], h, l);
        hi[(long)(c0 + r) * R + r0 + tc] = h;
        lo[(long)(c0 + r) * R + r0 + tc] = l;
    }
}

// ---------------- fp32 [R][C] -> bf16 [C][R] transpose (single) ----------------
__global__ void trcvt_kernel(const float* __restrict__ in, bf16* __restrict__ out,
                             int R, int C, long in_bat, long out_bat) {
    __shared__ float tile[32][33];
    in += (long)blockIdx.z * in_bat; out += (long)blockIdx.z * out_bat;
    int c0 = blockIdx.x * 32, r0 = blockIdx.y * 32;
    int tc = threadIdx.x & 31, tr = threadIdx.x >> 5;
    #pragma unroll
    for (int i = 0; i < 4; i++) {
        int r = tr + i * 8;
        tile[r][tc] = in[(long)(r0 + r) * C + c0 + tc];
    }
    __syncthreads();
    #pragma unroll
    for (int i = 0; i < 4; i++) {
        int r = tr + i * 8;
        out[(long)(c0 + r) * R + r0 + tc] = __float2bfloat16(tile[tc][r]);
    }
}

// ---- split-precision bf16 MFMA GEMM: C = A·B^T with A=Ah+Al, B=Bh+Bl ----
// acc += Ah·Bh + Ah·Bl + Al·Bh. Register-prefetch pipeline (T14-lite).
__global__ __launch_bounds__(256) void mgemm_kernel(
    const bf16* __restrict__ Ah, const bf16* __restrict__ Al,
    const bf16* __restrict__ Bh, const bf16* __restrict__ Bl,
    const float* __restrict__ bias, const float* __restrict__ resid, float* __restrict__ C,
    bf16* __restrict__ Oh, bf16* __restrict__ Ol,
    int M, int N, int K, long a_bat, long b_bat, long c_bat, int cs_m, int cs_n) {
    __shared__ short AsH[128 * 32];
    __shared__ short AsL[128 * 32];
    __shared__ short BsH[128 * 32];
    __shared__ short BsL[128 * 32];
    int bat = blockIdx.z;
    const short* AbH = (const short*)(Ah + (long)bat * a_bat);
    const short* AbL = (const short*)(Al + (long)bat * a_bat);
    const short* BbH = (const short*)(Bh + (long)bat * b_bat);
    const short* BbL = (const short*)(Bl + (long)bat * b_bat);
    float* Cb = C + (long)bat * c_bat;
    const float* Rb = resid ? resid + (long)bat * c_bat : nullptr;
    int bm = blockIdx.y * 128, bn = blockIdx.x * 128;
    int t = threadIdx.x, lane = t & 63, w = t >> 6;
    int wm = (w >> 1) * 64, wn = (w & 1) * 64;
    int p0 = t, p1 = t + 256;
    int r0 = p0 >> 2, k0s = (p0 & 3) ^ ((r0 >> 1) & 3);
    int r1 = p1 >> 2, k1s = (p1 & 3) ^ ((r1 >> 1) & 3);
    int ar0 = bm + r0; if (ar0 > M - 1) ar0 = M - 1;
    int ar1 = bm + r1; if (ar1 > M - 1) ar1 = M - 1;
    long aoff0 = (long)ar0 * K + k0s * 8, aoff1 = (long)ar1 * K + k1s * 8;
    long boff0 = (long)(bn + r0) * K + k0s * 8, boff1 = (long)(bn + r1) * K + k1s * 8;
    int fr = lane & 15, fq = lane >> 4;
    int aOff[4], bOff[4];
    #pragma unroll
    for (int i = 0; i < 4; i++) {
        int row = wm + i * 16 + fr;
        aOff[i] = row * 32 + ((fq ^ ((row >> 1) & 3)) * 8);
        int col = wn + i * 16 + fr;
        bOff[i] = col * 32 + ((fq ^ ((col >> 1) & 3)) * 8);
    }
    f32x4 acc[4][4] = {};
    // prologue loads (kk = 0)
    bf16x8 vah0 = *(const bf16x8*)(AbH + aoff0);
    bf16x8 vah1 = *(const bf16x8*)(AbH + aoff1);
    bf16x8 val0 = *(const bf16x8*)(AbL + aoff0);
    bf16x8 val1 = *(const bf16x8*)(AbL + aoff1);
    bf16x8 vbh0 = *(const bf16x8*)(BbH + boff0);
    bf16x8 vbh1 = *(const bf16x8*)(BbH + boff1);
    bf16x8 vbl0 = *(const bf16x8*)(BbL + boff0);
    bf16x8 vbl1 = *(const bf16x8*)(BbL + boff1);
    for (int kk = 0; kk < K; kk += 32) {
        __syncthreads();
        *(bf16x8*)&AsH[p0 * 8] = vah0;  *(bf16x8*)&AsH[p1 * 8] = vah1;
        *(bf16x8*)&AsL[p0 * 8] = val0;  *(bf16x8*)&AsL[p1 * 8] = val1;
        *(bf16x8*)&BsH[p0 * 8] = vbh0;  *(bf16x8*)&BsH[p1 * 8] = vbh1;
        *(bf16x8*)&BsL[p0 * 8] = vbl0;  *(bf16x8*)&BsL[p1 * 8] = vbl1;
        // prefetch next K-tile (clamped redundant reload on last iter)
        int kn = (kk + 32 < K) ? kk + 32 : kk;
        bf16x8 nah0 = *(const bf16x8*)(AbH + aoff0 + kn);
        bf16x8 nah1 = *(const bf16x8*)(AbH + aoff1 + kn);
        bf16x8 nal0 = *(const bf16x8*)(AbL + aoff0 + kn);
        bf16x8 nal1 = *(const bf16x8*)(AbL + aoff1 + kn);
        bf16x8 nbh0 = *(const bf16x8*)(BbH + boff0 + kn);
        bf16x8 nbh1 = *(const bf16x8*)(BbH + boff1 + kn);
        bf16x8 nbl0 = *(const bf16x8*)(BbL + boff0 + kn);
        bf16x8 nbl1 = *(const bf16x8*)(BbL + boff1 + kn);
        __syncthreads();
        bf16x8 aH[4], aL[4], bH[4], bL[4];
        #pragma unroll
        for (int i = 0; i < 4; i++) {
            aH[i] = *(const bf16x8*)&AsH[aOff[i]];
            aL[i] = *(const bf16x8*)&AsL[aOff[i]];
            bH[i] = *(const bf16x8*)&BsH[bOff[i]];
            bL[i] = *(const bf16x8*)&BsL[bOff[i]];
        }
        #pragma unroll
        for (int i = 0; i < 4; i++)
        #pragma unroll
        for (int j = 0; j < 4; j++) {
            acc[i][j] = __builtin_amdgcn_mfma_f32_16x16x32_bf16(aH[i], bH[j], acc[i][j], 0, 0, 0);
            acc[i][j] = __builtin_amdgcn_mfma_f32_16x16x32_bf16(aH[i], bL[j], acc[i][j], 0, 0, 0);
            acc[i][j] = __builtin_amdgcn_mfma_f32_16x16x32_bf16(aL[i], bH[j], acc[i][j], 0, 0, 0);
        }
        vah0 = nah0; vah1 = nah1; val0 = nal0; val1 = nal1;
        vbh0 = nbh0; vbh1 = nbh1; vbl0 = nbl0; vbl1 = nbl1;
    }
    #pragma unroll
    for (int i = 0; i < 4; i++)
    #pragma unroll
    for (int j = 0; j < 4; j++)
    #pragma unroll
    for (int r = 0; r < 4; r++) {
        int row = bm + wm + i * 16 + fq * 4 + r;
        int col = bn + wn + j * 16 + fr;
        if (row < M) {
            long off = (long)row * cs_m + (long)col * cs_n;
            float v = acc[i][j][r];
            if (bias) v += bias[col];
            if (Oh) {
                bf16 hh, ll; split2(v, hh, ll);
                Oh[off] = hh; Ol[off] = ll;
            } else {
                if (Rb) v += Rb[off];
                Cb[off] = v;
            }
        }
    }
}

// ---- split-precision MFMA flash self-attention (prefetched, setprio) ----
__global__ __launch_bounds__(256) void sa_mfma_kernel(
    const bf16* __restrict__ qh, const bf16* __restrict__ ql,
    bf16* __restrict__ oh, bf16* __restrict__ ol) {
    int qt = blockIdx.x, h = blockIdx.y, b = blockIdx.z;
    __shared__ short KsH[4096], KsL[4096];     // [kv][d], swz: col ^ ((kv&7)<<3)
    __shared__ short VtH[4096], VtL[4096];     // [d][kv], swz: col ^ (((d>>3)&7)<<3)
    __shared__ short PHs[4][1024], PLs[4][1024]; // per-wave P [q][kv], swz: col ^ ((q&7)<<3)
    int t = threadIdx.x, lane = t & 63, w = t >> 6;
    int fr = lane & 15, fq = lane >> 4;
    const short* QH = (const short*)qh;
    const short* QL = (const short*)ql;
    long qrow = (long)(b * 1024 + qt * 64 + w * 16 + fr) * 1536 + h * 64;
    bf16x8 Qh2[2], Ql2[2];
    Qh2[0] = *(const bf16x8*)(QH + qrow + fq * 8);
    Qh2[1] = *(const bf16x8*)(QH + qrow + 32 + fq * 8);
    Ql2[0] = *(const bf16x8*)(QL + qrow + fq * 8);
    Ql2[1] = *(const bf16x8*)(QL + qrow + 32 + fq * 8);
    float m_i[4], l_i[4];
    f32x4 o_acc[4] = {};
    #pragma unroll
    for (int i = 0; i < 4; i++) { m_i[i] = -1e30f; l_i[i] = 0.f; }
    int c0 = t, c1 = t + 256;
    int r0 = c0 >> 3, g0 = c0 & 7;
    int r1 = c1 >> 3, g1 = c1 & 7;
    int kd0 = r0 * 64 + ((g0 * 8) ^ ((r0 & 7) << 3));
    int kd1 = r1 * 64 + ((g1 * 8) ^ ((r1 & 7) << 3));
    long kb = (long)(b * 1024) * 1536 + 512 + h * 64;
    long vb = kb + 512;
    long lo0 = (long)r0 * 1536 + g0 * 8, lo1 = (long)r1 * 1536 + g1 * 8;
    short* ph = PHs[w]; short* pl = PLs[w];
    // prologue loads (kt = 0)
    bf16x8 kh0 = *(const bf16x8*)(QH + kb + lo0);
    bf16x8 kh1 = *(const bf16x8*)(QH + kb + lo1);
    bf16x8 kl0 = *(const bf16x8*)(QL + kb + lo0);
    bf16x8 kl1 = *(const bf16x8*)(QL + kb + lo1);
    bf16x8 vh0 = *(const bf16x8*)(QH + vb + lo0);
    bf16x8 vh1 = *(const bf16x8*)(QH + vb + lo1);
    bf16x8 vl0 = *(const bf16x8*)(QL + vb + lo0);
    bf16x8 vl1 = *(const bf16x8*)(QL + vb + lo1);
    for (int kt = 0; kt < 16; kt++) {
        __syncthreads();   // A: previous iteration's Ks/Vt reads complete
        *(bf16x8*)&KsH[kd0] = kh0;  *(bf16x8*)&KsH[kd1] = kh1;
        *(bf16x8*)&KsL[kd0] = kl0;  *(bf16x8*)&KsL[kd1] = kl1;
        #pragma unroll
        for (int j = 0; j < 8; j++) {
            int d0 = g0 * 8 + j;
            int i0 = d0 * 64 + (r0 ^ (((d0 >> 3) & 7) << 3));
            VtH[i0] = ((short*)&vh0)[j];  VtL[i0] = ((short*)&vl0)[j];
            int d1 = g1 * 8 + j;
            int i1 = d1 * 64 + (r1 ^ (((d1 >> 3) & 7) << 3));
            VtH[i1] = ((short*)&vh1)[j];  VtL[i1] = ((short*)&vl1)[j];
        }
        // prefetch next KV tile (clamped on last iter)
        int ktn = (kt + 1 < 16) ? kt + 1 : kt;
        long ko = kb + (long)(ktn * 64) * 1536;
        long vo = vb + (long)(ktn * 64) * 1536;
        bf16x8 nkh0 = *(const bf16x8*)(QH + ko + lo0);
        bf16x8 nkh1 = *(const bf16x8*)(QH + ko + lo1);
        bf16x8 nkl0 = *(const bf16x8*)(QL + ko + lo0);
        bf16x8 nkl1 = *(const bf16x8*)(QL + ko + lo1);
        bf16x8 nvh0 = *(const bf16x8*)(QH + vo + lo0);
        bf16x8 nvh1 = *(const bf16x8*)(QH + vo + lo1);
        bf16x8 nvl0 = *(const bf16x8*)(QL + vo + lo0);
        bf16x8 nvl1 = *(const bf16x8*)(QL + vo + lo1);
        __syncthreads();   // B: staging complete
        __builtin_amdgcn_s_setprio(1);
        f32x4 s[4] = {};
        #pragma unroll
        for (int cf = 0; cf < 4; cf++) {
            int kvrow = cf * 16 + fr;
            #pragma unroll
            for (int kf = 0; kf < 2; kf++) {
                int idx = kvrow * 64 + ((kf * 32 + fq * 8) ^ ((kvrow & 7) << 3));
                bf16x8 Bh2 = *(const bf16x8*)&KsH[idx];
                bf16x8 Bl2 = *(const bf16x8*)&KsL[idx];
                s[cf] = __builtin_amdgcn_mfma_f32_16x16x32_bf16(Qh2[kf], Bh2, s[cf], 0, 0, 0);
                s[cf] = __builtin_amdgcn_mfma_f32_16x16x32_bf16(Qh2[kf], Bl2, s[cf], 0, 0, 0);
                s[cf] = __builtin_amdgcn_mfma_f32_16x16x32_bf16(Ql2[kf], Bh2, s[cf], 0, 0, 0);
            }
        }
        __builtin_amdgcn_s_setprio(0);
        #pragma unroll
        for (int cf = 0; cf < 4; cf++)
        #pragma unroll
        for (int reg = 0; reg < 4; reg++) s[cf][reg] *= 0.125f;
        float sc_[4];
        #pragma unroll
        for (int reg = 0; reg < 4; reg++) {
            float mx = fmaxf(fmaxf(s[0][reg], s[1][reg]), fmaxf(s[2][reg], s[3][reg]));
            mx = fmaxf(mx, __shfl_xor(mx, 1));
            mx = fmaxf(mx, __shfl_xor(mx, 2));
            mx = fmaxf(mx, __shfl_xor(mx, 4));
            mx = fmaxf(mx, __shfl_xor(mx, 8));
            float mn = fmaxf(m_i[reg], mx);
            sc_[reg] = __expf(m_i[reg] - mn);
            m_i[reg] = mn;
            float rs = 0.f;
            #pragma unroll
            for (int cf = 0; cf < 4; cf++) { s[cf][reg] = __expf(s[cf][reg] - mn); rs += s[cf][reg]; }
            rs += __shfl_xor(rs, 1);
            rs += __shfl_xor(rs, 2);
            rs += __shfl_xor(rs, 4);
            rs += __shfl_xor(rs, 8);
            l_i[reg] = l_i[reg] * sc_[reg] + rs;
        }
        #pragma unroll
        for (int cf = 0; cf < 4; cf++)
        #pragma unroll
        for (int reg = 0; reg < 4; reg++) o_acc[cf][reg] *= sc_[reg];
        #pragma unroll
        for (int cf = 0; cf < 4; cf++)
        #pragma unroll
        for (int reg = 0; reg < 4; reg++) {
            int q = fq * 4 + reg, kv = cf * 16 + fr;
            int idx = q * 64 + (kv ^ ((q & 7) << 3));
            split2s(s[cf][reg], ph[idx], pl[idx]);
        }
        __syncthreads();   // C: P writes ordered before reads
        __builtin_amdgcn_s_setprio(1);
        bf16x8 Pf_h[2], Pf_l[2];
        #pragma unroll
        for (int kf = 0; kf < 2; kf++) {
            int idx = fr * 64 + ((kf * 32 + fq * 8) ^ ((fr & 7) << 3));
            Pf_h[kf] = *(const bf16x8*)&ph[idx];
            Pf_l[kf] = *(const bf16x8*)&pl[idx];
        }
        #pragma unroll
        for (int cf = 0; cf < 4; cf++) {
            int d = cf * 16 + fr;
            #pragma unroll
            for (int kf = 0; kf < 2; kf++) {
                int idx = d * 64 + ((kf * 32 + fq * 8) ^ (((d >> 3) & 7) << 3));
                bf16x8 Vh2 = *(const bf16x8*)&VtH[idx];
                bf16x8 Vl2 = *(const bf16x8*)&VtL[idx];
                o_acc[cf] = __builtin_amdgcn_mfma_f32_16x16x32_bf16(Pf_h[kf], Vh2, o_acc[cf], 0, 0, 0);
                o_acc[cf] = __builtin_amdgcn_mfma_f32_16x16x32_bf16(Pf_h[kf], Vl2, o_acc[cf], 0, 0, 0);
                o_acc[cf] = __builtin_amdgcn_mfma_f32_16x16x32_bf16(Pf_l[kf], Vh2, o_acc[cf], 0, 0, 0);
            }
        }
        __builtin_amdgcn_s_setprio(0);
        kh0 = nkh0; kh1 = nkh1; kl0 = nkl0; kl1 = nkl1;
        vh0 = nvh0; vh1 = nvh1; vl0 = nvl0; vl1 = nvl1;
    }
    #pragma unroll
    for (int reg = 0; reg < 4; reg++) {
        float inv = 1.f / l_i[reg];
        long m = (long)(b * 1024 + qt * 64 + w * 16 + fq * 4 + reg);
        #pragma unroll
        for (int cf = 0; cf < 4; cf++) {
            float v = o_acc[cf][reg] * inv;
            bf16 hh, ll; split2(v, hh, ll);
            long off = m * DIMC + h * 64 + cf * 16 + fr;
            oh[off] = hh; ol[off] = ll;
        }
    }
}

// ---- split-precision MFMA cross-attention: 77 keys padded to 96, single tile ----
__global__ __launch_bounds__(256) void ca_mfma_kernel(
    const bf16* __restrict__ qh, const bf16* __restrict__ ql,
    const bf16* __restrict__ kvh, const bf16* __restrict__ kvl,
    bf16* __restrict__ oh, bf16* __restrict__ ol) {
    int qt = blockIdx.x, h = blockIdx.y, b = blockIdx.z;
    __shared__ short UH[8192], UL[8192];          // K [96][64] swz -> reused as Vt [64][128] swz
    __shared__ short PHs[4][2048], PLs[4][2048];  // per-wave P [16 q][128 kv-padded]
    int t = threadIdx.x, lane = t & 63, w = t >> 6;
    int fr = lane & 15, fq = lane >> 4;
    const short* QH = (const short*)qh;
    const short* QL = (const short*)ql;
    const short* KVH = (const short*)kvh;
    const short* KVL = (const short*)kvl;
    long qrow = (long)(b * 1024 + qt * 64 + w * 16 + fr) * DIMC + h * 64;
    bf16x8 Qh2[2], Ql2[2];
    Qh2[0] = *(const bf16x8*)(QH + qrow + fq * 8);
    Qh2[1] = *(const bf16x8*)(QH + qrow + 32 + fq * 8);
    Ql2[0] = *(const bf16x8*)(QL + qrow + fq * 8);
    Ql2[1] = *(const bf16x8*)(QL + qrow + 32 + fq * 8);
    for (int c = t; c < 768; c += 256) {
        int r = c >> 3, g = c & 7;
        int idx = r * 64 + ((g * 8) ^ ((r & 7) << 3));
        bf16x8 vh = {}, vl = {};
        if (r < 77) {
            long src = (long)(b * 77 + r) * 1024 + h * 64 + g * 8;
            vh = *(const bf16x8*)(KVH + src);
            vl = *(const bf16x8*)(KVL + src);
        }
        *(bf16x8*)&UH[idx] = vh;
        *(bf16x8*)&UL[idx] = vl;
    }
    __syncthreads();
    f32x4 s[5] = {};
    #pragma unroll
    for (int cf = 0; cf < 5; cf++) {
        int kvrow = cf * 16 + fr;
        #pragma unroll
        for (int kf = 0; kf < 2; kf++) {
            int idx = kvrow * 64 + ((kf * 32 + fq * 8) ^ ((kvrow & 7) << 3));
            bf16x8 Bh2 = *(const bf16x8*)&UH[idx];
            bf16x8 Bl2 = *(const bf16x8*)&UL[idx];
            s[cf] = __builtin_amdgcn_mfma_f32_16x16x32_bf16(Qh2[kf], Bh2, s[cf], 0, 0, 0);
            s[cf] = __builtin_amdgcn_mfma_f32_16x16x32_bf16(Qh2[kf], Bl2, s[cf], 0, 0, 0);
            s[cf] = __builtin_amdgcn_mfma_f32_16x16x32_bf16(Ql2[kf], Bh2, s[cf], 0, 0, 0);
        }
    }
    #pragma unroll
    for (int cf = 0; cf < 5; cf++) {
        int kv = cf * 16 + fr;
        #pragma unroll
        for (int reg = 0; reg < 4; reg++)
            s[cf][reg] = (kv < 77) ? s[cf][reg] * 0.125f : -1e30f;
    }
    float inv[4];
    #pragma unroll
    for (int reg = 0; reg < 4; reg++) {
        float mx = s[0][reg];
        #pragma unroll
        for (int cf = 1; cf < 5; cf++) mx = fmaxf(mx, s[cf][reg]);
        mx = fmaxf(mx, __shfl_xor(mx, 1));
        mx = fmaxf(mx, __shfl_xor(mx, 2));
        mx = fmaxf(mx, __shfl_xor(mx, 4));
        mx = fmaxf(mx, __shfl_xor(mx, 8));
        float rs = 0.f;
        #pragma unroll
        for (int cf = 0; cf < 5; cf++) { s[cf][reg] = __expf(s[cf][reg] - mx); rs += s[cf][reg]; }
        rs += __shfl_xor(rs, 1);
        rs += __shfl_xor(rs, 2);
        rs += __shfl_xor(rs, 4);
        rs += __shfl_xor(rs, 8);
        inv[reg] = 1.f / rs;
    }
    short* ph = PHs[w]; short* pl = PLs[w];
    #pragma unroll
    for (int cf = 0; cf < 6; cf++)
    #pragma unroll
    for (int reg = 0; reg < 4; reg++) {
        int q = fq * 4 + reg, kv = cf * 16 + fr;
        int idx = q * 128 + (kv ^ ((q & 7) << 3));
        float pv = (cf < 5) ? s[cf][reg] * inv[reg] : 0.f;
        split2s(pv, ph[idx], pl[idx]);
    }
    __syncthreads();
    for (int c = t; c < 768; c += 256) {
        int r = c >> 3, g = c & 7;
        bf16x8 vh = {}, vl = {};
        if (r < 77) {
            long src = (long)(b * 77 + r) * 1024 + 512 + h * 64 + g * 8;
            vh = *(const bf16x8*)(KVH + src);
            vl = *(const bf16x8*)(KVL + src);
        }
        #pragma unroll
        for (int j = 0; j < 8; j++) {
            int d = g * 8 + j;
            int idx = d * 128 + (r ^ (((d >> 3) & 7) << 3));
            UH[idx] = ((short*)&vh)[j];
            UL[idx] = ((short*)&vl)[j];
        }
    }
    __syncthreads();
    f32x4 o_acc[4] = {};
    bf16x8 Pf_h[3], Pf_l[3];
    #pragma unroll
    for (int kf = 0; kf < 3; kf++) {
        int idx = fr * 128 + ((kf * 32 + fq * 8) ^ ((fr & 7) << 3));
        Pf_h[kf] = *(const bf16x8*)&ph[idx];
        Pf_l[kf] = *(const bf16x8*)&pl[idx];
    }
    #pragma unroll
    for (int cf = 0; cf < 4; cf++) {
        int d = cf * 16 + fr;
        #pragma unroll
        for (int kf = 0; kf < 3; kf++) {
            int idx = d * 128 + ((kf * 32 + fq * 8) ^ (((d >> 3) & 7) << 3));
            bf16x8 Vh2 = *(const bf16x8*)&UH[idx];
            bf16x8 Vl2 = *(const bf16x8*)&UL[idx];
            o_acc[cf] = __builtin_amdgcn_mfma_f32_16x16x32_bf16(Pf_h[kf], Vh2, o_acc[cf], 0, 0, 0);
            o_acc[cf] = __builtin_amdgcn_mfma_f32_16x16x32_bf16(Pf_h[kf], Vl2, o_acc[cf], 0, 0, 0);
            o_acc[cf] = __builtin_amdgcn_mfma_f32_16x16x32_bf16(Pf_l[kf], Vh2, o_acc[cf], 0, 0, 0);
        }
    }
    #pragma unroll
    for (int reg = 0; reg < 4; reg++) {
        long m = (long)(b * 1024 + qt * 64 + w * 16 + fq * 4 + reg);
        #pragma unroll
        for (int cf = 0; cf < 4; cf++) {
            bf16 hh, ll; split2(o_acc[cf][reg], hh, ll);
            long off = m * DIMC + h * 64 + cf * 16 + fr;
            oh[off] = hh; ol[off] = ll;
        }
    }
}

// ---- MoE grouped MFMA GEMM1 (plain bf16, prefetched): hid = gelu(xn·w1 + b1) ----
__global__ __launch_bounds__(256) void moe_mfma1_kernel(
    const bf16* __restrict__ xn_b, const bf16* __restrict__ e1T, const float* __restrict__ e_b1,
    const int* __restrict__ table, const int* __restrict__ ntiles, const int* __restrict__ perm,
    bf16* __restrict__ hid_b) {
    if (blockIdx.y >= ntiles[0]) return;
    int e = table[2 * blockIdx.y], row0 = table[2 * blockIdx.y + 1];
    int bn = blockIdx.x * 128;
    __shared__ short As[128 * 32];
    __shared__ short Bs[128 * 32];
    __shared__ int rowsS[128];
    int t = threadIdx.x, lane = t & 63, w = t >> 6;
    if (t < 128) rowsS[t] = perm[row0 + t];
    __syncthreads();
    int wm = (w >> 1) * 64, wn = (w & 1) * 64;
    int p0 = t, p1 = t + 256;
    int r0 = p0 >> 2, k0s = (p0 & 3) ^ ((r0 >> 1) & 3);
    int r1 = p1 >> 2, k1s = (p1 & 3) ^ ((r1 >> 1) & 3);
    int tok0 = rowsS[r0]; if (tok0 < 0) tok0 = 0;
    int tok1 = rowsS[r1]; if (tok1 < 0) tok1 = 0;
    const short* Xs = (const short*)xn_b;
    const short* Ws = (const short*)(e1T + (long)e * HIDC * DIMC);
    const short* a0 = Xs + (long)tok0 * DIMC + k0s * 8;
    const short* a1 = Xs + (long)tok1 * DIMC + k1s * 8;
    const short* b0 = Ws + (long)(bn + r0) * DIMC + k0s * 8;
    const short* b1 = Ws + (long)(bn + r1) * DIMC + k1s * 8;
    int fr = lane & 15, fq = lane >> 4;
    int aOff[4], bOff[4];
    #pragma unroll
    for (int i = 0; i < 4; i++) {
        int row = wm + i * 16 + fr;
        aOff[i] = row * 32 + ((fq ^ ((row >> 1) & 3)) * 8);
        int col = wn + i * 16 + fr;
        bOff[i] = col * 32 + ((fq ^ ((col >> 1) & 3)) * 8);
    }
    f32x4 acc[4][4] = {};
    bf16x8 va0 = *(const bf16x8*)(a0);
    bf16x8 va1 = *(const bf16x8*)(a1);
    bf16x8 vb0 = *(const bf16x8*)(b0);
    bf16x8 vb1 = *(const bf16x8*)(b1);
    for (int kk = 0; kk < DIMC; kk += 32) {
        __syncthreads();
        *(bf16x8*)&As[p0 * 8] = va0;  *(bf16x8*)&As[p1 * 8] = va1;
        *(bf16x8*)&Bs[p0 * 8] = vb0;  *(bf16x8*)&Bs[p1 * 8] = vb1;
        int kn = (kk + 32 < DIMC) ? kk + 32 : kk;
        bf16x8 na0 = *(const bf16x8*)(a0 + kn);
        bf16x8 na1 = *(const bf16x8*)(a1 + kn);
        bf16x8 nb0 = *(const bf16x8*)(b0 + kn);
        bf16x8 nb1 = *(const bf16x8*)(b1 + kn);
        __syncthreads();
        bf16x8 aF[4], bF[4];
        #pragma unroll
        for (int i = 0; i < 4; i++) {
            aF[i] = *(const bf16x8*)&As[aOff[i]];
            bF[i] = *(const bf16x8*)&Bs[bOff[i]];
        }
        #pragma unroll
        for (int i = 0; i < 4; i++)
        #pragma unroll
        for (int j = 0; j < 4; j++)
            acc[i][j] = __builtin_amdgcn_mfma_f32_16x16x32_bf16(aF[i], bF[j], acc[i][j], 0, 0, 0);
        va0 = na0; va1 = na1; vb0 = nb0; vb1 = nb1;
    }
    const float* bb = e_b1 + (long)e * HIDC;
    #pragma unroll
    for (int i = 0; i < 4; i++)
    #pragma unroll
    for (int r = 0; r < 4; r++) {
        int tok = rowsS[wm + i * 16 + fq * 4 + r];
        if (tok < 0) continue;
        #pragma unroll
        for (int j = 0; j < 4; j++) {
            int col = bn + wn + j * 16 + fr;
            float v = acc[i][j][r] + bb[col];
            v = 0.5f * v * (1.f + erff(v * 0.70710678f));
            hid_b[(long)tok * HIDC + col] = __float2bfloat16(v);
        }
    }
}

// ---- MoE grouped MFMA GEMM2 (plain bf16, prefetched): x_flat += hid·w2 + b2 ----
__global__ __launch_bounds__(256) void moe_mfma2_kernel(
    const bf16* __restrict__ hid_b, const bf16* __restrict__ e2T, const float* __restrict__ e_b2,
    const int* __restrict__ table, const int* __restrict__ ntiles, const int* __restrict__ perm,
    float* __restrict__ x_flat) {
    if (blockIdx.y >= ntiles[0]) return;
    int e = table[2 * blockIdx.y], row0 = table[2 * blockIdx.y + 1];
    int bn = blockIdx.x * 128;
    __shared__ short As[128 * 32];
    __shared__ short Bs[128 * 32];
    __shared__ int rowsS[128];
    int t = threadIdx.x, lane = t & 63, w = t >> 6;
    if (t < 128) rowsS[t] = perm[row0 + t];
    __syncthreads();
    int wm = (w >> 1) * 64, wn = (w & 1) * 64;
    int p0 = t, p1 = t + 256;
    int r0 = p0 >> 2, k0s = (p0 & 3) ^ ((r0 >> 1) & 3);
    int r1 = p1 >> 2, k1s = (p1 & 3) ^ ((r1 >> 1) & 3);
    int tok0 = rowsS[r0]; if (tok0 < 0) tok0 = 0;
    int tok1 = rowsS[r1]; if (tok1 < 0) tok1 = 0;
    const short* Hs = (const short*)hid_b;
    const short* Ws = (const short*)(e2T + (long)e * DIMC * HIDC);
    const short* a0 = Hs + (long)tok0 * HIDC + k0s * 8;
    const short* a1 = Hs + (long)tok1 * HIDC + k1s * 8;
    const short* b0 = Ws + (long)(bn + r0) * HIDC + k0s * 8;
    const short* b1 = Ws + (long)(bn + r1) * HIDC + k1s * 8;
    int fr = lane & 15, fq = lane >> 4;
    int aOff[4], bOff[4];
    #pragma unroll
    for (int i = 0; i < 4; i++) {
        int row = wm + i * 16 + fr;
        aOff[i] = row * 32 + ((fq ^ ((row >> 1) & 3)) * 8);
        int col = wn + i * 16 + fr;
        bOff[i] = col * 32 + ((fq ^ ((col >> 1) & 3)) * 8);
    }
    f32x4 acc[4][4] = {};
    bf16x8 va0 = *(const bf16x8*)(a0);
    bf16x8 va1 = *(const bf16x8*)(a1);
    bf16x8 vb0 = *(const bf16x8*)(b0);
    bf16x8 vb1 = *(const bf16x8*)(b1);
    for (int kk = 0; kk < HIDC; kk += 32) {
        __syncthreads();
        *(bf16x8*)&As[p0 * 8] = va0;  *(bf16x8*)&As[p1 * 8] = va1;
        *(bf16x8*)&Bs[p0 * 8] = vb0;  *(bf16x8*)&Bs[p1 * 8] = vb1;
        int kn = (kk + 32 < HIDC) ? kk + 32 : kk;
        bf16x8 na0 = *(const bf16x8*)(a0 + kn);
        bf16x8 na1 = *(const bf16x8*)(a1 + kn);
        bf16x8 nb0 = *(const bf16x8*)(b0 + kn);
        bf16x8 nb1 = *(const bf16x8*)(b1 + kn);
        __syncthreads();
        bf16x8 aF[4], bF[4];
        #pragma unroll
        for (int i = 0; i < 4; i++) {
            aF[i] = *(const bf16x8*)&As[aOff[i]];
            bF[i] = *(const bf16x8*)&Bs[bOff[i]];
        }
        #pragma unroll
        for (int i = 0; i < 4; i++)
        #pragma unroll
        for (int j = 0; j < 4; j++)
            acc[i][j] = __builtin_amdgcn_mfma_f32_16x16x32_bf16(aF[i], bF[j], acc[i][j], 0, 0, 0);
        va0 = na0; va1 = na1; vb0 = nb0; vb1 = nb1;
    }
    const float* bb = e_b2 + (long)e * DIMC;
    #pragma unroll
    for (int i = 0; i < 4; i++)
    #pragma unroll
    for (int r = 0; r < 4; r++) {
        int tok = rowsS[wm + i * 16 + fq * 4 + r];
        if (tok < 0) continue;
        #pragma unroll
        for (int j = 0; j < 4; j++) {
            int col = bn + wn + j * 16 + fr;
            x_flat[(long)tok * DIMC + col] += acc[i][j][r] + bb[col];
        }
    }
}

// ---------------- LayerNorm: optional fp32 + bf16 hi/lo outputs ----------------
__global__ void ln_kernel(const float* __restrict__ x, const float* __restrict__ g,
                          const float* __restrict__ b, float* __restrict__ y,
                          bf16* __restrict__ yh, bf16* __restrict__ yl) {
    int tok = blockIdx.x;
    int t = threadIdx.x;
    const float* xr = x + (long)tok * DIMC;
    float v0 = xr[t], v1 = xr[t + 256];
    __shared__ float red[256];
    red[t] = v0 + v1; __syncthreads();
    for (int s = 128; s > 0; s >>= 1) { if (t < s) red[t] += red[t + s]; __syncthreads(); }
    float mu = red[0] * (1.f / DIMC);
    __syncthreads();
    float d0 = v0 - mu, d1 = v1 - mu;
    red[t] = d0 * d0 + d1 * d1; __syncthreads();
    for (int s = 128; s > 0; s >>= 1) { if (t < s) red[t] += red[t + s]; __syncthreads(); }
    float rs = rsqrtf(red[0] * (1.f / DIMC) + 1e-5f);
    float o0 = d0 * rs * g[t] + b[t];
    float o1 = d1 * rs * g[t + 256] + b[t + 256];
    if (y) { y[(long)tok * DIMC + t] = o0; y[(long)tok * DIMC + t + 256] = o1; }
    bf16 h, l;
    split2(o0, h, l); yh[(long)tok * DIMC + t] = h;       yl[(long)tok * DIMC + t] = l;
    split2(o1, h, l); yh[(long)tok * DIMC + t + 256] = h; yl[(long)tok * DIMC + t + 256] = l;
}

// ---------------- router text part ----------------
__global__ void textpart_kernel(const float* __restrict__ w, const float* __restrict__ r_text_mu,
                                const float* __restrict__ r_comb_mu, float* __restrict__ tp) {
    __shared__ float tw[4][128];
    int t = threadIdx.x;
    for (int j = 0; j < 2; j++) {
        int idx = t + j * 256; int b = idx >> 7, c = idx & 127;
        const float* wr = w + (long)b * LATC;
        float s = 0.f;
        for (int k = 0; k < LATC; k++) s += wr[k] * r_text_mu[(long)k * 128 + c];
        tw[b][c] = s;
    }
    __syncthreads();
    if (t < 32) {
        int b = t >> 3, e = t & 7;
        float s = 0.f;
        for (int c = 0; c < 128; c++) s += tw[b][c] * r_comb_mu[(long)(128 + c) * 8 + e];
        tp[t] = s;
    }
}

// ---------------- MoE meta ----------------
__global__ void moe_init_kernel(int* __restrict__ cnt, int* __restrict__ perm) {
    int g = blockIdx.x * blockDim.x + threadIdx.x;
    if (g < MAXT * 128) perm[g] = -1;
    if (g < NE) cnt[g] = 0;
}

__global__ void route_kernel(const float* __restrict__ feat, const float* __restrict__ tp,
                             const float* __restrict__ r_comb_mu, const float* __restrict__ r_temp,
                             float* __restrict__ onehot, int* __restrict__ idx, int* __restrict__ cnt) {
    int n = blockIdx.x * blockDim.x + threadIdx.x;
    if (n >= NTOK) return;
    int b = n >> 10;
    float tmp = fmaxf(r_temp[0], 0.1f);
    float invt = 1.f / tmp;
    const float* fr = feat + (long)n * 128;
    float lg[8];
    for (int e = 0; e < 8; e++) {
        float s = 0.f;
        for (int c = 0; c < 128; c++) s += fr[c] * r_comb_mu[(long)c * 8 + e];
        lg[e] = (s + tp[b * 8 + e]) * invt;
    }
    float best = lg[0]; int bi = 0;
    for (int e = 1; e < 8; e++) { if (lg[e] > best) { best = lg[e]; bi = e; } }
    for (int e = 0; e < 8; e++) onehot[(long)n * 8 + e] = (e == bi) ? 1.f : 0.f;
    idx[n] = bi;
    atomicAdd(&cnt[bi], 1);
}

__global__ void offsets_kernel(const int* __restrict__ cnt, int* __restrict__ cursor,
                               int* __restrict__ ntiles, int* __restrict__ table) {
    if (threadIdx.x != 0) return;
    int po = 0, nt = 0;
    for (int e = 0; e < NE; e++) {
        cursor[e] = po;
        int tiles = (cnt[e] + 127) >> 7;
        for (int j = 0; j < tiles; j++) { table[2 * nt] = e; table[2 * nt + 1] = po + j * 128; nt++; }
        po += tiles * 128;
    }
    ntiles[0] = nt;
}

__global__ void scatter_kernel(const int* __restrict__ idx, int* __restrict__ cursor,
                               int* __restrict__ perm) {
    int n = blockIdx.x * blockDim.x + threadIdx.x;
    if (n >= NTOK) return;
    int e = idx[n];
    int pos = atomicAdd(&cursor[e], 1);
    perm[pos] = n;
}

extern "C" void kernel_launch(void* const* d_in, const int* in_sizes, int n_in,
                              void* d_out, int out_size, void* d_ws, size_t ws_size,
                              hipStream_t stream) {
    const float* x        = (const float*)d_in[0];
    const float* w        = (const float*)d_in[1];
    const float* text     = (const float*)d_in[2];
    const float* pin_w    = (const float*)d_in[3];
    const float* pin_mw   = (const float*)d_in[4];
    const float* pin_mb   = (const float*)d_in[5];
    const float* pout_w   = (const float*)d_in[6];
    const float* pout_mw  = (const float*)d_in[7];
    const float* pout_mb  = (const float*)d_in[8];
    const float* ln1g     = (const float*)d_in[9];
    const float* ln1b     = (const float*)d_in[10];
    const float* ln2g     = (const float*)d_in[11];
    const float* ln2b     = (const float*)d_in[12];
    const float* ln3g     = (const float*)d_in[13];
    const float* ln3b     = (const float*)d_in[14];
    const float* sa_in_w  = (const float*)d_in[15];
    const float* sa_in_b  = (const float*)d_in[16];
    const float* sa_out_w = (const float*)d_in[17];
    const float* sa_out_b = (const float*)d_in[18];
    const float* ca_in_w  = (const float*)d_in[19];
    const float* ca_in_b  = (const float*)d_in[20];
    const float* ca_out_w = (const float*)d_in[21];
    const float* ca_out_b = (const float*)d_in[22];
    const float* r_feat   = (const float*)d_in[23];
    const float* r_text   = (const float*)d_in[24];
    const float* r_comb   = (const float*)d_in[25];
    const float* r_temp   = (const float*)d_in[26];
    const float* e_w1     = (const float*)d_in[27];
    const float* e_b1     = (const float*)d_in[28];
    const float* e_w2     = (const float*)d_in[29];
    const float* e_b2     = (const float*)d_in[30];

    float* out    = (float*)d_out;               // [B, DIM, H, W]
    float* onehot = out + (long)BB * DIMC * HWX; // [4096, 8]

    // ---------------- workspace: fp32 pool ----------------
    float* f32p = (float*)d_ws;
    float* style_in  = f32p;                 // 2048
    float* style_out = f32p + 2048;          // 2048
    float* tp        = f32p + 4096;          // 32
    int*   idx       = (int*)(f32p + 4128);  // 4096
    int*   cnt       = (int*)(f32p + 8224);  // 8
    int*   cursor    = (int*)(f32p + 8232);  // 8
    int*   ntiles    = (int*)(f32p + 8240);  // 8
    int*   table     = (int*)(f32p + 8248);  // 128
    int*   perm      = (int*)(f32p + 8376);  // 5120 -> ends 13496
    float* x_flat    = f32p + 13496;         // 2097152
    float* xn        = x_flat + 2097152;     // 2097152 (dead fp32; kept for layout stability)
    float* qkv       = xn + 2097152;         // 6291456 (SA q split / CA q split home)
    float* spill     = qkv + 6291456;        // 2097152 (e2T tail)

    // ---------------- bf16 pool (phase-aliased) ----------------
    bf16* bp = (bf16*)(f32p + 12596408);
    bf16* R1 = bp;                           // 6291456 elems, 3 phases
    bf16* xT_h  = R1;
    bf16* xT_l  = R1 + 2097152;
    bf16* wtA_h = R1 + 4194304;
    bf16* wtA_l = R1 + 5242880;
    bf16* obuf_h = R1;
    bf16* obuf_l = R1 + 2097152;
    bf16* kvt_h  = R1 + 4194304;                       // [308][1024] split
    bf16* kvt_l  = kvt_h + 315392;
    float* feat  = (float*)(kvt_l + 315392);           // 524288 fp32
    bf16* wtC_h = R1;
    bf16* wtC_l = R1 + 1048576;
    bf16* xn_h = R1 + 6291456;               // 2097152
    bf16* xn_l = xn_h + 2097152;             // 2097152
    bf16* WB   = xn_l + 2097152;             // 8388608: weights (early) / hid_b (late)
    bf16* text_h   = WB;
    bf16* text_l   = text_h + 157696;
    bf16* sawin_h  = text_l + 157696;
    bf16* sawin_l  = sawin_h + 786432;
    bf16* sawout_h = sawin_l + 786432;
    bf16* sawout_l = sawout_h + 262144;
    bf16* caw_h    = sawout_l + 262144;
    bf16* caw_l    = caw_h + 786432;
    bf16* cawout_h = caw_l + 786432;
    bf16* cawout_l = cawout_h + 262144;
    bf16* rfT_h    = cawout_l + 262144;      // [128][512] split r_feat^T (dead before hid_b use)
    bf16* rfT_l    = rfT_h + 65536;
    bf16* hid_b    = WB;                     // overlays weights after ca_out
    bf16* e1T = (bf16*)qkv;                  // [8][2048][512] in qkv+spill
    bf16* e2T = e1T + 8388608;
    bf16* xfl_h = xn_h;
    bf16* xfl_l = xn_l;
    bf16* q_h = (bf16*)qkv;                  // [4096][1536]
    bf16* q_l = q_h + 6291456;
    bf16* ca_qh = (bf16*)qkv;                // [4096][512]
    bf16* ca_ql = ca_qh + 2097152;
    (void)ws_size; (void)spill; (void)xn;

    auto mg = [&](const bf16* Ah, const bf16* Al, const bf16* Bh, const bf16* Bl,
                  const float* bias, const float* resid, float* C, bf16* Oh, bf16* Ol,
                  int M, int N, int K, long ab, long bb, long cb, int csm, int csn, int nb) {
        dim3 g(N / 128, (M + 127) / 128, nb);
        hipLaunchKernelGGL(mgemm_kernel, g, dim3(256), 0, stream,
                           Ah, Al, Bh, Bl, bias, resid, C, Oh, Ol, M, N, K, ab, bb, cb, csm, csn);
    };
    auto cvt2 = [&](const float* in, bf16* h2, bf16* l2, int n) {
        hipLaunchKernelGGL(cvt2_kernel, dim3((n / 4 + 255) / 256), dim3(256), 0, stream, in, h2, l2, n);
    };

    // ---- input conversions (hi/lo) ----
    cvt2(sa_in_w, sawin_h, sawin_l, 1536 * 512);
    cvt2(sa_out_w, sawout_h, sawout_l, 512 * 512);
    cvt2(ca_in_w, caw_h, caw_l, 1536 * 512);
    cvt2(ca_out_w, cawout_h, cawout_l, 512 * 512);
    cvt2(text, text_h, text_l, BB * TXT * 512);
    hipLaunchKernelGGL(trcvt2_kernel, dim3(32, 16, BB), dim3(256), 0, stream,
                       x, xT_h, xT_l, 512, 1024, (long)512 * 1024, (long)1024 * 512);
    // r_feat [512][128] -> rfT [128][512] split
    hipLaunchKernelGGL(trcvt2_kernel, dim3(4, 16, 1), dim3(256), 0, stream,
                       r_feat, rfT_h, rfT_l, 512, 128, 0L, 0L);

    // ---- modconv in ----
    hipLaunchKernelGGL(style_kernel, dim3(8), dim3(256), 0, stream, w, pin_mw, pin_mb, style_in);
    hipLaunchKernelGGL(wtmod_kernel, dim3(BB * DIMC), dim3(256), 0, stream, pin_w, style_in, wtA_h, wtA_l);
    mg(xT_h, xT_l, wtA_h, wtA_l, nullptr, nullptr, x_flat, nullptr, nullptr,
       HWX, DIMC, DIMC, (long)HWX * DIMC, (long)DIMC * DIMC, (long)HWX * DIMC, DIMC, 1, BB);

    // ---- LN1 + self-attention (split MFMA) ----
    hipLaunchKernelGGL(ln_kernel, dim3(NTOK), dim3(256), 0, stream, x_flat, ln1g, ln1b,
                       (float*)nullptr, xn_h, xn_l);
    mg(xn_h, xn_l, sawin_h, sawin_l, sa_in_b, nullptr, nullptr, q_h, q_l,
       NTOK, 1536, 512, 0, 0, 0, 1536, 1, 1);
    hipLaunchKernelGGL(sa_mfma_kernel, dim3(16, HEADS, BB), dim3(256), 0, stream,
                       q_h, q_l, obuf_h, obuf_l);
    mg(obuf_h, obuf_l, sawout_h, sawout_l, sa_out_b, x_flat, x_flat, nullptr, nullptr,
       NTOK, 512, 512, 0, 0, 0, 512, 1, 1);

    // ---- LN2 + cross-attention (split MFMA) ----
    hipLaunchKernelGGL(ln_kernel, dim3(NTOK), dim3(256), 0, stream, x_flat, ln2g, ln2b,
                       (float*)nullptr, xn_h, xn_l);
    mg(xn_h, xn_l, caw_h, caw_l, ca_in_b, nullptr, nullptr, ca_qh, ca_ql,
       NTOK, 512, 512, 0, 0, 0, 512, 1, 1);
    mg(text_h, text_l, caw_h + 512 * 512, caw_l + 512 * 512, ca_in_b + 512, nullptr, nullptr,
       kvt_h, kvt_l, BB * TXT, 1024, 512, 0, 0, 0, 1024, 1, 1);
    hipLaunchKernelGGL(ca_mfma_kernel, dim3(16, HEADS, BB), dim3(256), 0, stream,
                       ca_qh, ca_ql, kvt_h, kvt_l, obuf_h, obuf_l);
    // qkv region dead after ca_mfma -> build expert weight transposes there
    hipLaunchKernelGGL(trcvt_kernel, dim3(64, 16, NE), dim3(256), 0, stream,
                       e_w1, e1T, 512, 2048, (long)512 * 2048, (long)2048 * 512);
    hipLaunchKernelGGL(trcvt_kernel, dim3(16, 64, NE), dim3(256), 0, stream,
                       e_w2, e2T, 2048, 512, (long)2048 * 512, (long)512 * 2048);
    mg(obuf_h, obuf_l, cawout_h, cawout_l, ca_out_b, x_flat, x_flat, nullptr, nullptr,
       NTOK, 512, 512, 0, 0, 0, 512, 1, 1);

    // ---- LN3 + router (feat via split MFMA) ----
    hipLaunchKernelGGL(ln_kernel, dim3(NTOK), dim3(256), 0, stream, x_flat, ln3g, ln3b,
                       (float*)nullptr, xn_h, xn_l);
    mg(xn_h, xn_l, rfT_h, rfT_l, nullptr, nullptr, feat, nullptr, nullptr,
       NTOK, 128, 512, 0, 0, 0, 128, 1, 1);
    hipLaunchKernelGGL(textpart_kernel, dim3(1), dim3(256), 0, stream, w, r_text, r_comb, tp);
    hipLaunchKernelGGL(moe_init_kernel, dim3((MAXT * 128 + 255) / 256), dim3(256), 0, stream, cnt, perm);
    hipLaunchKernelGGL(route_kernel, dim3(16), dim3(256), 0, stream, feat, tp, r_comb, r_temp, onehot, idx, cnt);
    hipLaunchKernelGGL(offsets_kernel, dim3(1), dim3(64), 0, stream, cnt, cursor, ntiles, table);
    hipLaunchKernelGGL(scatter_kernel, dim3(16), dim3(256), 0, stream, idx, cursor, perm);

    // ---- MoE grouped MFMA GEMMs ----
    hipLaunchKernelGGL(moe_mfma1_kernel, dim3(HIDC / 128, MAXT), dim3(256), 0, stream,
                       xn_h, e1T, e_b1, table, ntiles, perm, hid_b);
    hipLaunchKernelGGL(moe_mfma2_kernel, dim3(DIMC / 128, MAXT), dim3(256), 0, stream,
                       hid_b, e2T, e_b2, table, ntiles, perm, x_flat);

    // ---- modconv out (split both sides) ----
    cvt2(x_flat, xfl_h, xfl_l, NTOK * DIMC);
    hipLaunchKernelGGL(style_kernel, dim3(8), dim3(256), 0, stream, w, pout_mw, pout_mb, style_out);
    hipLaunchKernelGGL(wtmod_kernel, dim3(BB * DIMC), dim3(256), 0, stream, pout_w, style_out, wtC_h, wtC_l);
    mg(wtC_h, wtC_l, xfl_h, xfl_l, nullptr, nullptr, out, nullptr, nullptr,
       DIMC, HWX, DIMC, (long)DIMC * DIMC, (long)HWX * DIMC, (long)DIMC * HWX, HWX, 1, BB);
}

// Round 10
// 694.755 us; speedup vs baseline: 7.9673x; 1.0096x over previous
//
#include <hip/hip_runtime.h>
#include <hip/hip_bf16.h>
#include <math.h>

#define DIMC 512
#define HEADS 8
#define HD 64
#define BB 4
#define HWX 1024
#define TXT 77
#define LATC 512
#define NE 8
#define HIDC 2048
#define NTOK 4096
#define MAXT 40

typedef __attribute__((ext_vector_type(8))) short bf16x8;
typedef __attribute__((ext_vector_type(4))) float f32x4;
typedef __hip_bfloat16 bf16;

__device__ __forceinline__ void split2(float v, bf16& h, bf16& l) {
    h = __float2bfloat16(v);
    l = __float2bfloat16(v - __bfloat162float(h));
}
__device__ __forceinline__ void split2s(float v, short& h, short& l) {
    bf16 hb, lb; split2(v, hb, lb);
    h = *(short*)&hb; l = *(short*)&lb;
}

// ---------------- style = w @ mod_w.T + mod_b ----------------
__global__ void style_kernel(const float* __restrict__ w, const float* __restrict__ mod_w,
                             const float* __restrict__ mod_b, float* __restrict__ style) {
    int t = blockIdx.x * blockDim.x + threadIdx.x;
    if (t >= BB * DIMC) return;
    int b = t / DIMC, i = t % DIMC;
    const float* wr = w + (long)b * LATC;
    const float* mr = mod_w + (long)i * LATC;
    float s = 0.f;
    #pragma unroll 8
    for (int l = 0; l < LATC; l++) s += wr[l] * mr[l];
    style[t] = s + mod_b[i];
}

// ------- wtmod[b,o,i] -> bf16 hi/lo (demodulated per-sample weight) -------
__global__ void wtmod_kernel(const float* __restrict__ weight, const float* __restrict__ style,
                             bf16* __restrict__ wh, bf16* __restrict__ wl) {
    int bo = blockIdx.x;
    int b = bo / DIMC, o = bo % DIMC;
    const float* wr = weight + (long)o * DIMC;
    const float* sr = style + (long)b * DIMC;
    int t = threadIdx.x;
    float vals[2]; float part = 0.f;
    for (int j = 0; j < 2; j++) {
        int i = t + j * 256;
        float v = wr[i] * sr[i];
        vals[j] = v; part += v * v;
    }
    __shared__ float red[256];
    red[t] = part; __syncthreads();
    for (int s = 128; s > 0; s >>= 1) { if (t < s) red[t] += red[t + s]; __syncthreads(); }
    float d = rsqrtf(red[0] + 1e-8f);
    for (int j = 0; j < 2; j++) {
        int i = t + j * 256;
        bf16 h, l; split2(vals[j] * d, h, l);
        wh[(long)bo * DIMC + i] = h; wl[(long)bo * DIMC + i] = l;
    }
}

// ---------------- fp32 -> bf16 hi/lo convert (flat) ----------------
__global__ void cvt2_kernel(const float* __restrict__ in, bf16* __restrict__ hi,
                            bf16* __restrict__ lo, int n) {
    int i = (blockIdx.x * blockDim.x + threadIdx.x) * 4;
    if (i >= n) return;
    float4 v = *(const float4*)(in + i);
    float a[4] = {v.x, v.y, v.z, v.w};
    #pragma unroll
    for (int j = 0; j < 4; j++) { bf16 h, l; split2(a[j], h, l); hi[i + j] = h; lo[i + j] = l; }
}

// ---------------- fp32 [R][C] -> bf16 [C][R] transpose hi/lo ----------------
__global__ void trcvt2_kernel(const float* __restrict__ in, bf16* __restrict__ hi,
                              bf16* __restrict__ lo, int R, int C, long in_bat, long out_bat) {
    __shared__ float tile[32][33];
    in += (long)blockIdx.z * in_bat; hi += (long)blockIdx.z * out_bat; lo += (long)blockIdx.z * out_bat;
    int c0 = blockIdx.x * 32, r0 = blockIdx.y * 32;
    int tc = threadIdx.x & 31, tr = threadIdx.x >> 5;
    #pragma unroll
    for (int i = 0; i < 4; i++) {
        int r = tr + i * 8;
        tile[r][tc] = in[(long)(r0 + r) * C + c0 + tc];
    }
    __syncthreads();
    #pragma unroll
    for (int i = 0; i < 4; i++) {
        int r = tr + i * 8;
        bf16 h, l; split2(tile[tc][r], h, l);
        hi[(long)(c0 + r) * R + r0 + tc] = h;
        lo[(long)(c0 + r) * R + r0 + tc] = l;
    }
}

// ---------------- fp32 [R][C] -> bf16 [C][R] transpose (single) ----------------
__global__ void trcvt_kernel(const float* __restrict__ in, bf16* __restrict__ out,
                             int R, int C, long in_bat, long out_bat) {
    __shared__ float tile[32][33];
    in += (long)blockIdx.z * in_bat; out += (long)blockIdx.z * out_bat;
    int c0 = blockIdx.x * 32, r0 = blockIdx.y * 32;
    int tc = threadIdx.x & 31, tr = threadIdx.x >> 5;
    #pragma unroll
    for (int i = 0; i < 4; i++) {
        int r = tr + i * 8;
        tile[r][tc] = in[(long)(r0 + r) * C + c0 + tc];
    }
    __syncthreads();
    #pragma unroll
    for (int i = 0; i < 4; i++) {
        int r = tr + i * 8;
        out[(long)(c0 + r) * R + r0 + tc] = __float2bfloat16(tile[tc][r]);
    }
}

// ---- split-precision bf16 MFMA GEMM, double-buffered LDS (1 barrier/K-step) ----
__global__ __launch_bounds__(256) void mgemm_kernel(
    const bf16* __restrict__ Ah, const bf16* __restrict__ Al,
    const bf16* __restrict__ Bh, const bf16* __restrict__ Bl,
    const float* __restrict__ bias, const float* __restrict__ resid, float* __restrict__ C,
    bf16* __restrict__ Oh, bf16* __restrict__ Ol,
    int M, int N, int K, long a_bat, long b_bat, long c_bat, int cs_m, int cs_n) {
    __shared__ short AsH[2 * 4096];
    __shared__ short AsL[2 * 4096];
    __shared__ short BsH[2 * 4096];
    __shared__ short BsL[2 * 4096];
    int bat = blockIdx.z;
    const short* AbH = (const short*)(Ah + (long)bat * a_bat);
    const short* AbL = (const short*)(Al + (long)bat * a_bat);
    const short* BbH = (const short*)(Bh + (long)bat * b_bat);
    const short* BbL = (const short*)(Bl + (long)bat * b_bat);
    float* Cb = C + (long)bat * c_bat;
    const float* Rb = resid ? resid + (long)bat * c_bat : nullptr;
    int bm = blockIdx.y * 128, bn = blockIdx.x * 128;
    int t = threadIdx.x, lane = t & 63, w = t >> 6;
    int wm = (w >> 1) * 64, wn = (w & 1) * 64;
    int p0 = t, p1 = t + 256;
    int r0 = p0 >> 2, k0s = (p0 & 3) ^ ((r0 >> 1) & 3);
    int r1 = p1 >> 2, k1s = (p1 & 3) ^ ((r1 >> 1) & 3);
    int ar0 = bm + r0; if (ar0 > M - 1) ar0 = M - 1;
    int ar1 = bm + r1; if (ar1 > M - 1) ar1 = M - 1;
    long aoff0 = (long)ar0 * K + k0s * 8, aoff1 = (long)ar1 * K + k1s * 8;
    long boff0 = (long)(bn + r0) * K + k0s * 8, boff1 = (long)(bn + r1) * K + k1s * 8;
    int fr = lane & 15, fq = lane >> 4;
    int aOff[4], bOff[4];
    #pragma unroll
    for (int i = 0; i < 4; i++) {
        int row = wm + i * 16 + fr;
        aOff[i] = row * 32 + ((fq ^ ((row >> 1) & 3)) * 8);
        int col = wn + i * 16 + fr;
        bOff[i] = col * 32 + ((fq ^ ((col >> 1) & 3)) * 8);
    }
    f32x4 acc[4][4] = {};
    // prologue loads (kk = 0)
    bf16x8 vah0 = *(const bf16x8*)(AbH + aoff0);
    bf16x8 vah1 = *(const bf16x8*)(AbH + aoff1);
    bf16x8 val0 = *(const bf16x8*)(AbL + aoff0);
    bf16x8 val1 = *(const bf16x8*)(AbL + aoff1);
    bf16x8 vbh0 = *(const bf16x8*)(BbH + boff0);
    bf16x8 vbh1 = *(const bf16x8*)(BbH + boff1);
    bf16x8 vbl0 = *(const bf16x8*)(BbL + boff0);
    bf16x8 vbl1 = *(const bf16x8*)(BbL + boff1);
    int bufo = 0;
    for (int kk = 0; kk < K; kk += 32) {
        *(bf16x8*)&AsH[bufo + p0 * 8] = vah0;  *(bf16x8*)&AsH[bufo + p1 * 8] = vah1;
        *(bf16x8*)&AsL[bufo + p0 * 8] = val0;  *(bf16x8*)&AsL[bufo + p1 * 8] = val1;
        *(bf16x8*)&BsH[bufo + p0 * 8] = vbh0;  *(bf16x8*)&BsH[bufo + p1 * 8] = vbh1;
        *(bf16x8*)&BsL[bufo + p0 * 8] = vbl0;  *(bf16x8*)&BsL[bufo + p1 * 8] = vbl1;
        int kn = (kk + 32 < K) ? kk + 32 : kk;
        bf16x8 nah0 = *(const bf16x8*)(AbH + aoff0 + kn);
        bf16x8 nah1 = *(const bf16x8*)(AbH + aoff1 + kn);
        bf16x8 nal0 = *(const bf16x8*)(AbL + aoff0 + kn);
        bf16x8 nal1 = *(const bf16x8*)(AbL + aoff1 + kn);
        bf16x8 nbh0 = *(const bf16x8*)(BbH + boff0 + kn);
        bf16x8 nbh1 = *(const bf16x8*)(BbH + boff1 + kn);
        bf16x8 nbl0 = *(const bf16x8*)(BbL + boff0 + kn);
        bf16x8 nbl1 = *(const bf16x8*)(BbL + boff1 + kn);
        __syncthreads();
        bf16x8 aH[4], aL[4], bH[4], bL[4];
        #pragma unroll
        for (int i = 0; i < 4; i++) {
            aH[i] = *(const bf16x8*)&AsH[bufo + aOff[i]];
            aL[i] = *(const bf16x8*)&AsL[bufo + aOff[i]];
            bH[i] = *(const bf16x8*)&BsH[bufo + bOff[i]];
            bL[i] = *(const bf16x8*)&BsL[bufo + bOff[i]];
        }
        #pragma unroll
        for (int i = 0; i < 4; i++)
        #pragma unroll
        for (int j = 0; j < 4; j++) {
            acc[i][j] = __builtin_amdgcn_mfma_f32_16x16x32_bf16(aH[i], bH[j], acc[i][j], 0, 0, 0);
            acc[i][j] = __builtin_amdgcn_mfma_f32_16x16x32_bf16(aH[i], bL[j], acc[i][j], 0, 0, 0);
            acc[i][j] = __builtin_amdgcn_mfma_f32_16x16x32_bf16(aL[i], bH[j], acc[i][j], 0, 0, 0);
        }
        vah0 = nah0; vah1 = nah1; val0 = nal0; val1 = nal1;
        vbh0 = nbh0; vbh1 = nbh1; vbl0 = nbl0; vbl1 = nbl1;
        bufo ^= 4096;
    }
    #pragma unroll
    for (int i = 0; i < 4; i++)
    #pragma unroll
    for (int j = 0; j < 4; j++)
    #pragma unroll
    for (int r = 0; r < 4; r++) {
        int row = bm + wm + i * 16 + fq * 4 + r;
        int col = bn + wn + j * 16 + fr;
        if (row < M) {
            long off = (long)row * cs_m + (long)col * cs_n;
            float v = acc[i][j][r];
            if (bias) v += bias[col];
            if (Oh) {
                bf16 hh, ll; split2(v, hh, ll);
                Oh[off] = hh; Ol[off] = ll;
            } else {
                if (Rb) v += Rb[off];
                Cb[off] = v;
            }
        }
    }
}

// ---- split-precision MFMA flash SA: dbuf K/V (1 barrier/kt) + per-wave P waitcnt ----
__global__ __launch_bounds__(256) void sa_mfma_kernel(
    const bf16* __restrict__ qh, const bf16* __restrict__ ql,
    bf16* __restrict__ oh, bf16* __restrict__ ol) {
    int qt = blockIdx.x, h = blockIdx.y, b = blockIdx.z;
    __shared__ short KsH[2 * 4096], KsL[2 * 4096];   // [kv][d], swz: col ^ ((kv&7)<<3)
    __shared__ short VtH[2 * 4096], VtL[2 * 4096];   // [d][kv], swz: col ^ (((d>>3)&7)<<3)
    __shared__ short PHs[4][1024], PLs[4][1024];     // per-wave P (intra-wave only)
    int t = threadIdx.x, lane = t & 63, w = t >> 6;
    int fr = lane & 15, fq = lane >> 4;
    const short* QH = (const short*)qh;
    const short* QL = (const short*)ql;
    long qrow = (long)(b * 1024 + qt * 64 + w * 16 + fr) * 1536 + h * 64;
    bf16x8 Qh2[2], Ql2[2];
    Qh2[0] = *(const bf16x8*)(QH + qrow + fq * 8);
    Qh2[1] = *(const bf16x8*)(QH + qrow + 32 + fq * 8);
    Ql2[0] = *(const bf16x8*)(QL + qrow + fq * 8);
    Ql2[1] = *(const bf16x8*)(QL + qrow + 32 + fq * 8);
    float m_i[4], l_i[4];
    f32x4 o_acc[4] = {};
    #pragma unroll
    for (int i = 0; i < 4; i++) { m_i[i] = -1e30f; l_i[i] = 0.f; }
    int c0 = t, c1 = t + 256;
    int r0 = c0 >> 3, g0 = c0 & 7;
    int r1 = c1 >> 3, g1 = c1 & 7;
    int kd0 = r0 * 64 + ((g0 * 8) ^ ((r0 & 7) << 3));
    int kd1 = r1 * 64 + ((g1 * 8) ^ ((r1 & 7) << 3));
    long kb = (long)(b * 1024) * 1536 + 512 + h * 64;
    long vb = kb + 512;
    long lo0 = (long)r0 * 1536 + g0 * 8, lo1 = (long)r1 * 1536 + g1 * 8;
    short* ph = PHs[w]; short* pl = PLs[w];
    // prologue loads (kt = 0)
    bf16x8 kh0 = *(const bf16x8*)(QH + kb + lo0);
    bf16x8 kh1 = *(const bf16x8*)(QH + kb + lo1);
    bf16x8 kl0 = *(const bf16x8*)(QL + kb + lo0);
    bf16x8 kl1 = *(const bf16x8*)(QL + kb + lo1);
    bf16x8 vh0 = *(const bf16x8*)(QH + vb + lo0);
    bf16x8 vh1 = *(const bf16x8*)(QH + vb + lo1);
    bf16x8 vl0 = *(const bf16x8*)(QL + vb + lo0);
    bf16x8 vl1 = *(const bf16x8*)(QL + vb + lo1);
    int bufo = 0;
    for (int kt = 0; kt < 16; kt++) {
        // stage current tile into buf[bufo]
        *(bf16x8*)&KsH[bufo + kd0] = kh0;  *(bf16x8*)&KsH[bufo + kd1] = kh1;
        *(bf16x8*)&KsL[bufo + kd0] = kl0;  *(bf16x8*)&KsL[bufo + kd1] = kl1;
        #pragma unroll
        for (int j = 0; j < 8; j++) {
            int d0 = g0 * 8 + j;
            int i0 = bufo + d0 * 64 + (r0 ^ (((d0 >> 3) & 7) << 3));
            VtH[i0] = ((short*)&vh0)[j];  VtL[i0] = ((short*)&vl0)[j];
            int d1 = g1 * 8 + j;
            int i1 = bufo + d1 * 64 + (r1 ^ (((d1 >> 3) & 7) << 3));
            VtH[i1] = ((short*)&vh1)[j];  VtL[i1] = ((short*)&vl1)[j];
        }
        // prefetch next KV tile (clamped on last iter)
        int ktn = (kt + 1 < 16) ? kt + 1 : kt;
        long ko = kb + (long)(ktn * 64) * 1536;
        long vo = vb + (long)(ktn * 64) * 1536;
        bf16x8 nkh0 = *(const bf16x8*)(QH + ko + lo0);
        bf16x8 nkh1 = *(const bf16x8*)(QH + ko + lo1);
        bf16x8 nkl0 = *(const bf16x8*)(QL + ko + lo0);
        bf16x8 nkl1 = *(const bf16x8*)(QL + ko + lo1);
        bf16x8 nvh0 = *(const bf16x8*)(QH + vo + lo0);
        bf16x8 nvh1 = *(const bf16x8*)(QH + vo + lo1);
        bf16x8 nvl0 = *(const bf16x8*)(QL + vo + lo0);
        bf16x8 nvl1 = *(const bf16x8*)(QL + vo + lo1);
        __syncthreads();          // ONLY block barrier per kt: buf[bufo] staged
        __builtin_amdgcn_s_setprio(1);
        f32x4 s[4] = {};
        #pragma unroll
        for (int cf = 0; cf < 4; cf++) {
            int kvrow = cf * 16 + fr;
            #pragma unroll
            for (int kf = 0; kf < 2; kf++) {
                int idx = bufo + kvrow * 64 + ((kf * 32 + fq * 8) ^ ((kvrow & 7) << 3));
                bf16x8 Bh2 = *(const bf16x8*)&KsH[idx];
                bf16x8 Bl2 = *(const bf16x8*)&KsL[idx];
                s[cf] = __builtin_amdgcn_mfma_f32_16x16x32_bf16(Qh2[kf], Bh2, s[cf], 0, 0, 0);
                s[cf] = __builtin_amdgcn_mfma_f32_16x16x32_bf16(Qh2[kf], Bl2, s[cf], 0, 0, 0);
                s[cf] = __builtin_amdgcn_mfma_f32_16x16x32_bf16(Ql2[kf], Bh2, s[cf], 0, 0, 0);
            }
        }
        __builtin_amdgcn_s_setprio(0);
        #pragma unroll
        for (int cf = 0; cf < 4; cf++)
        #pragma unroll
        for (int reg = 0; reg < 4; reg++) s[cf][reg] *= 0.125f;
        float sc_[4];
        #pragma unroll
        for (int reg = 0; reg < 4; reg++) {
            float mx = fmaxf(fmaxf(s[0][reg], s[1][reg]), fmaxf(s[2][reg], s[3][reg]));
            mx = fmaxf(mx, __shfl_xor(mx, 1));
            mx = fmaxf(mx, __shfl_xor(mx, 2));
            mx = fmaxf(mx, __shfl_xor(mx, 4));
            mx = fmaxf(mx, __shfl_xor(mx, 8));
            float mn = fmaxf(m_i[reg], mx);
            sc_[reg] = __expf(m_i[reg] - mn);
            m_i[reg] = mn;
            float rs = 0.f;
            #pragma unroll
            for (int cf = 0; cf < 4; cf++) { s[cf][reg] = __expf(s[cf][reg] - mn); rs += s[cf][reg]; }
            rs += __shfl_xor(rs, 1);
            rs += __shfl_xor(rs, 2);
            rs += __shfl_xor(rs, 4);
            rs += __shfl_xor(rs, 8);
            l_i[reg] = l_i[reg] * sc_[reg] + rs;
        }
        #pragma unroll
        for (int cf = 0; cf < 4; cf++)
        #pragma unroll
        for (int reg = 0; reg < 4; reg++) o_acc[cf][reg] *= sc_[reg];
        #pragma unroll
        for (int cf = 0; cf < 4; cf++)
        #pragma unroll
        for (int reg = 0; reg < 4; reg++) {
            int q = fq * 4 + reg, kv = cf * 16 + fr;
            int idx = q * 64 + (kv ^ ((q & 7) << 3));
            split2s(s[cf][reg], ph[idx], pl[idx]);
        }
        // P is per-wave LDS: intra-wave ordering only (no block barrier needed)
        asm volatile("s_waitcnt lgkmcnt(0)" ::: "memory");
        __builtin_amdgcn_sched_barrier(0);
        __builtin_amdgcn_s_setprio(1);
        bf16x8 Pf_h[2], Pf_l[2];
        #pragma unroll
        for (int kf = 0; kf < 2; kf++) {
            int idx = fr * 64 + ((kf * 32 + fq * 8) ^ ((fr & 7) << 3));
            Pf_h[kf] = *(const bf16x8*)&ph[idx];
            Pf_l[kf] = *(const bf16x8*)&pl[idx];
        }
        #pragma unroll
        for (int cf = 0; cf < 4; cf++) {
            int d = cf * 16 + fr;
            #pragma unroll
            for (int kf = 0; kf < 2; kf++) {
                int idx = bufo + d * 64 + ((kf * 32 + fq * 8) ^ (((d >> 3) & 7) << 3));
                bf16x8 Vh2 = *(const bf16x8*)&VtH[idx];
                bf16x8 Vl2 = *(const bf16x8*)&VtL[idx];
                o_acc[cf] = __builtin_amdgcn_mfma_f32_16x16x32_bf16(Pf_h[kf], Vh2, o_acc[cf], 0, 0, 0);
                o_acc[cf] = __builtin_amdgcn_mfma_f32_16x16x32_bf16(Pf_h[kf], Vl2, o_acc[cf], 0, 0, 0);
                o_acc[cf] = __builtin_amdgcn_mfma_f32_16x16x32_bf16(Pf_l[kf], Vh2, o_acc[cf], 0, 0, 0);
            }
        }
        __builtin_amdgcn_s_setprio(0);
        kh0 = nkh0; kh1 = nkh1; kl0 = nkl0; kl1 = nkl1;
        vh0 = nvh0; vh1 = nvh1; vl0 = nvl0; vl1 = nvl1;
        bufo ^= 4096;
    }
    #pragma unroll
    for (int reg = 0; reg < 4; reg++) {
        float inv = 1.f / l_i[reg];
        long m = (long)(b * 1024 + qt * 64 + w * 16 + fq * 4 + reg);
        #pragma unroll
        for (int cf = 0; cf < 4; cf++) {
            float v = o_acc[cf][reg] * inv;
            bf16 hh, ll; split2(v, hh, ll);
            long off = m * DIMC + h * 64 + cf * 16 + fr;
            oh[off] = hh; ol[off] = ll;
        }
    }
}

// ---- split-precision MFMA cross-attention: 77 keys padded to 96, single tile ----
__global__ __launch_bounds__(256) void ca_mfma_kernel(
    const bf16* __restrict__ qh, const bf16* __restrict__ ql,
    const bf16* __restrict__ kvh, const bf16* __restrict__ kvl,
    bf16* __restrict__ oh, bf16* __restrict__ ol) {
    int qt = blockIdx.x, h = blockIdx.y, b = blockIdx.z;
    __shared__ short UH[8192], UL[8192];
    __shared__ short PHs[4][2048], PLs[4][2048];
    int t = threadIdx.x, lane = t & 63, w = t >> 6;
    int fr = lane & 15, fq = lane >> 4;
    const short* QH = (const short*)qh;
    const short* QL = (const short*)ql;
    const short* KVH = (const short*)kvh;
    const short* KVL = (const short*)kvl;
    long qrow = (long)(b * 1024 + qt * 64 + w * 16 + fr) * DIMC + h * 64;
    bf16x8 Qh2[2], Ql2[2];
    Qh2[0] = *(const bf16x8*)(QH + qrow + fq * 8);
    Qh2[1] = *(const bf16x8*)(QH + qrow + 32 + fq * 8);
    Ql2[0] = *(const bf16x8*)(QL + qrow + fq * 8);
    Ql2[1] = *(const bf16x8*)(QL + qrow + 32 + fq * 8);
    for (int c = t; c < 768; c += 256) {
        int r = c >> 3, g = c & 7;
        int idx = r * 64 + ((g * 8) ^ ((r & 7) << 3));
        bf16x8 vh = {}, vl = {};
        if (r < 77) {
            long src = (long)(b * 77 + r) * 1024 + h * 64 + g * 8;
            vh = *(const bf16x8*)(KVH + src);
            vl = *(const bf16x8*)(KVL + src);
        }
        *(bf16x8*)&UH[idx] = vh;
        *(bf16x8*)&UL[idx] = vl;
    }
    __syncthreads();
    f32x4 s[5] = {};
    #pragma unroll
    for (int cf = 0; cf < 5; cf++) {
        int kvrow = cf * 16 + fr;
        #pragma unroll
        for (int kf = 0; kf < 2; kf++) {
            int idx = kvrow * 64 + ((kf * 32 + fq * 8) ^ ((kvrow & 7) << 3));
            bf16x8 Bh2 = *(const bf16x8*)&UH[idx];
            bf16x8 Bl2 = *(const bf16x8*)&UL[idx];
            s[cf] = __builtin_amdgcn_mfma_f32_16x16x32_bf16(Qh2[kf], Bh2, s[cf], 0, 0, 0);
            s[cf] = __builtin_amdgcn_mfma_f32_16x16x32_bf16(Qh2[kf], Bl2, s[cf], 0, 0, 0);
            s[cf] = __builtin_amdgcn_mfma_f32_16x16x32_bf16(Ql2[kf], Bh2, s[cf], 0, 0, 0);
        }
    }
    #pragma unroll
    for (int cf = 0; cf < 5; cf++) {
        int kv = cf * 16 + fr;
        #pragma unroll
        for (int reg = 0; reg < 4; reg++)
            s[cf][reg] = (kv < 77) ? s[cf][reg] * 0.125f : -1e30f;
    }
    float inv[4];
    #pragma unroll
    for (int reg = 0; reg < 4; reg++) {
        float mx = s[0][reg];
        #pragma unroll
        for (int cf = 1; cf < 5; cf++) mx = fmaxf(mx, s[cf][reg]);
        mx = fmaxf(mx, __shfl_xor(mx, 1));
        mx = fmaxf(mx, __shfl_xor(mx, 2));
        mx = fmaxf(mx, __shfl_xor(mx, 4));
        mx = fmaxf(mx, __shfl_xor(mx, 8));
        float rs = 0.f;
        #pragma unroll
        for (int cf = 0; cf < 5; cf++) { s[cf][reg] = __expf(s[cf][reg] - mx); rs += s[cf][reg]; }
        rs += __shfl_xor(rs, 1);
        rs += __shfl_xor(rs, 2);
        rs += __shfl_xor(rs, 4);
        rs += __shfl_xor(rs, 8);
        inv[reg] = 1.f / rs;
    }
    short* ph = PHs[w]; short* pl = PLs[w];
    #pragma unroll
    for (int cf = 0; cf < 6; cf++)
    #pragma unroll
    for (int reg = 0; reg < 4; reg++) {
        int q = fq * 4 + reg, kv = cf * 16 + fr;
        int idx = q * 128 + (kv ^ ((q & 7) << 3));
        float pv = (cf < 5) ? s[cf][reg] * inv[reg] : 0.f;
        split2s(pv, ph[idx], pl[idx]);
    }
    __syncthreads();
    for (int c = t; c < 768; c += 256) {
        int r = c >> 3, g = c & 7;
        bf16x8 vh = {}, vl = {};
        if (r < 77) {
            long src = (long)(b * 77 + r) * 1024 + 512 + h * 64 + g * 8;
            vh = *(const bf16x8*)(KVH + src);
            vl = *(const bf16x8*)(KVL + src);
        }
        #pragma unroll
        for (int j = 0; j < 8; j++) {
            int d = g * 8 + j;
            int idx = d * 128 + (r ^ (((d >> 3) & 7) << 3));
            UH[idx] = ((short*)&vh)[j];
            UL[idx] = ((short*)&vl)[j];
        }
    }
    __syncthreads();
    f32x4 o_acc[4] = {};
    bf16x8 Pf_h[3], Pf_l[3];
    #pragma unroll
    for (int kf = 0; kf < 3; kf++) {
        int idx = fr * 128 + ((kf * 32 + fq * 8) ^ ((fr & 7) << 3));
        Pf_h[kf] = *(const bf16x8*)&ph[idx];
        Pf_l[kf] = *(const bf16x8*)&pl[idx];
    }
    #pragma unroll
    for (int cf = 0; cf < 4; cf++) {
        int d = cf * 16 + fr;
        #pragma unroll
        for (int kf = 0; kf < 3; kf++) {
            int idx = d * 128 + ((kf * 32 + fq * 8) ^ (((d >> 3) & 7) << 3));
            bf16x8 Vh2 = *(const bf16x8*)&UH[idx];
            bf16x8 Vl2 = *(const bf16x8*)&UL[idx];
            o_acc[cf] = __builtin_amdgcn_mfma_f32_16x16x32_bf16(Pf_h[kf], Vh2, o_acc[cf], 0, 0, 0);
            o_acc[cf] = __builtin_amdgcn_mfma_f32_16x16x32_bf16(Pf_h[kf], Vl2, o_acc[cf], 0, 0, 0);
            o_acc[cf] = __builtin_amdgcn_mfma_f32_16x16x32_bf16(Pf_l[kf], Vh2, o_acc[cf], 0, 0, 0);
        }
    }
    #pragma unroll
    for (int reg = 0; reg < 4; reg++) {
        long m = (long)(b * 1024 + qt * 64 + w * 16 + fq * 4 + reg);
        #pragma unroll
        for (int cf = 0; cf < 4; cf++) {
            bf16 hh, ll; split2(o_acc[cf][reg], hh, ll);
            long off = m * DIMC + h * 64 + cf * 16 + fr;
            oh[off] = hh; ol[off] = ll;
        }
    }
}

// ---- MoE grouped MFMA GEMM1 (plain bf16, dbuf): hid = gelu(xn·w1 + b1) ----
__global__ __launch_bounds__(256) void moe_mfma1_kernel(
    const bf16* __restrict__ xn_b, const bf16* __restrict__ e1T, const float* __restrict__ e_b1,
    const int* __restrict__ table, const int* __restrict__ ntiles, const int* __restrict__ perm,
    bf16* __restrict__ hid_b) {
    if (blockIdx.y >= ntiles[0]) return;
    int e = table[2 * blockIdx.y], row0 = table[2 * blockIdx.y + 1];
    int bn = blockIdx.x * 128;
    __shared__ short As[2 * 4096];
    __shared__ short Bs[2 * 4096];
    __shared__ int rowsS[128];
    int t = threadIdx.x, lane = t & 63, w = t >> 6;
    if (t < 128) rowsS[t] = perm[row0 + t];
    __syncthreads();
    int wm = (w >> 1) * 64, wn = (w & 1) * 64;
    int p0 = t, p1 = t + 256;
    int r0 = p0 >> 2, k0s = (p0 & 3) ^ ((r0 >> 1) & 3);
    int r1 = p1 >> 2, k1s = (p1 & 3) ^ ((r1 >> 1) & 3);
    int tok0 = rowsS[r0]; if (tok0 < 0) tok0 = 0;
    int tok1 = rowsS[r1]; if (tok1 < 0) tok1 = 0;
    const short* Xs = (const short*)xn_b;
    const short* Ws = (const short*)(e1T + (long)e * HIDC * DIMC);
    const short* a0 = Xs + (long)tok0 * DIMC + k0s * 8;
    const short* a1 = Xs + (long)tok1 * DIMC + k1s * 8;
    const short* b0 = Ws + (long)(bn + r0) * DIMC + k0s * 8;
    const short* b1 = Ws + (long)(bn + r1) * DIMC + k1s * 8;
    int fr = lane & 15, fq = lane >> 4;
    int aOff[4], bOff[4];
    #pragma unroll
    for (int i = 0; i < 4; i++) {
        int row = wm + i * 16 + fr;
        aOff[i] = row * 32 + ((fq ^ ((row >> 1) & 3)) * 8);
        int col = wn + i * 16 + fr;
        bOff[i] = col * 32 + ((fq ^ ((col >> 1) & 3)) * 8);
    }
    f32x4 acc[4][4] = {};
    bf16x8 va0 = *(const bf16x8*)(a0);
    bf16x8 va1 = *(const bf16x8*)(a1);
    bf16x8 vb0 = *(const bf16x8*)(b0);
    bf16x8 vb1 = *(const bf16x8*)(b1);
    int bufo = 0;
    for (int kk = 0; kk < DIMC; kk += 32) {
        *(bf16x8*)&As[bufo + p0 * 8] = va0;  *(bf16x8*)&As[bufo + p1 * 8] = va1;
        *(bf16x8*)&Bs[bufo + p0 * 8] = vb0;  *(bf16x8*)&Bs[bufo + p1 * 8] = vb1;
        int kn = (kk + 32 < DIMC) ? kk + 32 : kk;
        bf16x8 na0 = *(const bf16x8*)(a0 + kn);
        bf16x8 na1 = *(const bf16x8*)(a1 + kn);
        bf16x8 nb0 = *(const bf16x8*)(b0 + kn);
        bf16x8 nb1 = *(const bf16x8*)(b1 + kn);
        __syncthreads();
        bf16x8 aF[4], bF[4];
        #pragma unroll
        for (int i = 0; i < 4; i++) {
            aF[i] = *(const bf16x8*)&As[bufo + aOff[i]];
            bF[i] = *(const bf16x8*)&Bs[bufo + bOff[i]];
        }
        #pragma unroll
        for (int i = 0; i < 4; i++)
        #pragma unroll
        for (int j = 0; j < 4; j++)
            acc[i][j] = __builtin_amdgcn_mfma_f32_16x16x32_bf16(aF[i], bF[j], acc[i][j], 0, 0, 0);
        va0 = na0; va1 = na1; vb0 = nb0; vb1 = nb1;
        bufo ^= 4096;
    }
    const float* bb = e_b1 + (long)e * HIDC;
    #pragma unroll
    for (int i = 0; i < 4; i++)
    #pragma unroll
    for (int r = 0; r < 4; r++) {
        int tok = rowsS[wm + i * 16 + fq * 4 + r];
        if (tok < 0) continue;
        #pragma unroll
        for (int j = 0; j < 4; j++) {
            int col = bn + wn + j * 16 + fr;
            float v = acc[i][j][r] + bb[col];
            v = 0.5f * v * (1.f + erff(v * 0.70710678f));
            hid_b[(long)tok * HIDC + col] = __float2bfloat16(v);
        }
    }
}

// ---- MoE grouped MFMA GEMM2 (plain bf16, dbuf): x_flat += hid·w2 + b2 ----
__global__ __launch_bounds__(256) void moe_mfma2_kernel(
    const bf16* __restrict__ hid_b, const bf16* __restrict__ e2T, const float* __restrict__ e_b2,
    const int* __restrict__ table, const int* __restrict__ ntiles, const int* __restrict__ perm,
    float* __restrict__ x_flat) {
    if (blockIdx.y >= ntiles[0]) return;
    int e = table[2 * blockIdx.y], row0 = table[2 * blockIdx.y + 1];
    int bn = blockIdx.x * 128;
    __shared__ short As[2 * 4096];
    __shared__ short Bs[2 * 4096];
    __shared__ int rowsS[128];
    int t = threadIdx.x, lane = t & 63, w = t >> 6;
    if (t < 128) rowsS[t] = perm[row0 + t];
    __syncthreads();
    int wm = (w >> 1) * 64, wn = (w & 1) * 64;
    int p0 = t, p1 = t + 256;
    int r0 = p0 >> 2, k0s = (p0 & 3) ^ ((r0 >> 1) & 3);
    int r1 = p1 >> 2, k1s = (p1 & 3) ^ ((r1 >> 1) & 3);
    int tok0 = rowsS[r0]; if (tok0 < 0) tok0 = 0;
    int tok1 = rowsS[r1]; if (tok1 < 0) tok1 = 0;
    const short* Hs = (const short*)hid_b;
    const short* Ws = (const short*)(e2T + (long)e * DIMC * HIDC);
    const short* a0 = Hs + (long)tok0 * HIDC + k0s * 8;
    const short* a1 = Hs + (long)tok1 * HIDC + k1s * 8;
    const short* b0 = Ws + (long)(bn + r0) * HIDC + k0s * 8;
    const short* b1 = Ws + (long)(bn + r1) * HIDC + k1s * 8;
    int fr = lane & 15, fq = lane >> 4;
    int aOff[4], bOff[4];
    #pragma unroll
    for (int i = 0; i < 4; i++) {
        int row = wm + i * 16 + fr;
        aOff[i] = row * 32 + ((fq ^ ((row >> 1) & 3)) * 8);
        int col = wn + i * 16 + fr;
        bOff[i] = col * 32 + ((fq ^ ((col >> 1) & 3)) * 8);
    }
    f32x4 acc[4][4] = {};
    bf16x8 va0 = *(const bf16x8*)(a0);
    bf16x8 va1 = *(const bf16x8*)(a1);
    bf16x8 vb0 = *(const bf16x8*)(b0);
    bf16x8 vb1 = *(const bf16x8*)(b1);
    int bufo = 0;
    for (int kk = 0; kk < HIDC; kk += 32) {
        *(bf16x8*)&As[bufo + p0 * 8] = va0;  *(bf16x8*)&As[bufo + p1 * 8] = va1;
        *(bf16x8*)&Bs[bufo + p0 * 8] = vb0;  *(bf16x8*)&Bs[bufo + p1 * 8] = vb1;
        int kn = (kk + 32 < HIDC) ? kk + 32 : kk;
        bf16x8 na0 = *(const bf16x8*)(a0 + kn);
        bf16x8 na1 = *(const bf16x8*)(a1 + kn);
        bf16x8 nb0 = *(const bf16x8*)(b0 + kn);
        bf16x8 nb1 = *(const bf16x8*)(b1 + kn);
        __syncthreads();
        bf16x8 aF[4], bF[4];
        #pragma unroll
        for (int i = 0; i < 4; i++) {
            aF[i] = *(const bf16x8*)&As[bufo + aOff[i]];
            bF[i] = *(const bf16x8*)&Bs[bufo + bOff[i]];
        }
        #pragma unroll
        for (int i = 0; i < 4; i++)
        #pragma unroll
        for (int j = 0; j < 4; j++)
            acc[i][j] = __builtin_amdgcn_mfma_f32_16x16x32_bf16(aF[i], bF[j], acc[i][j], 0, 0, 0);
        va0 = na0; va1 = na1; vb0 = nb0; vb1 = nb1;
        bufo ^= 4096;
    }
    const float* bb = e_b2 + (long)e * DIMC;
    #pragma unroll
    for (int i = 0; i < 4; i++)
    #pragma unroll
    for (int r = 0; r < 4; r++) {
        int tok = rowsS[wm + i * 16 + fq * 4 + r];
        if (tok < 0) continue;
        #pragma unroll
        for (int j = 0; j < 4; j++) {
            int col = bn + wn + j * 16 + fr;
            x_flat[(long)tok * DIMC + col] += acc[i][j][r] + bb[col];
        }
    }
}

// ---------------- LayerNorm: optional fp32 + bf16 hi/lo outputs ----------------
__global__ void ln_kernel(const float* __restrict__ x, const float* __restrict__ g,
                          const float* __restrict__ b, float* __restrict__ y,
                          bf16* __restrict__ yh, bf16* __restrict__ yl) {
    int tok = blockIdx.x;
    int t = threadIdx.x;
    const float* xr = x + (long)tok * DIMC;
    float v0 = xr[t], v1 = xr[t + 256];
    __shared__ float red[256];
    red[t] = v0 + v1; __syncthreads();
    for (int s = 128; s > 0; s >>= 1) { if (t < s) red[t] += red[t + s]; __syncthreads(); }
    float mu = red[0] * (1.f / DIMC);
    __syncthreads();
    float d0 = v0 - mu, d1 = v1 - mu;
    red[t] = d0 * d0 + d1 * d1; __syncthreads();
    for (int s = 128; s > 0; s >>= 1) { if (t < s) red[t] += red[t + s]; __syncthreads(); }
    float rs = rsqrtf(red[0] * (1.f / DIMC) + 1e-5f);
    float o0 = d0 * rs * g[t] + b[t];
    float o1 = d1 * rs * g[t + 256] + b[t + 256];
    if (y) { y[(long)tok * DIMC + t] = o0; y[(long)tok * DIMC + t + 256] = o1; }
    bf16 h, l;
    split2(o0, h, l); yh[(long)tok * DIMC + t] = h;       yl[(long)tok * DIMC + t] = l;
    split2(o1, h, l); yh[(long)tok * DIMC + t + 256] = h; yl[(long)tok * DIMC + t + 256] = l;
}

// ---------------- router text part ----------------
__global__ void textpart_kernel(const float* __restrict__ w, const float* __restrict__ r_text_mu,
                                const float* __restrict__ r_comb_mu, float* __restrict__ tp) {
    __shared__ float tw[4][128];
    int t = threadIdx.x;
    for (int j = 0; j < 2; j++) {
        int idx = t + j * 256; int b = idx >> 7, c = idx & 127;
        const float* wr = w + (long)b * LATC;
        float s = 0.f;
        for (int k = 0; k < LATC; k++) s += wr[k] * r_text_mu[(long)k * 128 + c];
        tw[b][c] = s;
    }
    __syncthreads();
    if (t < 32) {
        int b = t >> 3, e = t & 7;
        float s = 0.f;
        for (int c = 0; c < 128; c++) s += tw[b][c] * r_comb_mu[(long)(128 + c) * 8 + e];
        tp[t] = s;
    }
}

// ---------------- MoE meta ----------------
__global__ void moe_init_kernel(int* __restrict__ cnt, int* __restrict__ perm) {
    int g = blockIdx.x * blockDim.x + threadIdx.x;
    if (g < MAXT * 128) perm[g] = -1;
    if (g < NE) cnt[g] = 0;
}

__global__ void route_kernel(const float* __restrict__ feat, const float* __restrict__ tp,
                             const float* __restrict__ r_comb_mu, const float* __restrict__ r_temp,
                             float* __restrict__ onehot, int* __restrict__ idx, int* __restrict__ cnt) {
    int n = blockIdx.x * blockDim.x + threadIdx.x;
    if (n >= NTOK) return;
    int b = n >> 10;
    float tmp = fmaxf(r_temp[0], 0.1f);
    float invt = 1.f / tmp;
    const float* fr = feat + (long)n * 128;
    float lg[8];
    for (int e = 0; e < 8; e++) {
        float s = 0.f;
        for (int c = 0; c < 128; c++) s += fr[c] * r_comb_mu[(long)c * 8 + e];
        lg[e] = (s + tp[b * 8 + e]) * invt;
    }
    float best = lg[0]; int bi = 0;
    for (int e = 1; e < 8; e++) { if (lg[e] > best) { best = lg[e]; bi = e; } }
    for (int e = 0; e < 8; e++) onehot[(long)n * 8 + e] = (e == bi) ? 1.f : 0.f;
    idx[n] = bi;
    atomicAdd(&cnt[bi], 1);
}

__global__ void offsets_kernel(const int* __restrict__ cnt, int* __restrict__ cursor,
                               int* __restrict__ ntiles, int* __restrict__ table) {
    if (threadIdx.x != 0) return;
    int po = 0, nt = 0;
    for (int e = 0; e < NE; e++) {
        cursor[e] = po;
        int tiles = (cnt[e] + 127) >> 7;
        for (int j = 0; j < tiles; j++) { table[2 * nt] = e; table[2 * nt + 1] = po + j * 128; nt++; }
        po += tiles * 128;
    }
    ntiles[0] = nt;
}

__global__ void scatter_kernel(const int* __restrict__ idx, int* __restrict__ cursor,
                               int* __restrict__ perm) {
    int n = blockIdx.x * blockDim.x + threadIdx.x;
    if (n >= NTOK) return;
    int e = idx[n];
    int pos = atomicAdd(&cursor[e], 1);
    perm[pos] = n;
}

extern "C" void kernel_launch(void* const* d_in, const int* in_sizes, int n_in,
                              void* d_out, int out_size, void* d_ws, size_t ws_size,
                              hipStream_t stream) {
    const float* x        = (const float*)d_in[0];
    const float* w        = (const float*)d_in[1];
    const float* text     = (const float*)d_in[2];
    const float* pin_w    = (const float*)d_in[3];
    const float* pin_mw   = (const float*)d_in[4];
    const float* pin_mb   = (const float*)d_in[5];
    const float* pout_w   = (const float*)d_in[6];
    const float* pout_mw  = (const float*)d_in[7];
    const float* pout_mb  = (const float*)d_in[8];
    const float* ln1g     = (const float*)d_in[9];
    const float* ln1b     = (const float*)d_in[10];
    const float* ln2g     = (const float*)d_in[11];
    const float* ln2b     = (const float*)d_in[12];
    const float* ln3g     = (const float*)d_in[13];
    const float* ln3b     = (const float*)d_in[14];
    const float* sa_in_w  = (const float*)d_in[15];
    const float* sa_in_b  = (const float*)d_in[16];
    const float* sa_out_w = (const float*)d_in[17];
    const float* sa_out_b = (const float*)d_in[18];
    const float* ca_in_w  = (const float*)d_in[19];
    const float* ca_in_b  = (const float*)d_in[20];
    const float* ca_out_w = (const float*)d_in[21];
    const float* ca_out_b = (const float*)d_in[22];
    const float* r_feat   = (const float*)d_in[23];
    const float* r_text   = (const float*)d_in[24];
    const float* r_comb   = (const float*)d_in[25];
    const float* r_temp   = (const float*)d_in[26];
    const float* e_w1     = (const float*)d_in[27];
    const float* e_b1     = (const float*)d_in[28];
    const float* e_w2     = (const float*)d_in[29];
    const float* e_b2     = (const float*)d_in[30];

    float* out    = (float*)d_out;               // [B, DIM, H, W]
    float* onehot = out + (long)BB * DIMC * HWX; // [4096, 8]

    // ---------------- workspace: fp32 pool ----------------
    float* f32p = (float*)d_ws;
    float* style_in  = f32p;                 // 2048
    float* style_out = f32p + 2048;          // 2048
    float* tp        = f32p + 4096;          // 32
    int*   idx       = (int*)(f32p + 4128);  // 4096
    int*   cnt       = (int*)(f32p + 8224);  // 8
    int*   cursor    = (int*)(f32p + 8232);  // 8
    int*   ntiles    = (int*)(f32p + 8240);  // 8
    int*   table     = (int*)(f32p + 8248);  // 128
    int*   perm      = (int*)(f32p + 8376);  // 5120 -> ends 13496
    float* x_flat    = f32p + 13496;         // 2097152
    float* xn        = x_flat + 2097152;     // 2097152 (dead fp32; kept for layout stability)
    float* qkv       = xn + 2097152;         // 6291456 (SA q split / CA q split home)
    float* spill     = qkv + 6291456;        // 2097152 (e2T tail)

    // ---------------- bf16 pool (phase-aliased) ----------------
    bf16* bp = (bf16*)(f32p + 12596408);
    bf16* R1 = bp;                           // 6291456 elems, 3 phases
    bf16* xT_h  = R1;
    bf16* xT_l  = R1 + 2097152;
    bf16* wtA_h = R1 + 4194304;
    bf16* wtA_l = R1 + 5242880;
    bf16* obuf_h = R1;
    bf16* obuf_l = R1 + 2097152;
    bf16* kvt_h  = R1 + 4194304;                       // [308][1024] split
    bf16* kvt_l  = kvt_h + 315392;
    float* feat  = (float*)(kvt_l + 315392);           // 524288 fp32
    bf16* wtC_h = R1;
    bf16* wtC_l = R1 + 1048576;
    bf16* xn_h = R1 + 6291456;               // 2097152
    bf16* xn_l = xn_h + 2097152;             // 2097152
    bf16* WB   = xn_l + 2097152;             // 8388608: weights (early) / hid_b (late)
    bf16* text_h   = WB;
    bf16* text_l   = text_h + 157696;
    bf16* sawin_h  = text_l + 157696;
    bf16* sawin_l  = sawin_h + 786432;
    bf16* sawout_h = sawin_l + 786432;
    bf16* sawout_l = sawout_h + 262144;
    bf16* caw_h    = sawout_l + 262144;
    bf16* caw_l    = caw_h + 786432;
    bf16* cawout_h = caw_l + 786432;
    bf16* cawout_l = cawout_h + 262144;
    bf16* rfT_h    = cawout_l + 262144;      // [128][512] split r_feat^T
    bf16* rfT_l    = rfT_h + 65536;
    bf16* hid_b    = WB;                     // overlays weights after ca_out
    bf16* e1T = (bf16*)qkv;                  // [8][2048][512] in qkv+spill
    bf16* e2T = e1T + 8388608;
    bf16* xfl_h = xn_h;
    bf16* xfl_l = xn_l;
    bf16* q_h = (bf16*)qkv;                  // [4096][1536]
    bf16* q_l = q_h + 6291456;
    bf16* ca_qh = (bf16*)qkv;                // [4096][512]
    bf16* ca_ql = ca_qh + 2097152;
    (void)ws_size; (void)spill; (void)xn;

    auto mg = [&](const bf16* Ah, const bf16* Al, const bf16* Bh, const bf16* Bl,
                  const float* bias, const float* resid, float* C, bf16* Oh, bf16* Ol,
                  int M, int N, int K, long ab, long bb, long cb, int csm, int csn, int nb) {
        dim3 g(N / 128, (M + 127) / 128, nb);
        hipLaunchKernelGGL(mgemm_kernel, g, dim3(256), 0, stream,
                           Ah, Al, Bh, Bl, bias, resid, C, Oh, Ol, M, N, K, ab, bb, cb, csm, csn);
    };
    auto cvt2 = [&](const float* in, bf16* h2, bf16* l2, int n) {
        hipLaunchKernelGGL(cvt2_kernel, dim3((n / 4 + 255) / 256), dim3(256), 0, stream, in, h2, l2, n);
    };

    // ---- input conversions (hi/lo) ----
    cvt2(sa_in_w, sawin_h, sawin_l, 1536 * 512);
    cvt2(sa_out_w, sawout_h, sawout_l, 512 * 512);
    cvt2(ca_in_w, caw_h, caw_l, 1536 * 512);
    cvt2(ca_out_w, cawout_h, cawout_l, 512 * 512);
    cvt2(text, text_h, text_l, BB * TXT * 512);
    hipLaunchKernelGGL(trcvt2_kernel, dim3(32, 16, BB), dim3(256), 0, stream,
                       x, xT_h, xT_l, 512, 1024, (long)512 * 1024, (long)1024 * 512);
    hipLaunchKernelGGL(trcvt2_kernel, dim3(4, 16, 1), dim3(256), 0, stream,
                       r_feat, rfT_h, rfT_l, 512, 128, 0L, 0L);

    // ---- modconv in ----
    hipLaunchKernelGGL(style_kernel, dim3(8), dim3(256), 0, stream, w, pin_mw, pin_mb, style_in);
    hipLaunchKernelGGL(wtmod_kernel, dim3(BB * DIMC), dim3(256), 0, stream, pin_w, style_in, wtA_h, wtA_l);
    mg(xT_h, xT_l, wtA_h, wtA_l, nullptr, nullptr, x_flat, nullptr, nullptr,
       HWX, DIMC, DIMC, (long)HWX * DIMC, (long)DIMC * DIMC, (long)HWX * DIMC, DIMC, 1, BB);

    // ---- LN1 + self-attention (split MFMA) ----
    hipLaunchKernelGGL(ln_kernel, dim3(NTOK), dim3(256), 0, stream, x_flat, ln1g, ln1b,
                       (float*)nullptr, xn_h, xn_l);
    mg(xn_h, xn_l, sawin_h, sawin_l, sa_in_b, nullptr, nullptr, q_h, q_l,
       NTOK, 1536, 512, 0, 0, 0, 1536, 1, 1);
    hipLaunchKernelGGL(sa_mfma_kernel, dim3(16, HEADS, BB), dim3(256), 0, stream,
                       q_h, q_l, obuf_h, obuf_l);
    mg(obuf_h, obuf_l, sawout_h, sawout_l, sa_out_b, x_flat, x_flat, nullptr, nullptr,
       NTOK, 512, 512, 0, 0, 0, 512, 1, 1);

    // ---- LN2 + cross-attention (split MFMA) ----
    hipLaunchKernelGGL(ln_kernel, dim3(NTOK), dim3(256), 0, stream, x_flat, ln2g, ln2b,
                       (float*)nullptr, xn_h, xn_l);
    mg(xn_h, xn_l, caw_h, caw_l, ca_in_b, nullptr, nullptr, ca_qh, ca_ql,
       NTOK, 512, 512, 0, 0, 0, 512, 1, 1);
    mg(text_h, text_l, caw_h + 512 * 512, caw_l + 512 * 512, ca_in_b + 512, nullptr, nullptr,
       kvt_h, kvt_l, BB * TXT, 1024, 512, 0, 0, 0, 1024, 1, 1);
    hipLaunchKernelGGL(ca_mfma_kernel, dim3(16, HEADS, BB), dim3(256), 0, stream,
                       ca_qh, ca_ql, kvt_h, kvt_l, obuf_h, obuf_l);
    hipLaunchKernelGGL(trcvt_kernel, dim3(64, 16, NE), dim3(256), 0, stream,
                       e_w1, e1T, 512, 2048, (long)512 * 2048, (long)2048 * 512);
    hipLaunchKernelGGL(trcvt_kernel, dim3(16, 64, NE), dim3(256), 0, stream,
                       e_w2, e2T, 2048, 512, (long)2048 * 512, (long)512 * 2048);
    mg(obuf_h, obuf_l, cawout_h, cawout_l, ca_out_b, x_flat, x_flat, nullptr, nullptr,
       NTOK, 512, 512, 0, 0, 0, 512, 1, 1);

    // ---- LN3 + router (feat via split MFMA) ----
    hipLaunchKernelGGL(ln_kernel, dim3(NTOK), dim3(256), 0, stream, x_flat, ln3g, ln3b,
                       (float*)nullptr, xn_h, xn_l);
    mg(xn_h, xn_l, rfT_h, rfT_l, nullptr, nullptr, feat, nullptr, nullptr,
       NTOK, 128, 512, 0, 0, 0, 128, 1, 1);
    hipLaunchKernelGGL(textpart_kernel, dim3(1), dim3(256), 0, stream, w, r_text, r_comb, tp);
    hipLaunchKernelGGL(moe_init_kernel, dim3((MAXT * 128 + 255) / 256), dim3(256), 0, stream, cnt, perm);
    hipLaunchKernelGGL(route_kernel, dim3(16), dim3(256), 0, stream, feat, tp, r_comb, r_temp, onehot, idx, cnt);
    hipLaunchKernelGGL(offsets_kernel, dim3(1), dim3(64), 0, stream, cnt, cursor, ntiles, table);
    hipLaunchKernelGGL(scatter_kernel, dim3(16), dim3(256), 0, stream, idx, cursor, perm);

    // ---- MoE grouped MFMA GEMMs ----
    hipLaunchKernelGGL(moe_mfma1_kernel, dim3(HIDC / 128, MAXT), dim3(256), 0, stream,
                       xn_h, e1T, e_b1, table, ntiles, perm, hid_b);
    hipLaunchKernelGGL(moe_mfma2_kernel, dim3(DIMC / 128, MAXT), dim3(256), 0, stream,
                       hid_b, e2T, e_b2, table, ntiles, perm, x_flat);

    // ---- modconv out (split both sides) ----
    cvt2(x_flat, xfl_h, xfl_l, NTOK * DIMC);
    hipLaunchKernelGGL(style_kernel, dim3(8), dim3(256), 0, stream, w, pout_mw, pout_mb, style_out);
    hipLaunchKernelGGL(wtmod_kernel, dim3(BB * DIMC), dim3(256), 0, stream, pout_w, style_out, wtC_h, wtC_l);
    mg(wtC_h, wtC_l, xfl_h, xfl_l, nullptr, nullptr, out, nullptr, nullptr,
       DIMC, HWX, DIMC, (long)DIMC * DIMC, (long)HWX * DIMC, (long)DIMC * HWX, HWX, 1, BB);
}